// Round 1
// baseline (1112.341 us; speedup 1.0000x reference)
//
#include <hip/hip_runtime.h>
#include <hip/hip_bf16.h>

#define N_NODESC 50000
#define N_EDGESC 500000
#define E_TOT    (N_EDGESC + N_NODESC)   // 550000, with self loops
#define HID      64
#define HEADS_C  8
#define F1       (HEADS_C * HID)         // 512
#define VOCAB_C  40000
#define N_GR     512

__device__ __forceinline__ float wred_max(float v) {
#pragma unroll
  for (int o = 32; o; o >>= 1) v = fmaxf(v, __shfl_xor(v, o));
  return v;
}
__device__ __forceinline__ float wred_sum(float v) {
#pragma unroll
  for (int o = 32; o; o >>= 1) v += __shfl_xor(v, o);
  return v;
}
__device__ __forceinline__ float lrelu(float x) { return x > 0.f ? x : 0.2f * x; }

// ---- CSR build ----------------------------------------------------------
__global__ void k_deg(const int* __restrict__ ei, int* __restrict__ deg) {
  int e = blockIdx.x * blockDim.x + threadIdx.x;
  if (e >= E_TOT) return;
  int dst = (e < N_EDGESC) ? ei[N_EDGESC + e] : (e - N_EDGESC);
  atomicAdd(&deg[dst], 1);
}

__global__ void k_scan(const int* __restrict__ deg, int* __restrict__ rowstart) {
  // single block, 1024 threads
  __shared__ int part[1024];
  const int ITEMS = 49;  // 1024*49 = 50176 >= 50000
  int t = threadIdx.x;
  int lo = t * ITEMS, hi = min(lo + ITEMS, N_NODESC);
  int s = 0;
  for (int i = lo; i < hi; ++i) s += deg[i];
  part[t] = s;
  __syncthreads();
  if (t == 0) {
    int run = 0;
    for (int i = 0; i < 1024; ++i) { int tmp = part[i]; part[i] = run; run += tmp; }
    rowstart[N_NODESC] = run;
  }
  __syncthreads();
  int off = part[t];
  for (int i = lo; i < hi; ++i) { rowstart[i] = off; off += deg[i]; }
}

__global__ void k_scatter(const int* __restrict__ ei, const int* __restrict__ rowstart,
                          int* __restrict__ cursor, int* __restrict__ esrc) {
  int e = blockIdx.x * blockDim.x + threadIdx.x;
  if (e >= E_TOT) return;
  int src, dst;
  if (e < N_EDGESC) { src = ei[e]; dst = ei[N_EDGESC + e]; }
  else { src = dst = e - N_EDGESC; }
  int slot = rowstart[dst] + atomicAdd(&cursor[dst], 1);
  esrc[slot] = src;
}

// ---- embedding lookup ---------------------------------------------------
__global__ void k_embed(const int* __restrict__ x, const float* __restrict__ emb,
                        float* __restrict__ h) {
  int idx = blockIdx.x * blockDim.x + threadIdx.x;  // over N*16 float4s
  int n = idx >> 4, q = idx & 15;
  int row = x[n];
  reinterpret_cast<float4*>(h)[(size_t)n * 16 + q] =
      reinterpret_cast<const float4*>(emb)[(size_t)row * 16 + q];
}

// ---- GEMM1: hp1[N,512] = h[N,64] @ W1[64,512] ---------------------------
__global__ __launch_bounds__(512) void k_gemm1(const float* __restrict__ h,
                                               const float* __restrict__ W1,
                                               float* __restrict__ hp1) {
  int j = threadIdx.x;  // output column 0..511
  float w[64];
#pragma unroll
  for (int c = 0; c < 64; ++c) w[c] = W1[c * F1 + j];
  __shared__ float hs[128 * 64];  // 32 KB
  int n0 = blockIdx.x * 128;
  int nCnt = min(128, N_NODESC - n0);
  for (int idx = threadIdx.x; idx < nCnt * 64; idx += 512) hs[idx] = h[(size_t)n0 * 64 + idx];
  __syncthreads();
  for (int nl = 0; nl < nCnt; ++nl) {
    const float4* hr4 = reinterpret_cast<const float4*>(&hs[nl * 64]);
    float acc = 0.f;
#pragma unroll
    for (int c4 = 0; c4 < 16; ++c4) {
      float4 hv = hr4[c4];
      acc += hv.x * w[c4 * 4 + 0] + hv.y * w[c4 * 4 + 1] + hv.z * w[c4 * 4 + 2] + hv.w * w[c4 * 4 + 3];
    }
    hp1[(size_t)(n0 + nl) * F1 + j] = acc;
  }
}

// ---- scores layer 1: one wave per (n,h) ---------------------------------
__global__ void k_scores1(const float* __restrict__ hp1, const float* __restrict__ as1,
                          const float* __restrict__ ad1, float* __restrict__ s1s,
                          float* __restrict__ s1d) {
  int gid = blockIdx.x * 4 + (threadIdx.x >> 6);  // wave id over N*HEADS
  int lane = threadIdx.x & 63;
  int n = gid >> 3, hh = gid & 7;
  float v = hp1[(size_t)n * F1 + hh * 64 + lane];
  float xs = v * as1[hh * 64 + lane];
  float xd = v * ad1[hh * 64 + lane];
  xs = wred_sum(xs);
  xd = wred_sum(xd);
  if (lane == 0) { s1s[n * 8 + hh] = xs; s1d[n * 8 + hh] = xd; }
}

// ---- layer-1 softmax-aggregate + bias + ELU, one block(8 waves) per node -
__global__ __launch_bounds__(512) void k_agg1(const int* __restrict__ rowstart,
                                              const int* __restrict__ esrc,
                                              const float* __restrict__ hp1,
                                              const float* __restrict__ s1s,
                                              const float* __restrict__ s1d,
                                              const float* __restrict__ b1,
                                              float* __restrict__ h1) {
  int n = blockIdx.x;
  int hh = threadIdx.x >> 6;
  int lane = threadIdx.x & 63;
  int r0 = rowstart[n], r1 = rowstart[n + 1];
  int dg = r1 - r0;
  float sdst = s1d[n * 8 + hh];
  // pass 1: max
  float m = -1e30f;
  for (int i = lane; i < dg; i += 64) {
    int s = esrc[r0 + i];
    m = fmaxf(m, lrelu(s1s[s * 8 + hh] + sdst));
  }
  m = wred_max(m);
  // pass 2: denom
  float dsum = 0.f;
  for (int i = lane; i < dg; i += 64) {
    int s = esrc[r0 + i];
    dsum += expf(lrelu(s1s[s * 8 + hh] + sdst) - m);
  }
  dsum = wred_sum(dsum);
  float inv = 1.f / (dsum + 1e-16f);
  // pass 3: weighted aggregation (chunked, shuffle-broadcast alpha & src)
  float acc = 0.f;
  for (int base = 0; base < dg; base += 64) {
    int i = base + lane;
    float p = 0.f;
    int s = 0;
    if (i < dg) {
      s = esrc[r0 + i];
      p = expf(lrelu(s1s[s * 8 + hh] + sdst) - m) * inv;
    }
    int cnt = min(64, dg - base);
    for (int j = 0; j < cnt; ++j) {
      float pj = __shfl(p, j);
      int sj = __shfl(s, j);
      acc += hp1[(size_t)sj * F1 + hh * 64 + lane] * pj;
    }
  }
  float o = acc + b1[hh * 64 + lane];
  h1[(size_t)n * F1 + hh * 64 + lane] = o > 0.f ? o : (expf(o) - 1.f);
}

// ---- GEMM2: hp2[N,64] = h1[N,512] @ W2[512,64] --------------------------
__global__ __launch_bounds__(512) void k_gemm2(const float* __restrict__ h1,
                                               const float* __restrict__ W2,
                                               float* __restrict__ hp2) {
  __shared__ float h1s[8 * 512];    // 16 KB
  __shared__ float w2s[128 * 64];   // 32 KB
  int n0 = blockIdx.x * 8;  // 6250 * 8 = 50000 exact
  for (int idx = threadIdx.x; idx < 8 * 512; idx += 512) h1s[idx] = h1[(size_t)n0 * F1 + idx];
  int nl = threadIdx.x >> 6;
  int jj = threadIdx.x & 63;
  float acc = 0.f;
  for (int cc = 0; cc < 512; cc += 128) {
    __syncthreads();
    for (int idx = threadIdx.x; idx < 128 * 64; idx += 512) w2s[idx] = W2[cc * 64 + idx];
    __syncthreads();
#pragma unroll
    for (int c = 0; c < 128; ++c) acc += h1s[nl * 512 + cc + c] * w2s[c * 64 + jj];
  }
  hp2[(size_t)(n0 + nl) * 64 + jj] = acc;
}

// ---- scores layer 2: one wave per node ----------------------------------
__global__ void k_scores2(const float* __restrict__ hp2, const float* __restrict__ as2,
                          const float* __restrict__ ad2, float* __restrict__ s2s,
                          float* __restrict__ s2d) {
  int n = blockIdx.x * 4 + (threadIdx.x >> 6);
  int lane = threadIdx.x & 63;
  float v = hp2[(size_t)n * 64 + lane];
  float xs = v * as2[lane];
  float xd = v * ad2[lane];
  xs = wred_sum(xs);
  xd = wred_sum(xd);
  if (lane == 0) { s2s[n] = xs; s2d[n] = xd; }
}

// ---- layer-2 softmax-aggregate + bias + pooled atomicAdd ----------------
__global__ __launch_bounds__(64) void k_agg2(const int* __restrict__ rowstart,
                                             const int* __restrict__ esrc,
                                             const float* __restrict__ hp2,
                                             const float* __restrict__ s2s,
                                             const float* __restrict__ s2d,
                                             const float* __restrict__ b2,
                                             const int* __restrict__ batch,
                                             float* __restrict__ pooled) {
  int n = blockIdx.x;
  int lane = threadIdx.x;
  int r0 = rowstart[n], r1 = rowstart[n + 1];
  int dg = r1 - r0;
  float sdst = s2d[n];
  float m = -1e30f;
  for (int i = lane; i < dg; i += 64) m = fmaxf(m, lrelu(s2s[esrc[r0 + i]] + sdst));
  m = wred_max(m);
  float dsum = 0.f;
  for (int i = lane; i < dg; i += 64) dsum += expf(lrelu(s2s[esrc[r0 + i]] + sdst) - m);
  dsum = wred_sum(dsum);
  float inv = 1.f / (dsum + 1e-16f);
  float acc = 0.f;
  for (int base = 0; base < dg; base += 64) {
    int i = base + lane;
    float p = 0.f;
    int s = 0;
    if (i < dg) {
      s = esrc[r0 + i];
      p = expf(lrelu(s2s[s] + sdst) - m) * inv;
    }
    int cnt = min(64, dg - base);
    for (int j = 0; j < cnt; ++j) {
      float pj = __shfl(p, j);
      int sj = __shfl(s, j);
      acc += hp2[(size_t)sj * 64 + lane] * pj;
    }
  }
  float o = acc + b2[lane];
  atomicAdd(&pooled[batch[n] * 64 + lane], o);
}

// ---- final: out[512,40000] = pooled[512,64] @ Wp[64,40000] + bp ---------
__global__ __launch_bounds__(256) void k_final(const float* __restrict__ pooled,
                                               const float* __restrict__ Wp,
                                               const float* __restrict__ bp,
                                               float* __restrict__ out) {
  int v = blockIdx.x * 256 + threadIdx.x;
  bool valid = v < VOCAB_C;
  float w[64];
  float bpv = 0.f;
  if (valid) {
#pragma unroll
    for (int c = 0; c < 64; ++c) w[c] = Wp[(size_t)c * VOCAB_C + v];
    bpv = bp[v];
  }
  __shared__ float ps[128 * 64];  // 32 KB
  for (int g0 = 0; g0 < N_GR; g0 += 128) {
    __syncthreads();
    for (int idx = threadIdx.x; idx < 128 * 64; idx += 256) ps[idx] = pooled[g0 * 64 + idx];
    __syncthreads();
    for (int gl = 0; gl < 128; ++gl) {
      const float4* pr4 = reinterpret_cast<const float4*>(&ps[gl * 64]);
      float acc = bpv;
#pragma unroll
      for (int c4 = 0; c4 < 16; ++c4) {
        float4 pv = pr4[c4];
        acc += pv.x * w[c4 * 4 + 0] + pv.y * w[c4 * 4 + 1] + pv.z * w[c4 * 4 + 2] + pv.w * w[c4 * 4 + 3];
      }
      if (valid) out[(size_t)(g0 + gl) * VOCAB_C + v] = acc;
    }
  }
}

extern "C" void kernel_launch(void* const* d_in, const int* in_sizes, int n_in,
                              void* d_out, int out_size, void* d_ws, size_t ws_size,
                              hipStream_t stream) {
  const int*   x     = (const int*)d_in[0];
  const int*   ei    = (const int*)d_in[1];
  const int*   batch = (const int*)d_in[2];
  const float* emb   = (const float*)d_in[3];
  const float* W1    = (const float*)d_in[4];
  const float* as1   = (const float*)d_in[5];
  const float* ad1   = (const float*)d_in[6];
  const float* b1    = (const float*)d_in[7];
  const float* W2    = (const float*)d_in[8];
  const float* as2   = (const float*)d_in[9];
  const float* ad2   = (const float*)d_in[10];
  const float* b2    = (const float*)d_in[11];
  const float* Wp    = (const float*)d_in[12];
  const float* bp    = (const float*)d_in[13];
  float* out = (float*)d_out;

  char* ws = (char*)d_ws;
  size_t off = 0;
#define WS_ALLOC(T, name, bytes) T name = (T)(ws + off); off += (((size_t)(bytes)) + 255) & ~(size_t)255;
  WS_ALLOC(float*, h,    (size_t)N_NODESC * HID * 4)     // reused as hp2
  WS_ALLOC(float*, hp1,  (size_t)N_NODESC * F1 * 4)
  WS_ALLOC(float*, h1,   (size_t)N_NODESC * F1 * 4)
  WS_ALLOC(float*, s1s,  (size_t)N_NODESC * HEADS_C * 4)
  WS_ALLOC(float*, s1d,  (size_t)N_NODESC * HEADS_C * 4)
  WS_ALLOC(float*, s2s,  (size_t)N_NODESC * 4)
  WS_ALLOC(float*, s2d,  (size_t)N_NODESC * 4)
  WS_ALLOC(float*, pooled, (size_t)N_GR * HID * 4)
  WS_ALLOC(int*,   deg,      (size_t)N_NODESC * 4)
  WS_ALLOC(int*,   rowstart, (size_t)(N_NODESC + 1) * 4)
  WS_ALLOC(int*,   cursor,   (size_t)N_NODESC * 4)
  WS_ALLOC(int*,   esrc,     (size_t)E_TOT * 4)
#undef WS_ALLOC
  float* hp2 = h;
  (void)ws_size; (void)in_sizes; (void)n_in; (void)out_size;

  hipMemsetAsync(deg, 0, (size_t)N_NODESC * 4, stream);
  hipMemsetAsync(cursor, 0, (size_t)N_NODESC * 4, stream);
  hipMemsetAsync(pooled, 0, (size_t)N_GR * HID * 4, stream);

  int ethreads = 256, eblocks = (E_TOT + 255) / 256;
  k_deg<<<eblocks, ethreads, 0, stream>>>(ei, deg);
  k_scan<<<1, 1024, 0, stream>>>(deg, rowstart);
  k_scatter<<<eblocks, ethreads, 0, stream>>>(ei, rowstart, cursor, esrc);

  k_embed<<<(N_NODESC * 16) / 256, 256, 0, stream>>>(x, emb, h);
  k_gemm1<<<(N_NODESC + 127) / 128, 512, 0, stream>>>(h, W1, hp1);
  k_scores1<<<(N_NODESC * HEADS_C) / 4, 256, 0, stream>>>(hp1, as1, ad1, s1s, s1d);
  k_agg1<<<N_NODESC, 512, 0, stream>>>(rowstart, esrc, hp1, s1s, s1d, b1, h1);

  k_gemm2<<<N_NODESC / 8, 512, 0, stream>>>(h1, W2, hp2);
  k_scores2<<<N_NODESC / 4, 256, 0, stream>>>(hp2, as2, ad2, s2s, s2d);
  k_agg2<<<N_NODESC, 64, 0, stream>>>(rowstart, esrc, hp2, s2s, s2d, b2, batch, pooled);

  k_final<<<(VOCAB_C + 255) / 256, 256, 0, stream>>>(pooled, Wp, bp, out);
}

// Round 2
// 841.372 us; speedup vs baseline: 1.3221x; 1.3221x over previous
//
#include <hip/hip_runtime.h>
#include <hip/hip_bf16.h>

#define N_NODESC 50000
#define N_EDGESC 500000
#define E_TOT    (N_EDGESC + N_NODESC)   // 550000, with self loops
#define HID      64
#define HEADS_C  8
#define F1       (HEADS_C * HID)         // 512
#define VOCAB_C  40000
#define N_GR     512

__device__ __forceinline__ float wred_max(float v) {
#pragma unroll
  for (int o = 32; o; o >>= 1) v = fmaxf(v, __shfl_xor(v, o));
  return v;
}
__device__ __forceinline__ float wred_sum(float v) {
#pragma unroll
  for (int o = 32; o; o >>= 1) v += __shfl_xor(v, o);
  return v;
}
__device__ __forceinline__ float lrelu(float x) { return x > 0.f ? x : 0.2f * x; }
__device__ __forceinline__ float bf2f(unsigned short u) {
  return __uint_as_float(((unsigned int)u) << 16);
}
__device__ __forceinline__ unsigned short f2bf(float f) {
  unsigned int u = __float_as_uint(f);
  unsigned int r = (u + 0x7fffu + ((u >> 16) & 1u)) >> 16;
  return (unsigned short)r;
}

// ---- CSR build ----------------------------------------------------------
__global__ void k_deg(const int* __restrict__ ei, int* __restrict__ deg) {
  int e = blockIdx.x * blockDim.x + threadIdx.x;
  if (e >= E_TOT) return;
  int dst = (e < N_EDGESC) ? ei[N_EDGESC + e] : (e - N_EDGESC);
  atomicAdd(&deg[dst], 1);
}

__global__ void k_scan(const int* __restrict__ deg, int* __restrict__ rowstart) {
  __shared__ int part[1024];
  const int ITEMS = 49;  // 1024*49 = 50176 >= 50000
  int t = threadIdx.x;
  int lo = t * ITEMS, hi = min(lo + ITEMS, N_NODESC);
  int s = 0;
  for (int i = lo; i < hi; ++i) s += deg[i];
  part[t] = s;
  __syncthreads();
  // Hillis-Steele inclusive scan over 1024 partials
  for (int o = 1; o < 1024; o <<= 1) {
    int v = (t >= o) ? part[t - o] : 0;
    __syncthreads();
    part[t] += v;
    __syncthreads();
  }
  int off = part[t] - s;  // exclusive
  for (int i = lo; i < hi; ++i) { rowstart[i] = off; off += deg[i]; }
  if (t == 1023) rowstart[N_NODESC] = part[1023];
}

__global__ void k_scatter(const int* __restrict__ ei, const int* __restrict__ rowstart,
                          int* __restrict__ cursor, int* __restrict__ esrc) {
  int e = blockIdx.x * blockDim.x + threadIdx.x;
  if (e >= E_TOT) return;
  int src, dst;
  if (e < N_EDGESC) { src = ei[e]; dst = ei[N_EDGESC + e]; }
  else { src = dst = e - N_EDGESC; }
  int slot = rowstart[dst] + atomicAdd(&cursor[dst], 1);
  esrc[slot] = src;
}

// ---- embedding lookup ---------------------------------------------------
__global__ void k_embed(const int* __restrict__ x, const float* __restrict__ emb,
                        float* __restrict__ h) {
  int idx = blockIdx.x * blockDim.x + threadIdx.x;  // over N*16 float4s
  int n = idx >> 4, q = idx & 15;
  int row = x[n];
  reinterpret_cast<float4*>(h)[(size_t)n * 16 + q] =
      reinterpret_cast<const float4*>(emb)[(size_t)row * 16 + q];
}

// ---- GEMM1: hp1b[N,512](bf16) = h[N,64] @ W1[64,512] --------------------
__global__ __launch_bounds__(512) void k_gemm1(const float* __restrict__ h,
                                               const float* __restrict__ W1,
                                               unsigned short* __restrict__ hp1b) {
  int j = threadIdx.x;  // output column 0..511
  float w[64];
#pragma unroll
  for (int c = 0; c < 64; ++c) w[c] = W1[c * F1 + j];
  __shared__ float hs[128 * 64];  // 32 KB
  int n0 = blockIdx.x * 128;
  int nCnt = min(128, N_NODESC - n0);
  for (int idx = threadIdx.x; idx < nCnt * 64; idx += 512) hs[idx] = h[(size_t)n0 * 64 + idx];
  __syncthreads();
  for (int nl = 0; nl < nCnt; ++nl) {
    const float4* hr4 = reinterpret_cast<const float4*>(&hs[nl * 64]);
    float acc = 0.f;
#pragma unroll
    for (int c4 = 0; c4 < 16; ++c4) {
      float4 hv = hr4[c4];
      acc += hv.x * w[c4 * 4 + 0] + hv.y * w[c4 * 4 + 1] + hv.z * w[c4 * 4 + 2] + hv.w * w[c4 * 4 + 3];
    }
    hp1b[(size_t)(n0 + nl) * F1 + j] = f2bf(acc);
  }
}

// ---- scores layer 1: one wave per (n,h) ---------------------------------
__global__ void k_scores1(const unsigned short* __restrict__ hp1b,
                          const float* __restrict__ as1, const float* __restrict__ ad1,
                          float* __restrict__ s1s, float* __restrict__ s1d) {
  int gid = blockIdx.x * 4 + (threadIdx.x >> 6);  // wave id over N*HEADS
  int lane = threadIdx.x & 63;
  int n = gid >> 3, hh = gid & 7;
  float v = bf2f(hp1b[(size_t)n * F1 + hh * 64 + lane]);
  float xs = v * as1[hh * 64 + lane];
  float xd = v * ad1[hh * 64 + lane];
  xs = wred_sum(xs);
  xd = wred_sum(xd);
  if (lane == 0) { s1s[n * 8 + hh] = xs; s1d[n * 8 + hh] = xd; }
}

// ---- layer-1 softmax-aggregate + bias + ELU; 2 waves (head-quads) per node
__global__ __launch_bounds__(128) void k_agg1(const int* __restrict__ rowstart,
                                              const int* __restrict__ esrc,
                                              const unsigned short* __restrict__ hp1b,
                                              const float* __restrict__ s1s,
                                              const float* __restrict__ s1d,
                                              const float* __restrict__ b1,
                                              unsigned short* __restrict__ h1b) {
  int n = blockIdx.x;
  int wq = threadIdx.x >> 6;      // head-quad 0/1 -> heads 4wq..4wq+3
  int lane = threadIdx.x & 63;
  int myh = wq * 4 + (lane >> 4); // this lane's head
  int sub = lane & 15;
  int r0 = rowstart[n], dg = rowstart[n + 1] - r0;
  float sdst = s1d[n * 8 + myh];
  // pass 1: per-head max (16-lane groups sweep all edges, stride 16)
  float m = -1e30f;
  for (int i = sub; i < dg; i += 16)
    m = fmaxf(m, lrelu(s1s[esrc[r0 + i] * 8 + myh] + sdst));
#pragma unroll
  for (int o = 1; o < 16; o <<= 1) m = fmaxf(m, __shfl_xor(m, o));
  // pass 2: denom
  float dsum = 0.f;
  for (int i = sub; i < dg; i += 16)
    dsum += expf(lrelu(s1s[esrc[r0 + i] * 8 + myh] + sdst) - m);
#pragma unroll
  for (int o = 1; o < 16; o <<= 1) dsum += __shfl_xor(dsum, o);
  float inv = 1.f / (dsum + 1e-16f);
  // pass 3: aggregate, 16-edge chunks; lane covers 4 bf16 features (8B load)
  float4 acc = {0.f, 0.f, 0.f, 0.f};
  const size_t qoff = (size_t)wq * 256 + (size_t)lane * 4;
  for (int base = 0; base < dg; base += 16) {
    int i = base + sub;
    float p = 0.f;
    int s = 0;
    if (i < dg) {
      s = esrc[r0 + i];
      p = expf(lrelu(s1s[s * 8 + myh] + sdst) - m) * inv;
    }
    int cnt = min(16, dg - base);
    for (int j = 0; j < cnt; ++j) {
      float pj = __shfl(p, j, 16);
      int sj = __shfl(s, j, 16);
      ushort4 hv = *reinterpret_cast<const ushort4*>(&hp1b[(size_t)sj * F1 + qoff]);
      acc.x += pj * bf2f(hv.x);
      acc.y += pj * bf2f(hv.y);
      acc.z += pj * bf2f(hv.z);
      acc.w += pj * bf2f(hv.w);
    }
  }
  int fbase = wq * 256 + lane * 4;
  float o0 = acc.x + b1[fbase + 0];
  float o1 = acc.y + b1[fbase + 1];
  float o2 = acc.z + b1[fbase + 2];
  float o3 = acc.w + b1[fbase + 3];
  o0 = o0 > 0.f ? o0 : (expf(o0) - 1.f);
  o1 = o1 > 0.f ? o1 : (expf(o1) - 1.f);
  o2 = o2 > 0.f ? o2 : (expf(o2) - 1.f);
  o3 = o3 > 0.f ? o3 : (expf(o3) - 1.f);
  ushort4 ov;
  ov.x = f2bf(o0); ov.y = f2bf(o1); ov.z = f2bf(o2); ov.w = f2bf(o3);
  *reinterpret_cast<ushort4*>(&h1b[(size_t)n * F1 + fbase]) = ov;
}

// ---- GEMM2: hp2b[N,64](bf16) = h1b[N,512] @ W2[512,64] ------------------
__global__ __launch_bounds__(512) void k_gemm2(const unsigned short* __restrict__ h1b,
                                               const float* __restrict__ W2,
                                               unsigned short* __restrict__ hp2b) {
  __shared__ float h1s[8 * 512];    // 16 KB
  __shared__ float w2s[128 * 64];   // 32 KB
  int n0 = blockIdx.x * 8;  // 6250 * 8 = 50000 exact
  const ushort4* h1v = reinterpret_cast<const ushort4*>(h1b + (size_t)n0 * F1);
  for (int idx = threadIdx.x; idx < 8 * 128; idx += 512) {
    ushort4 u = h1v[idx];
    h1s[idx * 4 + 0] = bf2f(u.x);
    h1s[idx * 4 + 1] = bf2f(u.y);
    h1s[idx * 4 + 2] = bf2f(u.z);
    h1s[idx * 4 + 3] = bf2f(u.w);
  }
  int nl = threadIdx.x >> 6;
  int jj = threadIdx.x & 63;
  float acc = 0.f;
  for (int cc = 0; cc < 512; cc += 128) {
    __syncthreads();
    for (int idx = threadIdx.x; idx < 128 * 64; idx += 512) w2s[idx] = W2[cc * 64 + idx];
    __syncthreads();
#pragma unroll
    for (int c = 0; c < 128; ++c) acc += h1s[nl * 512 + cc + c] * w2s[c * 64 + jj];
  }
  hp2b[(size_t)(n0 + nl) * 64 + jj] = f2bf(acc);
}

// ---- scores layer 2: one wave per node ----------------------------------
__global__ void k_scores2(const unsigned short* __restrict__ hp2b,
                          const float* __restrict__ as2, const float* __restrict__ ad2,
                          float* __restrict__ s2s, float* __restrict__ s2d) {
  int n = blockIdx.x * 4 + (threadIdx.x >> 6);
  int lane = threadIdx.x & 63;
  float v = bf2f(hp2b[(size_t)n * 64 + lane]);
  float xs = v * as2[lane];
  float xd = v * ad2[lane];
  xs = wred_sum(xs);
  xd = wred_sum(xd);
  if (lane == 0) { s2s[n] = xs; s2d[n] = xd; }
}

// ---- layer-2 softmax-aggregate + bias + pooled atomicAdd ----------------
// One wave per node; 2 edges per inner iteration (ushort2 loads).
__global__ __launch_bounds__(64) void k_agg2(const int* __restrict__ rowstart,
                                             const int* __restrict__ esrc,
                                             const unsigned short* __restrict__ hp2b,
                                             const float* __restrict__ s2s,
                                             const float* __restrict__ s2d,
                                             const float* __restrict__ b2,
                                             const int* __restrict__ batch,
                                             float* __restrict__ pooled) {
  int n = blockIdx.x;
  int lane = threadIdx.x;
  int half = lane >> 5;       // edge parity
  int fl = lane & 31;         // feature pair index: features 2fl, 2fl+1
  int r0 = rowstart[n], dg = rowstart[n + 1] - r0;
  float sdst = s2d[n];
  float m = -1e30f;
  for (int i = lane; i < dg; i += 64) m = fmaxf(m, lrelu(s2s[esrc[r0 + i]] + sdst));
  m = wred_max(m);
  float dsum = 0.f;
  for (int i = lane; i < dg; i += 64) dsum += expf(lrelu(s2s[esrc[r0 + i]] + sdst) - m);
  dsum = wred_sum(dsum);
  float inv = 1.f / (dsum + 1e-16f);
  float ax = 0.f, ay = 0.f;
  for (int base = 0; base < dg; base += 32) {
    int i = base + fl;  // both halves compute same 32 alphas
    float p = 0.f;
    int s = 0;
    if (i < dg && half == 0) { /* only lo half needs valid p/s, but compute in both for shfl symmetry */ }
    if (i < dg) {
      s = esrc[r0 + i];
      p = expf(lrelu(s2s[s] + sdst) - m) * inv;
    }
    int cnt = min(32, dg - base);
    for (int j = 0; j < cnt; j += 2) {
      int jj = j + half;  // lo half: edge j; hi half: edge j+1 (p=0 beyond cnt)
      float pj = __shfl(p, jj, 32);
      int sj = __shfl(s, jj, 32);
      ushort2 hv = *reinterpret_cast<const ushort2*>(&hp2b[(size_t)sj * 64 + fl * 2]);
      ax += pj * bf2f(hv.x);
      ay += pj * bf2f(hv.y);
    }
  }
  // combine halves: each feature pair summed across lane fl and lane 32+fl
  ax += __shfl_xor(ax, 32);
  ay += __shfl_xor(ay, 32);
  int f = 2 * fl + half;
  float o = (half ? ay : ax) + b2[f];
  atomicAdd(&pooled[batch[n] * 64 + f], o);
}

// ---- final: out[512,40000] = pooled[512,64] @ Wp[64,40000] + bp ---------
__global__ __launch_bounds__(256) void k_final(const float* __restrict__ pooled,
                                               const float* __restrict__ Wp,
                                               const float* __restrict__ bp,
                                               float* __restrict__ out) {
  int v = blockIdx.x * 256 + threadIdx.x;
  bool valid = v < VOCAB_C;
  float w[64];
  float bpv = 0.f;
  if (valid) {
#pragma unroll
    for (int c = 0; c < 64; ++c) w[c] = Wp[(size_t)c * VOCAB_C + v];
    bpv = bp[v];
  }
  __shared__ float ps[128 * 64];  // 32 KB
  for (int g0 = 0; g0 < N_GR; g0 += 128) {
    __syncthreads();
    for (int idx = threadIdx.x; idx < 128 * 64; idx += 256) ps[idx] = pooled[g0 * 64 + idx];
    __syncthreads();
    for (int gl = 0; gl < 128; ++gl) {
      const float4* pr4 = reinterpret_cast<const float4*>(&ps[gl * 64]);
      float acc = bpv;
#pragma unroll
      for (int c4 = 0; c4 < 16; ++c4) {
        float4 pv = pr4[c4];
        acc += pv.x * w[c4 * 4 + 0] + pv.y * w[c4 * 4 + 1] + pv.z * w[c4 * 4 + 2] + pv.w * w[c4 * 4 + 3];
      }
      if (valid) out[(size_t)(g0 + gl) * VOCAB_C + v] = acc;
    }
  }
}

extern "C" void kernel_launch(void* const* d_in, const int* in_sizes, int n_in,
                              void* d_out, int out_size, void* d_ws, size_t ws_size,
                              hipStream_t stream) {
  const int*   x     = (const int*)d_in[0];
  const int*   ei    = (const int*)d_in[1];
  const int*   batch = (const int*)d_in[2];
  const float* emb   = (const float*)d_in[3];
  const float* W1    = (const float*)d_in[4];
  const float* as1   = (const float*)d_in[5];
  const float* ad1   = (const float*)d_in[6];
  const float* b1    = (const float*)d_in[7];
  const float* W2    = (const float*)d_in[8];
  const float* as2   = (const float*)d_in[9];
  const float* ad2   = (const float*)d_in[10];
  const float* b2    = (const float*)d_in[11];
  const float* Wp    = (const float*)d_in[12];
  const float* bp    = (const float*)d_in[13];
  float* out = (float*)d_out;

  char* ws = (char*)d_ws;
  size_t off = 0;
#define WS_ALLOC(T, name, bytes) T name = (T)(ws + off); off += (((size_t)(bytes)) + 255) & ~(size_t)255;
  WS_ALLOC(float*, h,    (size_t)N_NODESC * HID * 4)
  WS_ALLOC(unsigned short*, hp1b, (size_t)N_NODESC * F1 * 2)
  WS_ALLOC(unsigned short*, h1b,  (size_t)N_NODESC * F1 * 2)
  WS_ALLOC(unsigned short*, hp2b, (size_t)N_NODESC * HID * 2)
  WS_ALLOC(float*, s1s,  (size_t)N_NODESC * HEADS_C * 4)
  WS_ALLOC(float*, s1d,  (size_t)N_NODESC * HEADS_C * 4)
  WS_ALLOC(float*, s2s,  (size_t)N_NODESC * 4)
  WS_ALLOC(float*, s2d,  (size_t)N_NODESC * 4)
  WS_ALLOC(float*, pooled, (size_t)N_GR * HID * 4)
  WS_ALLOC(int*,   deg,      (size_t)N_NODESC * 4)
  WS_ALLOC(int*,   rowstart, (size_t)(N_NODESC + 1) * 4)
  WS_ALLOC(int*,   cursor,   (size_t)N_NODESC * 4)
  WS_ALLOC(int*,   esrc,     (size_t)E_TOT * 4)
#undef WS_ALLOC
  (void)ws_size; (void)in_sizes; (void)n_in; (void)out_size;

  hipMemsetAsync(deg, 0, (size_t)N_NODESC * 4, stream);
  hipMemsetAsync(cursor, 0, (size_t)N_NODESC * 4, stream);
  hipMemsetAsync(pooled, 0, (size_t)N_GR * HID * 4, stream);

  int ethreads = 256, eblocks = (E_TOT + 255) / 256;
  k_deg<<<eblocks, ethreads, 0, stream>>>(ei, deg);
  k_scan<<<1, 1024, 0, stream>>>(deg, rowstart);
  k_scatter<<<eblocks, ethreads, 0, stream>>>(ei, rowstart, cursor, esrc);

  k_embed<<<(N_NODESC * 16) / 256, 256, 0, stream>>>(x, emb, h);
  k_gemm1<<<(N_NODESC + 127) / 128, 512, 0, stream>>>(h, W1, hp1b);
  k_scores1<<<(N_NODESC * HEADS_C) / 4, 256, 0, stream>>>(hp1b, as1, ad1, s1s, s1d);
  k_agg1<<<N_NODESC, 128, 0, stream>>>(rowstart, esrc, hp1b, s1s, s1d, b1, h1b);

  k_gemm2<<<N_NODESC / 8, 512, 0, stream>>>(h1b, W2, hp2b);
  k_scores2<<<N_NODESC / 4, 256, 0, stream>>>(hp2b, as2, ad2, s2s, s2d);
  k_agg2<<<N_NODESC, 64, 0, stream>>>(rowstart, esrc, hp2b, s2s, s2d, b2, batch, pooled);

  k_final<<<(VOCAB_C + 255) / 256, 256, 0, stream>>>(pooled, Wp, bp, out);
}

// Round 3
// 687.495 us; speedup vs baseline: 1.6180x; 1.2238x over previous
//
#include <hip/hip_runtime.h>
#include <hip/hip_bf16.h>

#define N_NODESC 50000
#define N_EDGESC 500000
#define E_TOT    (N_EDGESC + N_NODESC)   // 550000, with self loops
#define HID      64
#define HEADS_C  8
#define F1       (HEADS_C * HID)         // 512
#define VOCAB_C  40000
#define N_GR     512

__device__ __forceinline__ float wred_max(float v) {
#pragma unroll
  for (int o = 32; o; o >>= 1) v = fmaxf(v, __shfl_xor(v, o));
  return v;
}
__device__ __forceinline__ float wred_sum(float v) {
#pragma unroll
  for (int o = 32; o; o >>= 1) v += __shfl_xor(v, o);
  return v;
}
__device__ __forceinline__ float lrelu(float x) { return x > 0.f ? x : 0.2f * x; }
__device__ __forceinline__ float bf2f(unsigned short u) {
  return __uint_as_float(((unsigned int)u) << 16);
}
__device__ __forceinline__ unsigned short f2bf(float f) {
  unsigned int u = __float_as_uint(f);
  unsigned int r = (u + 0x7fffu + ((u >> 16) & 1u)) >> 16;
  return (unsigned short)r;
}

// ---- CSR build ----------------------------------------------------------
__global__ void k_deg(const int* __restrict__ ei, int* __restrict__ deg) {
  int e = blockIdx.x * blockDim.x + threadIdx.x;
  if (e >= E_TOT) return;
  int dst = (e < N_EDGESC) ? ei[N_EDGESC + e] : (e - N_EDGESC);
  atomicAdd(&deg[dst], 1);
}

__global__ void k_scan(const int* __restrict__ deg, int* __restrict__ rowstart) {
  __shared__ int part[1024];
  const int ITEMS = 49;  // 1024*49 = 50176 >= 50000
  int t = threadIdx.x;
  int lo = t * ITEMS, hi = min(lo + ITEMS, N_NODESC);
  int s = 0;
  for (int i = lo; i < hi; ++i) s += deg[i];
  part[t] = s;
  __syncthreads();
  for (int o = 1; o < 1024; o <<= 1) {
    int v = (t >= o) ? part[t - o] : 0;
    __syncthreads();
    part[t] += v;
    __syncthreads();
  }
  int off = part[t] - s;  // exclusive
  for (int i = lo; i < hi; ++i) { rowstart[i] = off; off += deg[i]; }
  if (t == 1023) rowstart[N_NODESC] = part[1023];
}

__global__ void k_scatter(const int* __restrict__ ei, const int* __restrict__ rowstart,
                          int* __restrict__ cursor, int* __restrict__ esrc) {
  int e = blockIdx.x * blockDim.x + threadIdx.x;
  if (e >= E_TOT) return;
  int src, dst;
  if (e < N_EDGESC) { src = ei[e]; dst = ei[N_EDGESC + e]; }
  else { src = dst = e - N_EDGESC; }
  int slot = rowstart[dst] + atomicAdd(&cursor[dst], 1);
  esrc[slot] = src;
}

// ---- prep: fold attention vectors through the weight matrices -----------
// Wa1s[k][h] = sum_c W1[k][h*64+c]*as1[h][c];  w2sv[k] = sum_c W2[k][c]*as2[c]
__global__ __launch_bounds__(512) void k_prep(const float* __restrict__ W1,
                                              const float* __restrict__ as1,
                                              const float* __restrict__ ad1,
                                              const float* __restrict__ W2,
                                              const float* __restrict__ as2,
                                              const float* __restrict__ ad2,
                                              float* __restrict__ wa1s, float* __restrict__ wa1d,
                                              float* __restrict__ w2sv, float* __restrict__ w2dv) {
  int t = threadIdx.x;  // 512
  int k = t >> 3, h = t & 7;
  float ss = 0.f, dd = 0.f;
  for (int c = 0; c < 64; ++c) {
    float w = W1[k * F1 + h * 64 + c];
    ss += w * as1[h * 64 + c];
    dd += w * ad1[h * 64 + c];
  }
  // stored h-major: wa1s[h][k]
  wa1s[h * 64 + k] = ss;
  wa1d[h * 64 + k] = dd;
  float s2 = 0.f, d2 = 0.f;
  for (int c = 0; c < 64; ++c) {
    float w = W2[t * 64 + c];
    s2 += w * as2[c];
    d2 += w * ad2[c];
  }
  w2sv[t] = s2;
  w2dv[t] = d2;
}

// ---- GEMM1 (+embed gather +scores1): hp1b = emb[x] @ W1 -----------------
__global__ __launch_bounds__(512) void k_gemm1(const int* __restrict__ x,
                                               const float* __restrict__ emb,
                                               const float* __restrict__ W1,
                                               const float* __restrict__ wa1s,
                                               const float* __restrict__ wa1d,
                                               unsigned short* __restrict__ hp1b,
                                               float* __restrict__ s1s,
                                               float* __restrict__ s1d) {
  int j = threadIdx.x;  // output column 0..511
  float w[64];
#pragma unroll
  for (int c = 0; c < 64; ++c) w[c] = W1[c * F1 + j];
  __shared__ float hs[128 * 64];  // 32 KB
  __shared__ float was[8 * 64], wad[8 * 64];
  was[j] = wa1s[j];
  wad[j] = wa1d[j];
  int n0 = blockIdx.x * 128;
  int nCnt = min(128, N_NODESC - n0);
  for (int idx = threadIdx.x; idx < nCnt * 16; idx += 512) {
    int node = idx >> 4, q = idx & 15;
    int row = x[n0 + node];
    reinterpret_cast<float4*>(hs)[idx] =
        reinterpret_cast<const float4*>(emb)[(size_t)row * 16 + q];
  }
  __syncthreads();
  for (int nl = 0; nl < nCnt; ++nl) {
    const float4* hr4 = reinterpret_cast<const float4*>(&hs[nl * 64]);
    float acc = 0.f;
#pragma unroll
    for (int c4 = 0; c4 < 16; ++c4) {
      float4 hv = hr4[c4];
      acc += hv.x * w[c4 * 4 + 0] + hv.y * w[c4 * 4 + 1] + hv.z * w[c4 * 4 + 2] + hv.w * w[c4 * 4 + 3];
    }
    hp1b[(size_t)(n0 + nl) * F1 + j] = f2bf(acc);
  }
  // ---- scores epilogue: 4 threads per node, each does 4 head-dots of 64
  int nl2 = j >> 2;        // node 0..127
  int part = j & 3;        // bit1: src/dst, bit0: head group (0..3 / 4..7)
  if (nl2 < nCnt) {
    const float* wa = (part & 2) ? wad : was;
    int h0 = (part & 1) * 4;
    float a0 = 0.f, a1 = 0.f, a2 = 0.f, a3 = 0.f;
#pragma unroll 8
    for (int kk = 0; kk < 64; ++kk) {
      int k = (kk + nl2) & 63;  // rotate start to kill LDS bank conflicts on hs
      float hv = hs[nl2 * 64 + k];
      a0 += hv * wa[(h0 + 0) * 64 + k];
      a1 += hv * wa[(h0 + 1) * 64 + k];
      a2 += hv * wa[(h0 + 2) * 64 + k];
      a3 += hv * wa[(h0 + 3) * 64 + k];
    }
    float4 st = {a0, a1, a2, a3};
    float* dst = (part & 2) ? s1d : s1s;
    reinterpret_cast<float4*>(dst)[(size_t)(n0 + nl2) * 2 + (part & 1)] = st;
  }
}

// ---- layer-1 softmax-aggregate + bias + ELU; 2 waves (head-quads) per node
__global__ __launch_bounds__(128) void k_agg1(const int* __restrict__ rowstart,
                                              const int* __restrict__ esrc,
                                              const unsigned short* __restrict__ hp1b,
                                              const float* __restrict__ s1s,
                                              const float* __restrict__ s1d,
                                              const float* __restrict__ b1,
                                              unsigned short* __restrict__ h1b) {
  int n = blockIdx.x;
  int wq = threadIdx.x >> 6;      // head-quad 0/1 -> heads 4wq..4wq+3
  int lane = threadIdx.x & 63;
  int myh = wq * 4 + (lane >> 4); // this lane's head
  int sub = lane & 15;
  int r0 = rowstart[n], dg = rowstart[n + 1] - r0;
  float sdst = s1d[n * 8 + myh];
  float m = -1e30f;
  for (int i = sub; i < dg; i += 16)
    m = fmaxf(m, lrelu(s1s[esrc[r0 + i] * 8 + myh] + sdst));
#pragma unroll
  for (int o = 1; o < 16; o <<= 1) m = fmaxf(m, __shfl_xor(m, o));
  float dsum = 0.f;
  for (int i = sub; i < dg; i += 16)
    dsum += expf(lrelu(s1s[esrc[r0 + i] * 8 + myh] + sdst) - m);
#pragma unroll
  for (int o = 1; o < 16; o <<= 1) dsum += __shfl_xor(dsum, o);
  float inv = 1.f / (dsum + 1e-16f);
  float4 acc = {0.f, 0.f, 0.f, 0.f};
  const size_t qoff = (size_t)wq * 256 + (size_t)lane * 4;
  for (int base = 0; base < dg; base += 16) {
    int i = base + sub;
    float p = 0.f;
    int s = 0;
    if (i < dg) {
      s = esrc[r0 + i];
      p = expf(lrelu(s1s[s * 8 + myh] + sdst) - m) * inv;
    }
    int cnt = min(16, dg - base);
    for (int j = 0; j < cnt; ++j) {
      float pj = __shfl(p, j, 16);
      int sj = __shfl(s, j, 16);
      ushort4 hv = *reinterpret_cast<const ushort4*>(&hp1b[(size_t)sj * F1 + qoff]);
      acc.x += pj * bf2f(hv.x);
      acc.y += pj * bf2f(hv.y);
      acc.z += pj * bf2f(hv.z);
      acc.w += pj * bf2f(hv.w);
    }
  }
  int fbase = wq * 256 + lane * 4;
  float o0 = acc.x + b1[fbase + 0];
  float o1 = acc.y + b1[fbase + 1];
  float o2 = acc.z + b1[fbase + 2];
  float o3 = acc.w + b1[fbase + 3];
  o0 = o0 > 0.f ? o0 : (expf(o0) - 1.f);
  o1 = o1 > 0.f ? o1 : (expf(o1) - 1.f);
  o2 = o2 > 0.f ? o2 : (expf(o2) - 1.f);
  o3 = o3 > 0.f ? o3 : (expf(o3) - 1.f);
  ushort4 ov;
  ov.x = f2bf(o0); ov.y = f2bf(o1); ov.z = f2bf(o2); ov.w = f2bf(o3);
  *reinterpret_cast<ushort4*>(&h1b[(size_t)n * F1 + fbase]) = ov;
}

// ---- GEMM2 (+scores2): hp2b[N,64] = h1b[N,512] @ W2[512,64] -------------
__global__ __launch_bounds__(512) void k_gemm2(const unsigned short* __restrict__ h1b,
                                               const float* __restrict__ W2,
                                               const float* __restrict__ w2sv,
                                               const float* __restrict__ w2dv,
                                               unsigned short* __restrict__ hp2b,
                                               float* __restrict__ s2s,
                                               float* __restrict__ s2d) {
  __shared__ float h1s[8 * 512];    // 16 KB
  __shared__ float w2s[128 * 64];   // 32 KB
  __shared__ float wsv[512], wdv[512];
  wsv[threadIdx.x] = w2sv[threadIdx.x];
  wdv[threadIdx.x] = w2dv[threadIdx.x];
  int n0 = blockIdx.x * 8;  // 6250 * 8 = 50000 exact
  const ushort4* h1v = reinterpret_cast<const ushort4*>(h1b + (size_t)n0 * F1);
  for (int idx = threadIdx.x; idx < 8 * 128; idx += 512) {
    ushort4 u = h1v[idx];
    h1s[idx * 4 + 0] = bf2f(u.x);
    h1s[idx * 4 + 1] = bf2f(u.y);
    h1s[idx * 4 + 2] = bf2f(u.z);
    h1s[idx * 4 + 3] = bf2f(u.w);
  }
  int nl = threadIdx.x >> 6;
  int jj = threadIdx.x & 63;
  float acc = 0.f;
  for (int cc = 0; cc < 512; cc += 128) {
    __syncthreads();
    for (int idx = threadIdx.x; idx < 128 * 64; idx += 512) w2s[idx] = W2[cc * 64 + idx];
    __syncthreads();
#pragma unroll
    for (int c = 0; c < 128; ++c) acc += h1s[nl * 512 + cc + c] * w2s[c * 64 + jj];
  }
  hp2b[(size_t)(n0 + nl) * 64 + jj] = f2bf(acc);
  // ---- scores epilogue: wave nl handles node n0+nl
  float ss = 0.f, dd = 0.f;
  for (int c = jj; c < 512; c += 64) {
    float hv = h1s[nl * 512 + c];
    ss += hv * wsv[c];
    dd += hv * wdv[c];
  }
  ss = wred_sum(ss);
  dd = wred_sum(dd);
  if (jj == 0) { s2s[n0 + nl] = ss; s2d[n0 + nl] = dd; }
}

// ---- layer-2 softmax-aggregate + bias + pooled atomicAdd ----------------
__global__ __launch_bounds__(64) void k_agg2(const int* __restrict__ rowstart,
                                             const int* __restrict__ esrc,
                                             const unsigned short* __restrict__ hp2b,
                                             const float* __restrict__ s2s,
                                             const float* __restrict__ s2d,
                                             const float* __restrict__ b2,
                                             const int* __restrict__ batch,
                                             float* __restrict__ pooled) {
  int n = blockIdx.x;
  int lane = threadIdx.x;
  int half = lane >> 5;
  int fl = lane & 31;
  int r0 = rowstart[n], dg = rowstart[n + 1] - r0;
  float sdst = s2d[n];
  float m = -1e30f;
  for (int i = lane; i < dg; i += 64) m = fmaxf(m, lrelu(s2s[esrc[r0 + i]] + sdst));
  m = wred_max(m);
  float dsum = 0.f;
  for (int i = lane; i < dg; i += 64) dsum += expf(lrelu(s2s[esrc[r0 + i]] + sdst) - m);
  dsum = wred_sum(dsum);
  float inv = 1.f / (dsum + 1e-16f);
  float ax = 0.f, ay = 0.f;
  for (int base = 0; base < dg; base += 32) {
    int i = base + fl;
    float p = 0.f;
    int s = 0;
    if (i < dg) {
      s = esrc[r0 + i];
      p = expf(lrelu(s2s[s] + sdst) - m) * inv;
    }
    int cnt = min(32, dg - base);
    for (int j = 0; j < cnt; j += 2) {
      int jj = j + half;
      float pj = __shfl(p, jj, 32);
      int sj = __shfl(s, jj, 32);
      ushort2 hv = *reinterpret_cast<const ushort2*>(&hp2b[(size_t)sj * 64 + fl * 2]);
      ax += pj * bf2f(hv.x);
      ay += pj * bf2f(hv.y);
    }
  }
  ax += __shfl_xor(ax, 32);
  ay += __shfl_xor(ay, 32);
  int f = 2 * fl + half;
  float o = (half ? ay : ax) + b2[f];
  atomicAdd(&pooled[batch[n] * 64 + f], o);
}

// ---- final: out[512,40000] = pooled[512,64] @ Wp[64,40000] + bp ---------
// Grid: (ceil(40000/256), 8); block handles 256 vocab x 64 graphs.
__global__ __launch_bounds__(256) void k_final(const float* __restrict__ pooled,
                                               const float* __restrict__ Wp,
                                               const float* __restrict__ bp,
                                               float* __restrict__ out) {
  int v = blockIdx.x * 256 + threadIdx.x;
  bool valid = v < VOCAB_C;
  float w[64];
  float bpv = 0.f;
  if (valid) {
#pragma unroll
    for (int c = 0; c < 64; ++c) w[c] = Wp[(size_t)c * VOCAB_C + v];
    bpv = bp[v];
  }
  __shared__ float ps[64 * 64];  // 16 KB
  int g0 = blockIdx.y * 64;
  const float4* psrc = reinterpret_cast<const float4*>(pooled + (size_t)g0 * 64);
  for (int idx = threadIdx.x; idx < 1024; idx += 256)
    reinterpret_cast<float4*>(ps)[idx] = psrc[idx];
  __syncthreads();
  for (int gl = 0; gl < 64; ++gl) {
    const float4* pr4 = reinterpret_cast<const float4*>(&ps[gl * 64]);
    float acc = bpv;
#pragma unroll
    for (int c4 = 0; c4 < 16; ++c4) {
      float4 pv = pr4[c4];
      acc += pv.x * w[c4 * 4 + 0] + pv.y * w[c4 * 4 + 1] + pv.z * w[c4 * 4 + 2] + pv.w * w[c4 * 4 + 3];
    }
    if (valid) out[(size_t)(g0 + gl) * VOCAB_C + v] = acc;
  }
}

extern "C" void kernel_launch(void* const* d_in, const int* in_sizes, int n_in,
                              void* d_out, int out_size, void* d_ws, size_t ws_size,
                              hipStream_t stream) {
  const int*   x     = (const int*)d_in[0];
  const int*   ei    = (const int*)d_in[1];
  const int*   batch = (const int*)d_in[2];
  const float* emb   = (const float*)d_in[3];
  const float* W1    = (const float*)d_in[4];
  const float* as1   = (const float*)d_in[5];
  const float* ad1   = (const float*)d_in[6];
  const float* b1    = (const float*)d_in[7];
  const float* W2    = (const float*)d_in[8];
  const float* as2   = (const float*)d_in[9];
  const float* ad2   = (const float*)d_in[10];
  const float* b2    = (const float*)d_in[11];
  const float* Wp    = (const float*)d_in[12];
  const float* bp    = (const float*)d_in[13];
  float* out = (float*)d_out;

  char* ws = (char*)d_ws;
  size_t off = 0;
#define WS_ALLOC(T, name, bytes) T name = (T)(ws + off); off += (((size_t)(bytes)) + 255) & ~(size_t)255;
  WS_ALLOC(unsigned short*, hp1b, (size_t)N_NODESC * F1 * 2)
  WS_ALLOC(unsigned short*, h1b,  (size_t)N_NODESC * F1 * 2)
  WS_ALLOC(unsigned short*, hp2b, (size_t)N_NODESC * HID * 2)
  WS_ALLOC(float*, s1s,  (size_t)N_NODESC * HEADS_C * 4)
  WS_ALLOC(float*, s1d,  (size_t)N_NODESC * HEADS_C * 4)
  WS_ALLOC(float*, s2s,  (size_t)N_NODESC * 4)
  WS_ALLOC(float*, s2d,  (size_t)N_NODESC * 4)
  WS_ALLOC(float*, pooled, (size_t)N_GR * HID * 4)
  WS_ALLOC(float*, wa1s, 8 * 64 * 4)
  WS_ALLOC(float*, wa1d, 8 * 64 * 4)
  WS_ALLOC(float*, w2sv, 512 * 4)
  WS_ALLOC(float*, w2dv, 512 * 4)
  WS_ALLOC(int*,   deg,      (size_t)N_NODESC * 4)
  WS_ALLOC(int*,   rowstart, (size_t)(N_NODESC + 1) * 4)
  WS_ALLOC(int*,   cursor,   (size_t)N_NODESC * 4)
  WS_ALLOC(int*,   esrc,     (size_t)E_TOT * 4)
#undef WS_ALLOC
  (void)ws_size; (void)in_sizes; (void)n_in; (void)out_size;

  hipMemsetAsync(deg, 0, (size_t)N_NODESC * 4, stream);
  hipMemsetAsync(cursor, 0, (size_t)N_NODESC * 4, stream);
  hipMemsetAsync(pooled, 0, (size_t)N_GR * HID * 4, stream);

  int ethreads = 256, eblocks = (E_TOT + 255) / 256;
  k_deg<<<eblocks, ethreads, 0, stream>>>(ei, deg);
  k_scan<<<1, 1024, 0, stream>>>(deg, rowstart);
  k_scatter<<<eblocks, ethreads, 0, stream>>>(ei, rowstart, cursor, esrc);
  k_prep<<<1, 512, 0, stream>>>(W1, as1, ad1, W2, as2, ad2, wa1s, wa1d, w2sv, w2dv);

  k_gemm1<<<(N_NODESC + 127) / 128, 512, 0, stream>>>(x, emb, W1, wa1s, wa1d, hp1b, s1s, s1d);
  k_agg1<<<N_NODESC, 128, 0, stream>>>(rowstart, esrc, hp1b, s1s, s1d, b1, h1b);

  k_gemm2<<<N_NODESC / 8, 512, 0, stream>>>(h1b, W2, w2sv, w2dv, hp2b, s2s, s2d);
  k_agg2<<<N_NODESC, 64, 0, stream>>>(rowstart, esrc, hp2b, s2s, s2d, b2, batch, pooled);

  k_final<<<dim3((VOCAB_C + 255) / 256, 8), 256, 0, stream>>>(pooled, Wp, bp, out);
}

// Round 4
// 576.838 us; speedup vs baseline: 1.9283x; 1.1918x over previous
//
#include <hip/hip_runtime.h>
#include <hip/hip_bf16.h>

#define N_NODESC 50000
#define N_EDGESC 500000
#define E_TOT    (N_EDGESC + N_NODESC)   // 550000, with self loops
#define HID      64
#define HEADS_C  8
#define F1       (HEADS_C * HID)         // 512
#define VOCAB_C  40000
#define N_GR     512

__device__ __forceinline__ float wred_max(float v) {
#pragma unroll
  for (int o = 32; o; o >>= 1) v = fmaxf(v, __shfl_xor(v, o));
  return v;
}
__device__ __forceinline__ float wred_sum(float v) {
#pragma unroll
  for (int o = 32; o; o >>= 1) v += __shfl_xor(v, o);
  return v;
}
__device__ __forceinline__ float lrelu(float x) { return x > 0.f ? x : 0.2f * x; }
__device__ __forceinline__ float bf2f(unsigned short u) {
  return __uint_as_float(((unsigned int)u) << 16);
}
__device__ __forceinline__ unsigned short f2bf(float f) {
  unsigned int u = __float_as_uint(f);
  unsigned int r = (u + 0x7fffu + ((u >> 16) & 1u)) >> 16;
  return (unsigned short)r;
}

// ---- CSR build ----------------------------------------------------------
__global__ void k_deg(const int* __restrict__ ei, int* __restrict__ deg) {
  int e = blockIdx.x * blockDim.x + threadIdx.x;
  if (e >= E_TOT) return;
  int dst = (e < N_EDGESC) ? ei[N_EDGESC + e] : (e - N_EDGESC);
  atomicAdd(&deg[dst], 1);
}

__global__ void k_scan(const int* __restrict__ deg, int* __restrict__ rowstart) {
  __shared__ int part[1024];
  const int ITEMS = 49;  // 1024*49 = 50176 >= 50000
  int t = threadIdx.x;
  int lo = t * ITEMS, hi = min(lo + ITEMS, N_NODESC);
  int s = 0;
  for (int i = lo; i < hi; ++i) s += deg[i];
  part[t] = s;
  __syncthreads();
  for (int o = 1; o < 1024; o <<= 1) {
    int v = (t >= o) ? part[t - o] : 0;
    __syncthreads();
    part[t] += v;
    __syncthreads();
  }
  int off = part[t] - s;  // exclusive
  for (int i = lo; i < hi; ++i) { rowstart[i] = off; off += deg[i]; }
  if (t == 1023) rowstart[N_NODESC] = part[1023];
}

__global__ void k_scatter(const int* __restrict__ ei, const int* __restrict__ rowstart,
                          int* __restrict__ cursor, int* __restrict__ esrc) {
  int e = blockIdx.x * blockDim.x + threadIdx.x;
  if (e >= E_TOT) return;
  int src, dst;
  if (e < N_EDGESC) { src = ei[e]; dst = ei[N_EDGESC + e]; }
  else { src = dst = e - N_EDGESC; }
  int slot = rowstart[dst] + atomicAdd(&cursor[dst], 1);
  esrc[slot] = src;
}

// ---- prep: fold attention vectors through the weight matrices -----------
__global__ __launch_bounds__(512) void k_prep(const float* __restrict__ W1,
                                              const float* __restrict__ as1,
                                              const float* __restrict__ ad1,
                                              const float* __restrict__ W2,
                                              const float* __restrict__ as2,
                                              const float* __restrict__ ad2,
                                              float* __restrict__ wa1s, float* __restrict__ wa1d,
                                              float* __restrict__ w2sv, float* __restrict__ w2dv) {
  int t = threadIdx.x;  // 512
  int k = t >> 3, h = t & 7;
  float ss = 0.f, dd = 0.f;
  for (int c = 0; c < 64; ++c) {
    float w = W1[k * F1 + h * 64 + c];
    ss += w * as1[h * 64 + c];
    dd += w * ad1[h * 64 + c];
  }
  wa1s[h * 64 + k] = ss;
  wa1d[h * 64 + k] = dd;
  float s2 = 0.f, d2 = 0.f;
  for (int c = 0; c < 64; ++c) {
    float w = W2[t * 64 + c];
    s2 += w * as2[c];
    d2 += w * ad2[c];
  }
  w2sv[t] = s2;
  w2dv[t] = d2;
}

// ---- GEMM1 (+embed gather +scores1): hp1b = emb[x] @ W1 -----------------
__global__ __launch_bounds__(512) void k_gemm1(const int* __restrict__ x,
                                               const float* __restrict__ emb,
                                               const float* __restrict__ W1,
                                               const float* __restrict__ wa1s,
                                               const float* __restrict__ wa1d,
                                               unsigned short* __restrict__ hp1b,
                                               float* __restrict__ s1s,
                                               float* __restrict__ s1d) {
  int j = threadIdx.x;  // output column 0..511
  float w[64];
#pragma unroll
  for (int c = 0; c < 64; ++c) w[c] = W1[c * F1 + j];
  __shared__ float hs[128 * 64];  // 32 KB
  __shared__ float was[8 * 64], wad[8 * 64];
  was[j] = wa1s[j];
  wad[j] = wa1d[j];
  int n0 = blockIdx.x * 128;
  int nCnt = min(128, N_NODESC - n0);
  for (int idx = threadIdx.x; idx < nCnt * 16; idx += 512) {
    int node = idx >> 4, q = idx & 15;
    int row = x[n0 + node];
    reinterpret_cast<float4*>(hs)[idx] =
        reinterpret_cast<const float4*>(emb)[(size_t)row * 16 + q];
  }
  __syncthreads();
  for (int nl = 0; nl < nCnt; ++nl) {
    const float4* hr4 = reinterpret_cast<const float4*>(&hs[nl * 64]);
    float acc = 0.f;
#pragma unroll
    for (int c4 = 0; c4 < 16; ++c4) {
      float4 hv = hr4[c4];
      acc += hv.x * w[c4 * 4 + 0] + hv.y * w[c4 * 4 + 1] + hv.z * w[c4 * 4 + 2] + hv.w * w[c4 * 4 + 3];
    }
    hp1b[(size_t)(n0 + nl) * F1 + j] = f2bf(acc);
  }
  // ---- scores epilogue: 4 threads per node, each does 4 head-dots of 64
  int nl2 = j >> 2;
  int part = j & 3;
  if (nl2 < nCnt) {
    const float* wa = (part & 2) ? wad : was;
    int h0 = (part & 1) * 4;
    float a0 = 0.f, a1 = 0.f, a2 = 0.f, a3 = 0.f;
#pragma unroll 8
    for (int kk = 0; kk < 64; ++kk) {
      int k = (kk + nl2) & 63;
      float hv = hs[nl2 * 64 + k];
      a0 += hv * wa[(h0 + 0) * 64 + k];
      a1 += hv * wa[(h0 + 1) * 64 + k];
      a2 += hv * wa[(h0 + 2) * 64 + k];
      a3 += hv * wa[(h0 + 3) * 64 + k];
    }
    float4 st = {a0, a1, a2, a3};
    float* dst = (part & 2) ? s1d : s1s;
    reinterpret_cast<float4*>(dst)[(size_t)(n0 + nl2) * 2 + (part & 1)] = st;
  }
}

// ---- layer-1 softmax-aggregate + bias + ELU; 2 waves (head-quads) per node
__global__ __launch_bounds__(128) void k_agg1(const int* __restrict__ rowstart,
                                              const int* __restrict__ esrc,
                                              const unsigned short* __restrict__ hp1b,
                                              const float* __restrict__ s1s,
                                              const float* __restrict__ s1d,
                                              const float* __restrict__ b1,
                                              unsigned short* __restrict__ h1b) {
  int n = blockIdx.x;
  int wq = threadIdx.x >> 6;
  int lane = threadIdx.x & 63;
  int myh = wq * 4 + (lane >> 4);
  int sub = lane & 15;
  int r0 = rowstart[n], dg = rowstart[n + 1] - r0;
  float sdst = s1d[n * 8 + myh];
  float m = -1e30f;
  for (int i = sub; i < dg; i += 16)
    m = fmaxf(m, lrelu(s1s[esrc[r0 + i] * 8 + myh] + sdst));
#pragma unroll
  for (int o = 1; o < 16; o <<= 1) m = fmaxf(m, __shfl_xor(m, o));
  float dsum = 0.f;
  for (int i = sub; i < dg; i += 16)
    dsum += expf(lrelu(s1s[esrc[r0 + i] * 8 + myh] + sdst) - m);
#pragma unroll
  for (int o = 1; o < 16; o <<= 1) dsum += __shfl_xor(dsum, o);
  float inv = 1.f / (dsum + 1e-16f);
  float4 acc = {0.f, 0.f, 0.f, 0.f};
  const size_t qoff = (size_t)wq * 256 + (size_t)lane * 4;
  for (int base = 0; base < dg; base += 16) {
    int i = base + sub;
    float p = 0.f;
    int s = 0;
    if (i < dg) {
      s = esrc[r0 + i];
      p = expf(lrelu(s1s[s * 8 + myh] + sdst) - m) * inv;
    }
    int cnt = min(16, dg - base);
    for (int j = 0; j < cnt; ++j) {
      float pj = __shfl(p, j, 16);
      int sj = __shfl(s, j, 16);
      ushort4 hv = *reinterpret_cast<const ushort4*>(&hp1b[(size_t)sj * F1 + qoff]);
      acc.x += pj * bf2f(hv.x);
      acc.y += pj * bf2f(hv.y);
      acc.z += pj * bf2f(hv.z);
      acc.w += pj * bf2f(hv.w);
    }
  }
  int fbase = wq * 256 + lane * 4;
  float o0 = acc.x + b1[fbase + 0];
  float o1 = acc.y + b1[fbase + 1];
  float o2 = acc.z + b1[fbase + 2];
  float o3 = acc.w + b1[fbase + 3];
  o0 = o0 > 0.f ? o0 : (expf(o0) - 1.f);
  o1 = o1 > 0.f ? o1 : (expf(o1) - 1.f);
  o2 = o2 > 0.f ? o2 : (expf(o2) - 1.f);
  o3 = o3 > 0.f ? o3 : (expf(o3) - 1.f);
  ushort4 ov;
  ov.x = f2bf(o0); ov.y = f2bf(o1); ov.z = f2bf(o2); ov.w = f2bf(o3);
  *reinterpret_cast<ushort4*>(&h1b[(size_t)n * F1 + fbase]) = ov;
}

// ---- GEMM2 (+scores2), register-tiled -----------------------------------
// Block: 256 thr, 128 nodes, N=64, K-chunks of 64.
// LDS: h1T[64][128] f32 (k-major) + w2s[64][64] + score-reduce buf = 50 KB.
// Thread (tn=t&15, tc=t>>4) computes acc[8 nodes][4 cols].
__global__ __launch_bounds__(256) void k_gemm2(const unsigned short* __restrict__ h1b,
                                               const float* __restrict__ W2,
                                               const float* __restrict__ w2sv,
                                               const float* __restrict__ w2dv,
                                               unsigned short* __restrict__ hp2b,
                                               float* __restrict__ s2s,
                                               float* __restrict__ s2d) {
  __shared__ float h1T[64][128];   // 32 KB
  __shared__ float w2s[64][64];    // 16 KB
  __shared__ float sred_s[128], sred_d[128];  // 1 KB
  int t = threadIdx.x;
  int n0 = blockIdx.x * 128;
  int nCnt = min(128, N_NODESC - n0);
  int tn8 = (t & 15) * 8;
  int tc4 = (t >> 4) * 4;
  int sn = t & 127;          // staging node
  int kh = (t >> 7) * 32;    // staging k-half
  float acc[8][4] = {};
  float ssp = 0.f, ddp = 0.f;  // score partials for node sn over this thread's k's
  for (int cc = 0; cc < 512; cc += 64) {
    __syncthreads();
    // stage W2 chunk [64 k][64 col]
    for (int i = t; i < 1024; i += 256)
      reinterpret_cast<float4*>(&w2s[0][0])[i] =
          reinterpret_cast<const float4*>(W2 + (size_t)cc * 64)[i];
    // stage h1 chunk transposed (each thread: 64B contiguous = one cache line)
    if (sn < nCnt) {
      const size_t base = (size_t)(n0 + sn) * F1 + cc + kh;
#pragma unroll
      for (int i = 0; i < 4; ++i) {
        uint4 u = *reinterpret_cast<const uint4*>(&h1b[base + i * 8]);
        int k0 = kh + i * 8;
        float f0 = bf2f((unsigned short)(u.x & 0xffff));
        float f1 = bf2f((unsigned short)(u.x >> 16));
        float f2 = bf2f((unsigned short)(u.y & 0xffff));
        float f3 = bf2f((unsigned short)(u.y >> 16));
        float f4 = bf2f((unsigned short)(u.z & 0xffff));
        float f5 = bf2f((unsigned short)(u.z >> 16));
        float f6 = bf2f((unsigned short)(u.w & 0xffff));
        float f7 = bf2f((unsigned short)(u.w >> 16));
        h1T[k0 + 0][sn] = f0; h1T[k0 + 1][sn] = f1;
        h1T[k0 + 2][sn] = f2; h1T[k0 + 3][sn] = f3;
        h1T[k0 + 4][sn] = f4; h1T[k0 + 5][sn] = f5;
        h1T[k0 + 6][sn] = f6; h1T[k0 + 7][sn] = f7;
        int kg = cc + k0;  // wave-uniform -> scalar loads
        ssp += f0 * w2sv[kg + 0] + f1 * w2sv[kg + 1] + f2 * w2sv[kg + 2] + f3 * w2sv[kg + 3]
             + f4 * w2sv[kg + 4] + f5 * w2sv[kg + 5] + f6 * w2sv[kg + 6] + f7 * w2sv[kg + 7];
        ddp += f0 * w2dv[kg + 0] + f1 * w2dv[kg + 1] + f2 * w2dv[kg + 2] + f3 * w2dv[kg + 3]
             + f4 * w2dv[kg + 4] + f5 * w2dv[kg + 5] + f6 * w2dv[kg + 6] + f7 * w2dv[kg + 7];
      }
    }
    __syncthreads();
#pragma unroll 8
    for (int k = 0; k < 64; ++k) {
      float4 a0 = *reinterpret_cast<const float4*>(&h1T[k][tn8]);
      float4 a1 = *reinterpret_cast<const float4*>(&h1T[k][tn8 + 4]);
      float4 bv = *reinterpret_cast<const float4*>(&w2s[k][tc4]);
      float av[8] = {a0.x, a0.y, a0.z, a0.w, a1.x, a1.y, a1.z, a1.w};
      float bvv[4] = {bv.x, bv.y, bv.z, bv.w};
#pragma unroll
      for (int i = 0; i < 8; ++i)
#pragma unroll
        for (int jj = 0; jj < 4; ++jj) acc[i][jj] += av[i] * bvv[jj];
    }
  }
  // ---- scores: combine the two k-halves per node
  if (t >= 128) { sred_s[sn] = ssp; sred_d[sn] = ddp; }
  __syncthreads();
  if (t < 128 && sn < nCnt) {
    s2s[n0 + sn] = ssp + sred_s[sn];
    s2d[n0 + sn] = ddp + sred_d[sn];
  }
  // ---- write hp2b
#pragma unroll
  for (int i = 0; i < 8; ++i) {
    int node = tn8 + i;
    if (node < nCnt) {
      ushort4 ov;
      ov.x = f2bf(acc[i][0]); ov.y = f2bf(acc[i][1]);
      ov.z = f2bf(acc[i][2]); ov.w = f2bf(acc[i][3]);
      *reinterpret_cast<ushort4*>(&hp2b[(size_t)(n0 + node) * HID + tc4]) = ov;
    }
  }
}

// ---- layer-2 softmax-aggregate + bias + pooled atomicAdd ----------------
__global__ __launch_bounds__(64) void k_agg2(const int* __restrict__ rowstart,
                                             const int* __restrict__ esrc,
                                             const unsigned short* __restrict__ hp2b,
                                             const float* __restrict__ s2s,
                                             const float* __restrict__ s2d,
                                             const float* __restrict__ b2,
                                             const int* __restrict__ batch,
                                             float* __restrict__ pooled) {
  int n = blockIdx.x;
  int lane = threadIdx.x;
  int half = lane >> 5;
  int fl = lane & 31;
  int r0 = rowstart[n], dg = rowstart[n + 1] - r0;
  float sdst = s2d[n];
  float m = -1e30f;
  for (int i = lane; i < dg; i += 64) m = fmaxf(m, lrelu(s2s[esrc[r0 + i]] + sdst));
  m = wred_max(m);
  float dsum = 0.f;
  for (int i = lane; i < dg; i += 64) dsum += expf(lrelu(s2s[esrc[r0 + i]] + sdst) - m);
  dsum = wred_sum(dsum);
  float inv = 1.f / (dsum + 1e-16f);
  float ax = 0.f, ay = 0.f;
  for (int base = 0; base < dg; base += 32) {
    int i = base + fl;
    float p = 0.f;
    int s = 0;
    if (i < dg) {
      s = esrc[r0 + i];
      p = expf(lrelu(s2s[s] + sdst) - m) * inv;
    }
    int cnt = min(32, dg - base);
    for (int j = 0; j < cnt; j += 2) {
      int jj = j + half;
      float pj = __shfl(p, jj, 32);
      int sj = __shfl(s, jj, 32);
      ushort2 hv = *reinterpret_cast<const ushort2*>(&hp2b[(size_t)sj * 64 + fl * 2]);
      ax += pj * bf2f(hv.x);
      ay += pj * bf2f(hv.y);
    }
  }
  ax += __shfl_xor(ax, 32);
  ay += __shfl_xor(ay, 32);
  int f = 2 * fl + half;
  float o = (half ? ay : ax) + b2[f];
  atomicAdd(&pooled[batch[n] * 64 + f], o);
}

// ---- final: out[512,40000] = pooled[512,64] @ Wp[64,40000] + bp ---------
__global__ __launch_bounds__(256) void k_final(const float* __restrict__ pooled,
                                               const float* __restrict__ Wp,
                                               const float* __restrict__ bp,
                                               float* __restrict__ out) {
  int v = blockIdx.x * 256 + threadIdx.x;
  bool valid = v < VOCAB_C;
  float w[64];
  float bpv = 0.f;
  if (valid) {
#pragma unroll
    for (int c = 0; c < 64; ++c) w[c] = Wp[(size_t)c * VOCAB_C + v];
    bpv = bp[v];
  }
  __shared__ float ps[64 * 64];  // 16 KB
  int g0 = blockIdx.y * 64;
  const float4* psrc = reinterpret_cast<const float4*>(pooled + (size_t)g0 * 64);
  for (int idx = threadIdx.x; idx < 1024; idx += 256)
    reinterpret_cast<float4*>(ps)[idx] = psrc[idx];
  __syncthreads();
  for (int gl = 0; gl < 64; ++gl) {
    const float4* pr4 = reinterpret_cast<const float4*>(&ps[gl * 64]);
    float acc = bpv;
#pragma unroll
    for (int c4 = 0; c4 < 16; ++c4) {
      float4 pv = pr4[c4];
      acc += pv.x * w[c4 * 4 + 0] + pv.y * w[c4 * 4 + 1] + pv.z * w[c4 * 4 + 2] + pv.w * w[c4 * 4 + 3];
    }
    if (valid) out[(size_t)(g0 + gl) * VOCAB_C + v] = acc;
  }
}

extern "C" void kernel_launch(void* const* d_in, const int* in_sizes, int n_in,
                              void* d_out, int out_size, void* d_ws, size_t ws_size,
                              hipStream_t stream) {
  const int*   x     = (const int*)d_in[0];
  const int*   ei    = (const int*)d_in[1];
  const int*   batch = (const int*)d_in[2];
  const float* emb   = (const float*)d_in[3];
  const float* W1    = (const float*)d_in[4];
  const float* as1   = (const float*)d_in[5];
  const float* ad1   = (const float*)d_in[6];
  const float* b1    = (const float*)d_in[7];
  const float* W2    = (const float*)d_in[8];
  const float* as2   = (const float*)d_in[9];
  const float* ad2   = (const float*)d_in[10];
  const float* b2    = (const float*)d_in[11];
  const float* Wp    = (const float*)d_in[12];
  const float* bp    = (const float*)d_in[13];
  float* out = (float*)d_out;

  char* ws = (char*)d_ws;
  size_t off = 0;
#define WS_ALLOC(T, name, bytes) T name = (T)(ws + off); off += (((size_t)(bytes)) + 255) & ~(size_t)255;
  WS_ALLOC(unsigned short*, hp1b, (size_t)N_NODESC * F1 * 2)
  WS_ALLOC(unsigned short*, h1b,  (size_t)N_NODESC * F1 * 2)
  WS_ALLOC(unsigned short*, hp2b, (size_t)N_NODESC * HID * 2)
  WS_ALLOC(float*, s1s,  (size_t)N_NODESC * HEADS_C * 4)
  WS_ALLOC(float*, s1d,  (size_t)N_NODESC * HEADS_C * 4)
  WS_ALLOC(float*, s2s,  (size_t)N_NODESC * 4)
  WS_ALLOC(float*, s2d,  (size_t)N_NODESC * 4)
  WS_ALLOC(float*, pooled, (size_t)N_GR * HID * 4)
  WS_ALLOC(float*, wa1s, 8 * 64 * 4)
  WS_ALLOC(float*, wa1d, 8 * 64 * 4)
  WS_ALLOC(float*, w2sv, 512 * 4)
  WS_ALLOC(float*, w2dv, 512 * 4)
  WS_ALLOC(int*,   deg,      (size_t)N_NODESC * 4)
  WS_ALLOC(int*,   rowstart, (size_t)(N_NODESC + 1) * 4)
  WS_ALLOC(int*,   cursor,   (size_t)N_NODESC * 4)
  WS_ALLOC(int*,   esrc,     (size_t)E_TOT * 4)
#undef WS_ALLOC
  (void)ws_size; (void)in_sizes; (void)n_in; (void)out_size;

  hipMemsetAsync(deg, 0, (size_t)N_NODESC * 4, stream);
  hipMemsetAsync(cursor, 0, (size_t)N_NODESC * 4, stream);
  hipMemsetAsync(pooled, 0, (size_t)N_GR * HID * 4, stream);

  int ethreads = 256, eblocks = (E_TOT + 255) / 256;
  k_deg<<<eblocks, ethreads, 0, stream>>>(ei, deg);
  k_scan<<<1, 1024, 0, stream>>>(deg, rowstart);
  k_scatter<<<eblocks, ethreads, 0, stream>>>(ei, rowstart, cursor, esrc);
  k_prep<<<1, 512, 0, stream>>>(W1, as1, ad1, W2, as2, ad2, wa1s, wa1d, w2sv, w2dv);

  k_gemm1<<<(N_NODESC + 127) / 128, 512, 0, stream>>>(x, emb, W1, wa1s, wa1d, hp1b, s1s, s1d);
  k_agg1<<<N_NODESC, 128, 0, stream>>>(rowstart, esrc, hp1b, s1s, s1d, b1, h1b);

  k_gemm2<<<(N_NODESC + 127) / 128, 256, 0, stream>>>(h1b, W2, w2sv, w2dv, hp2b, s2s, s2d);
  k_agg2<<<N_NODESC, 64, 0, stream>>>(rowstart, esrc, hp2b, s2s, s2d, b2, batch, pooled);

  k_final<<<dim3((VOCAB_C + 255) / 256, 8), 256, 0, stream>>>(pooled, Wp, bp, out);
}

// Round 5
// 501.097 us; speedup vs baseline: 2.2198x; 1.1511x over previous
//
#include <hip/hip_runtime.h>
#include <hip/hip_bf16.h>

#define N_NODESC 50000
#define N_EDGESC 500000
#define E_TOT    (N_EDGESC + N_NODESC)   // 550000, with self loops
#define HID      64
#define HEADS_C  8
#define F1       (HEADS_C * HID)         // 512
#define VOCAB_C  40000
#define N_GR     512

__device__ __forceinline__ float wred_max(float v) {
#pragma unroll
  for (int o = 32; o; o >>= 1) v = fmaxf(v, __shfl_xor(v, o));
  return v;
}
__device__ __forceinline__ float wred_sum(float v) {
#pragma unroll
  for (int o = 32; o; o >>= 1) v += __shfl_xor(v, o);
  return v;
}
__device__ __forceinline__ float lrelu(float x) { return x > 0.f ? x : 0.2f * x; }
__device__ __forceinline__ float bf2f(unsigned short u) {
  return __uint_as_float(((unsigned int)u) << 16);
}
__device__ __forceinline__ unsigned short f2bf(float f) {
  unsigned int u = __float_as_uint(f);
  unsigned int r = (u + 0x7fffu + ((u >> 16) & 1u)) >> 16;
  return (unsigned short)r;
}

// ---- CSR build ----------------------------------------------------------
__global__ void k_deg(const int* __restrict__ ei, int* __restrict__ deg) {
  int e = blockIdx.x * blockDim.x + threadIdx.x;
  if (e >= E_TOT) return;
  int dst = (e < N_EDGESC) ? ei[N_EDGESC + e] : (e - N_EDGESC);
  atomicAdd(&deg[dst], 1);
}

__global__ void k_scan(const int* __restrict__ deg, int* __restrict__ rowstart) {
  __shared__ int part[1024];
  const int ITEMS = 49;  // 1024*49 = 50176 >= 50000
  int t = threadIdx.x;
  int lo = t * ITEMS, hi = min(lo + ITEMS, N_NODESC);
  int s = 0;
  for (int i = lo; i < hi; ++i) s += deg[i];
  part[t] = s;
  __syncthreads();
  for (int o = 1; o < 1024; o <<= 1) {
    int v = (t >= o) ? part[t - o] : 0;
    __syncthreads();
    part[t] += v;
    __syncthreads();
  }
  int off = part[t] - s;  // exclusive
  for (int i = lo; i < hi; ++i) { rowstart[i] = off; off += deg[i]; }
  if (t == 1023) rowstart[N_NODESC] = part[1023];
}

__global__ void k_scatter(const int* __restrict__ ei, const int* __restrict__ rowstart,
                          int* __restrict__ cursor, int* __restrict__ esrc) {
  int e = blockIdx.x * blockDim.x + threadIdx.x;
  if (e >= E_TOT) return;
  int src, dst;
  if (e < N_EDGESC) { src = ei[e]; dst = ei[N_EDGESC + e]; }
  else { src = dst = e - N_EDGESC; }
  int slot = rowstart[dst] + atomicAdd(&cursor[dst], 1);
  esrc[slot] = src;
}

// ---- prep: fold attention vectors through the weight matrices -----------
__global__ __launch_bounds__(512) void k_prep(const float* __restrict__ W1,
                                              const float* __restrict__ as1,
                                              const float* __restrict__ ad1,
                                              const float* __restrict__ W2,
                                              const float* __restrict__ as2,
                                              const float* __restrict__ ad2,
                                              float* __restrict__ wa1s, float* __restrict__ wa1d,
                                              float* __restrict__ w2sv, float* __restrict__ w2dv) {
  int t = threadIdx.x;  // 512
  int k = t >> 3, h = t & 7;
  float ss = 0.f, dd = 0.f;
  for (int c = 0; c < 64; ++c) {
    float w = W1[k * F1 + h * 64 + c];
    ss += w * as1[h * 64 + c];
    dd += w * ad1[h * 64 + c];
  }
  wa1s[h * 64 + k] = ss;
  wa1d[h * 64 + k] = dd;
  float s2 = 0.f, d2 = 0.f;
  for (int c = 0; c < 64; ++c) {
    float w = W2[t * 64 + c];
    s2 += w * as2[c];
    d2 += w * ad2[c];
  }
  w2sv[t] = s2;
  w2dv[t] = d2;
}

// ---- GEMM1 (+embed gather +scores1), register-tiled ---------------------
// Block: 256 thr, 64 nodes, cols in 4 chunks of 128, K=64.
// LDS: hT[64 k][64 n] + w1s[64][128] + was/wad = 52 KB -> 3 blocks/CU.
__global__ __launch_bounds__(256) void k_gemm1(const int* __restrict__ x,
                                               const float* __restrict__ emb,
                                               const float* __restrict__ W1,
                                               const float* __restrict__ wa1s,
                                               const float* __restrict__ wa1d,
                                               unsigned short* __restrict__ hp1b,
                                               float* __restrict__ s1s,
                                               float* __restrict__ s1d) {
  __shared__ float hT[64][64];     // 16 KB, [k][node]
  __shared__ float w1s[64][128];   // 32 KB
  __shared__ float was[512], wad[512];  // 4 KB
  int t = threadIdx.x;
  int n0 = blockIdx.x * 64;
  int nCnt = min(64, N_NODESC - n0);
  was[t] = wa1s[t]; was[t + 256] = wa1s[t + 256];
  wad[t] = wa1d[t]; wad[t + 256] = wa1d[t + 256];
  // stage h transposed: thread (sn = t&63, kq = (t>>6)*16) loads 64B contiguous
  int sn = t & 63, kq = (t >> 6) * 16;
  if (sn < nCnt) {
    int row = x[n0 + sn];
    const float4* er = reinterpret_cast<const float4*>(emb + (size_t)row * 64 + kq);
#pragma unroll
    for (int i = 0; i < 4; ++i) {
      float4 v = er[i];
      hT[kq + i * 4 + 0][sn] = v.x;
      hT[kq + i * 4 + 1][sn] = v.y;
      hT[kq + i * 4 + 2][sn] = v.z;
      hT[kq + i * 4 + 3][sn] = v.w;
    }
  } else {
#pragma unroll
    for (int i = 0; i < 16; ++i) hT[kq + i][sn] = 0.f;
  }
  __syncthreads();
  // ---- scores epilogue: wave = part (bit0: head-half, bit1: src/dst), lane = node
  {
    int node = t & 63;
    int part = t >> 6;
    const float* wa = (part & 2) ? wad : was;
    int h0 = (part & 1) * 4;
    float a0 = 0.f, a1 = 0.f, a2 = 0.f, a3 = 0.f;
#pragma unroll 8
    for (int k = 0; k < 64; ++k) {
      float hv = hT[k][node];
      a0 += hv * wa[(h0 + 0) * 64 + k];
      a1 += hv * wa[(h0 + 1) * 64 + k];
      a2 += hv * wa[(h0 + 2) * 64 + k];
      a3 += hv * wa[(h0 + 3) * 64 + k];
    }
    if (node < nCnt) {
      float4 st = {a0, a1, a2, a3};
      float* dstp = (part & 2) ? s1d : s1s;
      reinterpret_cast<float4*>(dstp)[(size_t)(n0 + node) * 2 + (part & 1)] = st;
    }
  }
  // ---- main GEMM: col-chunks of 128
  int cg = t & 31;   // col group: 4 cols
  int ng = t >> 5;   // node group: 8 nodes
  for (int cc = 0; cc < 512; cc += 128) {
    __syncthreads();
    for (int idx = t; idx < 64 * 32; idx += 256) {
      int k = idx >> 5, c4 = idx & 31;
      reinterpret_cast<float4*>(&w1s[k][0])[c4] =
          *reinterpret_cast<const float4*>(&W1[(size_t)k * F1 + cc + c4 * 4]);
    }
    __syncthreads();
    float acc[8][4] = {};
#pragma unroll 4
    for (int k = 0; k < 64; ++k) {
      float4 b = *reinterpret_cast<const float4*>(&w1s[k][cg * 4]);
      float4 a0 = *reinterpret_cast<const float4*>(&hT[k][ng * 8]);
      float4 a1 = *reinterpret_cast<const float4*>(&hT[k][ng * 8 + 4]);
      float av[8] = {a0.x, a0.y, a0.z, a0.w, a1.x, a1.y, a1.z, a1.w};
#pragma unroll
      for (int i = 0; i < 8; ++i) {
        acc[i][0] += av[i] * b.x;
        acc[i][1] += av[i] * b.y;
        acc[i][2] += av[i] * b.z;
        acc[i][3] += av[i] * b.w;
      }
    }
#pragma unroll
    for (int i = 0; i < 8; ++i) {
      int node = ng * 8 + i;
      if (node < nCnt) {
        ushort4 ov;
        ov.x = f2bf(acc[i][0]); ov.y = f2bf(acc[i][1]);
        ov.z = f2bf(acc[i][2]); ov.w = f2bf(acc[i][3]);
        *reinterpret_cast<ushort4*>(&hp1b[(size_t)(n0 + node) * F1 + cc + cg * 4]) = ov;
      }
    }
  }
}

// ---- layer-1 softmax-aggregate + bias + ELU; 2 waves (head-quads) per node
__global__ __launch_bounds__(128) void k_agg1(const int* __restrict__ rowstart,
                                              const int* __restrict__ esrc,
                                              const unsigned short* __restrict__ hp1b,
                                              const float* __restrict__ s1s,
                                              const float* __restrict__ s1d,
                                              const float* __restrict__ b1,
                                              unsigned short* __restrict__ h1b) {
  int n = blockIdx.x;
  int wq = threadIdx.x >> 6;
  int lane = threadIdx.x & 63;
  int myh = wq * 4 + (lane >> 4);
  int sub = lane & 15;
  int r0 = rowstart[n], dg = rowstart[n + 1] - r0;
  float sdst = s1d[n * 8 + myh];
  float m = -1e30f;
  for (int i = sub; i < dg; i += 16)
    m = fmaxf(m, lrelu(s1s[esrc[r0 + i] * 8 + myh] + sdst));
#pragma unroll
  for (int o = 1; o < 16; o <<= 1) m = fmaxf(m, __shfl_xor(m, o));
  float dsum = 0.f;
  for (int i = sub; i < dg; i += 16)
    dsum += expf(lrelu(s1s[esrc[r0 + i] * 8 + myh] + sdst) - m);
#pragma unroll
  for (int o = 1; o < 16; o <<= 1) dsum += __shfl_xor(dsum, o);
  float inv = 1.f / (dsum + 1e-16f);
  float4 acc = {0.f, 0.f, 0.f, 0.f};
  const size_t qoff = (size_t)wq * 256 + (size_t)lane * 4;
  for (int base = 0; base < dg; base += 16) {
    int i = base + sub;
    float p = 0.f;
    int s = 0;
    if (i < dg) {
      s = esrc[r0 + i];
      p = expf(lrelu(s1s[s * 8 + myh] + sdst) - m) * inv;
    }
    int cnt = min(16, dg - base);
    for (int j = 0; j < cnt; ++j) {
      float pj = __shfl(p, j, 16);
      int sj = __shfl(s, j, 16);
      ushort4 hv = *reinterpret_cast<const ushort4*>(&hp1b[(size_t)sj * F1 + qoff]);
      acc.x += pj * bf2f(hv.x);
      acc.y += pj * bf2f(hv.y);
      acc.z += pj * bf2f(hv.z);
      acc.w += pj * bf2f(hv.w);
    }
  }
  int fbase = wq * 256 + lane * 4;
  float o0 = acc.x + b1[fbase + 0];
  float o1 = acc.y + b1[fbase + 1];
  float o2 = acc.z + b1[fbase + 2];
  float o3 = acc.w + b1[fbase + 3];
  o0 = o0 > 0.f ? o0 : (expf(o0) - 1.f);
  o1 = o1 > 0.f ? o1 : (expf(o1) - 1.f);
  o2 = o2 > 0.f ? o2 : (expf(o2) - 1.f);
  o3 = o3 > 0.f ? o3 : (expf(o3) - 1.f);
  ushort4 ov;
  ov.x = f2bf(o0); ov.y = f2bf(o1); ov.z = f2bf(o2); ov.w = f2bf(o3);
  *reinterpret_cast<ushort4*>(&h1b[(size_t)n * F1 + fbase]) = ov;
}

// ---- GEMM2 (+scores2), register-tiled -----------------------------------
__global__ __launch_bounds__(256) void k_gemm2(const unsigned short* __restrict__ h1b,
                                               const float* __restrict__ W2,
                                               const float* __restrict__ w2sv,
                                               const float* __restrict__ w2dv,
                                               unsigned short* __restrict__ hp2b,
                                               float* __restrict__ s2s,
                                               float* __restrict__ s2d) {
  __shared__ float h1T[64][128];   // 32 KB
  __shared__ float w2s[64][64];    // 16 KB
  __shared__ float sred_s[128], sred_d[128];  // 1 KB
  int t = threadIdx.x;
  int n0 = blockIdx.x * 128;
  int nCnt = min(128, N_NODESC - n0);
  int tn8 = (t & 15) * 8;
  int tc4 = (t >> 4) * 4;
  int sn = t & 127;          // staging node
  int kh = (t >> 7) * 32;    // staging k-half
  float acc[8][4] = {};
  float ssp = 0.f, ddp = 0.f;
  for (int cc = 0; cc < 512; cc += 64) {
    __syncthreads();
    for (int i = t; i < 1024; i += 256)
      reinterpret_cast<float4*>(&w2s[0][0])[i] =
          reinterpret_cast<const float4*>(W2 + (size_t)cc * 64)[i];
    if (sn < nCnt) {
      const size_t base = (size_t)(n0 + sn) * F1 + cc + kh;
#pragma unroll
      for (int i = 0; i < 4; ++i) {
        uint4 u = *reinterpret_cast<const uint4*>(&h1b[base + i * 8]);
        int k0 = kh + i * 8;
        float f0 = bf2f((unsigned short)(u.x & 0xffff));
        float f1 = bf2f((unsigned short)(u.x >> 16));
        float f2 = bf2f((unsigned short)(u.y & 0xffff));
        float f3 = bf2f((unsigned short)(u.y >> 16));
        float f4 = bf2f((unsigned short)(u.z & 0xffff));
        float f5 = bf2f((unsigned short)(u.z >> 16));
        float f6 = bf2f((unsigned short)(u.w & 0xffff));
        float f7 = bf2f((unsigned short)(u.w >> 16));
        h1T[k0 + 0][sn] = f0; h1T[k0 + 1][sn] = f1;
        h1T[k0 + 2][sn] = f2; h1T[k0 + 3][sn] = f3;
        h1T[k0 + 4][sn] = f4; h1T[k0 + 5][sn] = f5;
        h1T[k0 + 6][sn] = f6; h1T[k0 + 7][sn] = f7;
        int kg = cc + k0;
        ssp += f0 * w2sv[kg + 0] + f1 * w2sv[kg + 1] + f2 * w2sv[kg + 2] + f3 * w2sv[kg + 3]
             + f4 * w2sv[kg + 4] + f5 * w2sv[kg + 5] + f6 * w2sv[kg + 6] + f7 * w2sv[kg + 7];
        ddp += f0 * w2dv[kg + 0] + f1 * w2dv[kg + 1] + f2 * w2dv[kg + 2] + f3 * w2dv[kg + 3]
             + f4 * w2dv[kg + 4] + f5 * w2dv[kg + 5] + f6 * w2dv[kg + 6] + f7 * w2dv[kg + 7];
      }
    }
    __syncthreads();
#pragma unroll 8
    for (int k = 0; k < 64; ++k) {
      float4 a0 = *reinterpret_cast<const float4*>(&h1T[k][tn8]);
      float4 a1 = *reinterpret_cast<const float4*>(&h1T[k][tn8 + 4]);
      float4 bv = *reinterpret_cast<const float4*>(&w2s[k][tc4]);
      float av[8] = {a0.x, a0.y, a0.z, a0.w, a1.x, a1.y, a1.z, a1.w};
      float bvv[4] = {bv.x, bv.y, bv.z, bv.w};
#pragma unroll
      for (int i = 0; i < 8; ++i)
#pragma unroll
        for (int jj = 0; jj < 4; ++jj) acc[i][jj] += av[i] * bvv[jj];
    }
  }
  if (t >= 128) { sred_s[sn] = ssp; sred_d[sn] = ddp; }
  __syncthreads();
  if (t < 128 && sn < nCnt) {
    s2s[n0 + sn] = ssp + sred_s[sn];
    s2d[n0 + sn] = ddp + sred_d[sn];
  }
#pragma unroll
  for (int i = 0; i < 8; ++i) {
    int node = tn8 + i;
    if (node < nCnt) {
      ushort4 ov;
      ov.x = f2bf(acc[i][0]); ov.y = f2bf(acc[i][1]);
      ov.z = f2bf(acc[i][2]); ov.w = f2bf(acc[i][3]);
      *reinterpret_cast<ushort4*>(&hp2b[(size_t)(n0 + node) * HID + tc4]) = ov;
    }
  }
}

// ---- layer-2 softmax-aggregate + bias + pooled atomicAdd ----------------
__global__ __launch_bounds__(64) void k_agg2(const int* __restrict__ rowstart,
                                             const int* __restrict__ esrc,
                                             const unsigned short* __restrict__ hp2b,
                                             const float* __restrict__ s2s,
                                             const float* __restrict__ s2d,
                                             const float* __restrict__ b2,
                                             const int* __restrict__ batch,
                                             float* __restrict__ pooled) {
  int n = blockIdx.x;
  int lane = threadIdx.x;
  int half = lane >> 5;
  int fl = lane & 31;
  int r0 = rowstart[n], dg = rowstart[n + 1] - r0;
  float sdst = s2d[n];
  float m = -1e30f;
  for (int i = lane; i < dg; i += 64) m = fmaxf(m, lrelu(s2s[esrc[r0 + i]] + sdst));
  m = wred_max(m);
  float dsum = 0.f;
  for (int i = lane; i < dg; i += 64) dsum += expf(lrelu(s2s[esrc[r0 + i]] + sdst) - m);
  dsum = wred_sum(dsum);
  float inv = 1.f / (dsum + 1e-16f);
  float ax = 0.f, ay = 0.f;
  for (int base = 0; base < dg; base += 32) {
    int i = base + fl;
    float p = 0.f;
    int s = 0;
    if (i < dg) {
      s = esrc[r0 + i];
      p = expf(lrelu(s2s[s] + sdst) - m) * inv;
    }
    int cnt = min(32, dg - base);
    for (int j = 0; j < cnt; j += 2) {
      int jj = j + half;
      float pj = __shfl(p, jj, 32);
      int sj = __shfl(s, jj, 32);
      ushort2 hv = *reinterpret_cast<const ushort2*>(&hp2b[(size_t)sj * 64 + fl * 2]);
      ax += pj * bf2f(hv.x);
      ay += pj * bf2f(hv.y);
    }
  }
  ax += __shfl_xor(ax, 32);
  ay += __shfl_xor(ay, 32);
  int f = 2 * fl + half;
  float o = (half ? ay : ax) + b2[f];
  atomicAdd(&pooled[batch[n] * 64 + f], o);
}

// ---- final: out[512,40000] = pooled[512,64] @ Wp[64,40000] + bp ---------
__global__ __launch_bounds__(256) void k_final(const float* __restrict__ pooled,
                                               const float* __restrict__ Wp,
                                               const float* __restrict__ bp,
                                               float* __restrict__ out) {
  int v = blockIdx.x * 256 + threadIdx.x;
  bool valid = v < VOCAB_C;
  float w[64];
  float bpv = 0.f;
  if (valid) {
#pragma unroll
    for (int c = 0; c < 64; ++c) w[c] = Wp[(size_t)c * VOCAB_C + v];
    bpv = bp[v];
  }
  __shared__ float ps[64 * 64];  // 16 KB
  int g0 = blockIdx.y * 64;
  const float4* psrc = reinterpret_cast<const float4*>(pooled + (size_t)g0 * 64);
  for (int idx = threadIdx.x; idx < 1024; idx += 256)
    reinterpret_cast<float4*>(ps)[idx] = psrc[idx];
  __syncthreads();
  for (int gl = 0; gl < 64; ++gl) {
    const float4* pr4 = reinterpret_cast<const float4*>(&ps[gl * 64]);
    float acc = bpv;
#pragma unroll
    for (int c4 = 0; c4 < 16; ++c4) {
      float4 pv = pr4[c4];
      acc += pv.x * w[c4 * 4 + 0] + pv.y * w[c4 * 4 + 1] + pv.z * w[c4 * 4 + 2] + pv.w * w[c4 * 4 + 3];
    }
    if (valid) out[(size_t)(g0 + gl) * VOCAB_C + v] = acc;
  }
}

extern "C" void kernel_launch(void* const* d_in, const int* in_sizes, int n_in,
                              void* d_out, int out_size, void* d_ws, size_t ws_size,
                              hipStream_t stream) {
  const int*   x     = (const int*)d_in[0];
  const int*   ei    = (const int*)d_in[1];
  const int*   batch = (const int*)d_in[2];
  const float* emb   = (const float*)d_in[3];
  const float* W1    = (const float*)d_in[4];
  const float* as1   = (const float*)d_in[5];
  const float* ad1   = (const float*)d_in[6];
  const float* b1    = (const float*)d_in[7];
  const float* W2    = (const float*)d_in[8];
  const float* as2   = (const float*)d_in[9];
  const float* ad2   = (const float*)d_in[10];
  const float* b2    = (const float*)d_in[11];
  const float* Wp    = (const float*)d_in[12];
  const float* bp    = (const float*)d_in[13];
  float* out = (float*)d_out;

  char* ws = (char*)d_ws;
  size_t off = 0;
#define WS_ALLOC(T, name, bytes) T name = (T)(ws + off); off += (((size_t)(bytes)) + 255) & ~(size_t)255;
  WS_ALLOC(unsigned short*, hp1b, (size_t)N_NODESC * F1 * 2)
  WS_ALLOC(unsigned short*, h1b,  (size_t)N_NODESC * F1 * 2)
  WS_ALLOC(unsigned short*, hp2b, (size_t)N_NODESC * HID * 2)
  WS_ALLOC(float*, s1s,  (size_t)N_NODESC * HEADS_C * 4)
  WS_ALLOC(float*, s1d,  (size_t)N_NODESC * HEADS_C * 4)
  WS_ALLOC(float*, s2s,  (size_t)N_NODESC * 4)
  WS_ALLOC(float*, s2d,  (size_t)N_NODESC * 4)
  WS_ALLOC(float*, pooled, (size_t)N_GR * HID * 4)
  WS_ALLOC(float*, wa1s, 8 * 64 * 4)
  WS_ALLOC(float*, wa1d, 8 * 64 * 4)
  WS_ALLOC(float*, w2sv, 512 * 4)
  WS_ALLOC(float*, w2dv, 512 * 4)
  WS_ALLOC(int*,   deg,      (size_t)N_NODESC * 4)
  WS_ALLOC(int*,   rowstart, (size_t)(N_NODESC + 1) * 4)
  WS_ALLOC(int*,   cursor,   (size_t)N_NODESC * 4)
  WS_ALLOC(int*,   esrc,     (size_t)E_TOT * 4)
#undef WS_ALLOC
  (void)ws_size; (void)in_sizes; (void)n_in; (void)out_size;

  hipMemsetAsync(deg, 0, (size_t)N_NODESC * 4, stream);
  hipMemsetAsync(cursor, 0, (size_t)N_NODESC * 4, stream);
  hipMemsetAsync(pooled, 0, (size_t)N_GR * HID * 4, stream);

  int ethreads = 256, eblocks = (E_TOT + 255) / 256;
  k_deg<<<eblocks, ethreads, 0, stream>>>(ei, deg);
  k_scan<<<1, 1024, 0, stream>>>(deg, rowstart);
  k_scatter<<<eblocks, ethreads, 0, stream>>>(ei, rowstart, cursor, esrc);
  k_prep<<<1, 512, 0, stream>>>(W1, as1, ad1, W2, as2, ad2, wa1s, wa1d, w2sv, w2dv);

  k_gemm1<<<(N_NODESC + 63) / 64, 256, 0, stream>>>(x, emb, W1, wa1s, wa1d, hp1b, s1s, s1d);
  k_agg1<<<N_NODESC, 128, 0, stream>>>(rowstart, esrc, hp1b, s1s, s1d, b1, h1b);

  k_gemm2<<<(N_NODESC + 127) / 128, 256, 0, stream>>>(h1b, W2, w2sv, w2dv, hp2b, s2s, s2d);
  k_agg2<<<N_NODESC, 64, 0, stream>>>(rowstart, esrc, hp2b, s2s, s2d, b2, batch, pooled);

  k_final<<<dim3((VOCAB_C + 255) / 256, 8), 256, 0, stream>>>(pooled, Wp, bp, out);
}

// Round 6
// 479.401 us; speedup vs baseline: 2.3203x; 1.0453x over previous
//
#include <hip/hip_runtime.h>
#include <hip/hip_bf16.h>

#define N_NODESC 50000
#define N_EDGESC 500000
#define E_TOT    (N_EDGESC + N_NODESC)   // 550000, with self loops
#define HID      64
#define HEADS_C  8
#define F1       (HEADS_C * HID)         // 512
#define VOCAB_C  40000
#define N_GR     512

__device__ __forceinline__ float wred_sum(float v) {
#pragma unroll
  for (int o = 32; o; o >>= 1) v += __shfl_xor(v, o);
  return v;
}
__device__ __forceinline__ float lrelu(float x) { return x > 0.f ? x : 0.2f * x; }
__device__ __forceinline__ float bf2f(unsigned short u) {
  return __uint_as_float(((unsigned int)u) << 16);
}
__device__ __forceinline__ unsigned short f2bf(float f) {
  unsigned int u = __float_as_uint(f);
  unsigned int r = (u + 0x7fffu + ((u >> 16) & 1u)) >> 16;
  return (unsigned short)r;
}

// ---- CSR build ----------------------------------------------------------
__global__ void k_deg(const int* __restrict__ ei, int* __restrict__ deg) {
  int e = blockIdx.x * blockDim.x + threadIdx.x;
  if (e >= E_TOT) return;
  int dst = (e < N_EDGESC) ? ei[N_EDGESC + e] : (e - N_EDGESC);
  atomicAdd(&deg[dst], 1);
}

__global__ void k_scan(const int* __restrict__ deg, int* __restrict__ rowstart) {
  __shared__ int part[1024];
  const int ITEMS = 49;  // 1024*49 = 50176 >= 50000
  int t = threadIdx.x;
  int lo = t * ITEMS, hi = min(lo + ITEMS, N_NODESC);
  int s = 0;
  for (int i = lo; i < hi; ++i) s += deg[i];
  part[t] = s;
  __syncthreads();
  for (int o = 1; o < 1024; o <<= 1) {
    int v = (t >= o) ? part[t - o] : 0;
    __syncthreads();
    part[t] += v;
    __syncthreads();
  }
  int off = part[t] - s;  // exclusive
  for (int i = lo; i < hi; ++i) { rowstart[i] = off; off += deg[i]; }
  if (t == 1023) rowstart[N_NODESC] = part[1023];
}

__global__ void k_scatter(const int* __restrict__ ei, const int* __restrict__ rowstart,
                          int* __restrict__ cursor, int* __restrict__ esrc) {
  int e = blockIdx.x * blockDim.x + threadIdx.x;
  if (e >= E_TOT) return;
  int src, dst;
  if (e < N_EDGESC) { src = ei[e]; dst = ei[N_EDGESC + e]; }
  else { src = dst = e - N_EDGESC; }
  int slot = rowstart[dst] + atomicAdd(&cursor[dst], 1);
  esrc[slot] = src;
}

// ---- prep: fold attention vectors through the weight matrices -----------
__global__ __launch_bounds__(512) void k_prep(const float* __restrict__ W1,
                                              const float* __restrict__ as1,
                                              const float* __restrict__ ad1,
                                              const float* __restrict__ W2,
                                              const float* __restrict__ as2,
                                              const float* __restrict__ ad2,
                                              float* __restrict__ wa1s, float* __restrict__ wa1d,
                                              float* __restrict__ w2sv, float* __restrict__ w2dv) {
  int t = threadIdx.x;  // 512
  int k = t >> 3, h = t & 7;
  float ss = 0.f, dd = 0.f;
  for (int c = 0; c < 64; ++c) {
    float w = W1[k * F1 + h * 64 + c];
    ss += w * as1[h * 64 + c];
    dd += w * ad1[h * 64 + c];
  }
  wa1s[h * 64 + k] = ss;
  wa1d[h * 64 + k] = dd;
  float s2 = 0.f, d2 = 0.f;
  for (int c = 0; c < 64; ++c) {
    float w = W2[t * 64 + c];
    s2 += w * as2[c];
    d2 += w * ad2[c];
  }
  w2sv[t] = s2;
  w2dv[t] = d2;
}

// ---- GEMM1 (+embed gather +scores1), register-tiled ---------------------
__global__ __launch_bounds__(256) void k_gemm1(const int* __restrict__ x,
                                               const float* __restrict__ emb,
                                               const float* __restrict__ W1,
                                               const float* __restrict__ wa1s,
                                               const float* __restrict__ wa1d,
                                               unsigned short* __restrict__ hp1b,
                                               float* __restrict__ s1s,
                                               float* __restrict__ s1d) {
  __shared__ float hT[64][64];     // 16 KB, [k][node]
  __shared__ float w1s[64][128];   // 32 KB
  __shared__ float was[512], wad[512];  // 4 KB
  int t = threadIdx.x;
  int n0 = blockIdx.x * 64;
  int nCnt = min(64, N_NODESC - n0);
  was[t] = wa1s[t]; was[t + 256] = wa1s[t + 256];
  wad[t] = wa1d[t]; wad[t + 256] = wa1d[t + 256];
  int sn = t & 63, kq = (t >> 6) * 16;
  if (sn < nCnt) {
    int row = x[n0 + sn];
    const float4* er = reinterpret_cast<const float4*>(emb + (size_t)row * 64 + kq);
#pragma unroll
    for (int i = 0; i < 4; ++i) {
      float4 v = er[i];
      hT[kq + i * 4 + 0][sn] = v.x;
      hT[kq + i * 4 + 1][sn] = v.y;
      hT[kq + i * 4 + 2][sn] = v.z;
      hT[kq + i * 4 + 3][sn] = v.w;
    }
  } else {
#pragma unroll
    for (int i = 0; i < 16; ++i) hT[kq + i][sn] = 0.f;
  }
  __syncthreads();
  {
    int node = t & 63;
    int part = t >> 6;
    const float* wa = (part & 2) ? wad : was;
    int h0 = (part & 1) * 4;
    float a0 = 0.f, a1 = 0.f, a2 = 0.f, a3 = 0.f;
#pragma unroll 8
    for (int k = 0; k < 64; ++k) {
      float hv = hT[k][node];
      a0 += hv * wa[(h0 + 0) * 64 + k];
      a1 += hv * wa[(h0 + 1) * 64 + k];
      a2 += hv * wa[(h0 + 2) * 64 + k];
      a3 += hv * wa[(h0 + 3) * 64 + k];
    }
    if (node < nCnt) {
      float4 st = {a0, a1, a2, a3};
      float* dstp = (part & 2) ? s1d : s1s;
      reinterpret_cast<float4*>(dstp)[(size_t)(n0 + node) * 2 + (part & 1)] = st;
    }
  }
  int cg = t & 31;   // col group: 4 cols
  int ng = t >> 5;   // node group: 8 nodes
  for (int cc = 0; cc < 512; cc += 128) {
    __syncthreads();
    for (int idx = t; idx < 64 * 32; idx += 256) {
      int k = idx >> 5, c4 = idx & 31;
      reinterpret_cast<float4*>(&w1s[k][0])[c4] =
          *reinterpret_cast<const float4*>(&W1[(size_t)k * F1 + cc + c4 * 4]);
    }
    __syncthreads();
    float acc[8][4] = {};
#pragma unroll 4
    for (int k = 0; k < 64; ++k) {
      float4 b = *reinterpret_cast<const float4*>(&w1s[k][cg * 4]);
      float4 a0 = *reinterpret_cast<const float4*>(&hT[k][ng * 8]);
      float4 a1 = *reinterpret_cast<const float4*>(&hT[k][ng * 8 + 4]);
      float av[8] = {a0.x, a0.y, a0.z, a0.w, a1.x, a1.y, a1.z, a1.w};
#pragma unroll
      for (int i = 0; i < 8; ++i) {
        acc[i][0] += av[i] * b.x;
        acc[i][1] += av[i] * b.y;
        acc[i][2] += av[i] * b.z;
        acc[i][3] += av[i] * b.w;
      }
    }
#pragma unroll
    for (int i = 0; i < 8; ++i) {
      int node = ng * 8 + i;
      if (node < nCnt) {
        ushort4 ov;
        ov.x = f2bf(acc[i][0]); ov.y = f2bf(acc[i][1]);
        ov.z = f2bf(acc[i][2]); ov.w = f2bf(acc[i][3]);
        *reinterpret_cast<ushort4*>(&hp1b[(size_t)(n0 + node) * F1 + cc + cg * 4]) = ov;
      }
    }
  }
}

// ---- layer-1 aggregate: SINGLE PASS unnormalized softmax ----------------
// exp(l-m)/sum(exp(l-m)) == exp(l)/sum(exp(l)); logits ~ +-0.05 so exp is safe.
// Block: 256 thr = 2 nodes x 2 head-quad waves.
__global__ __launch_bounds__(256) void k_agg1(const int* __restrict__ rowstart,
                                              const int* __restrict__ esrc,
                                              const unsigned short* __restrict__ hp1b,
                                              const float* __restrict__ s1s,
                                              const float* __restrict__ s1d,
                                              const float* __restrict__ b1,
                                              unsigned short* __restrict__ h1b) {
  int n = blockIdx.x * 2 + (threadIdx.x >> 7);
  int wq = (threadIdx.x >> 6) & 1;  // head-quad
  int lane = threadIdx.x & 63;
  int myh = wq * 4 + (lane >> 4);
  int sub = lane & 15;
  int r0 = rowstart[n], dg = rowstart[n + 1] - r0;
  float sdst = s1d[n * 8 + myh];
  float4 acc = {0.f, 0.f, 0.f, 0.f};
  float dsum = 0.f;
  const size_t qoff = (size_t)wq * 256 + (size_t)lane * 4;
  for (int base = 0; base < dg; base += 16) {
    int i = base + sub;
    float p = 0.f;
    int s = 0;
    if (i < dg) {
      s = esrc[r0 + i];
      p = __expf(lrelu(s1s[s * 8 + myh] + sdst));
    }
    dsum += p;
    int cnt = min(16, dg - base);
    for (int j = 0; j < cnt; ++j) {
      float pj = __shfl(p, j, 16);
      int sj = __shfl(s, j, 16);
      ushort4 hv = *reinterpret_cast<const ushort4*>(&hp1b[(size_t)sj * F1 + qoff]);
      acc.x += pj * bf2f(hv.x);
      acc.y += pj * bf2f(hv.y);
      acc.z += pj * bf2f(hv.z);
      acc.w += pj * bf2f(hv.w);
    }
  }
#pragma unroll
  for (int o = 1; o < 16; o <<= 1) dsum += __shfl_xor(dsum, o);
  float inv = 1.f / (dsum + 1e-16f);
  int fbase = wq * 256 + lane * 4;
  float o0 = acc.x * inv + b1[fbase + 0];
  float o1 = acc.y * inv + b1[fbase + 1];
  float o2 = acc.z * inv + b1[fbase + 2];
  float o3 = acc.w * inv + b1[fbase + 3];
  o0 = o0 > 0.f ? o0 : (__expf(o0) - 1.f);
  o1 = o1 > 0.f ? o1 : (__expf(o1) - 1.f);
  o2 = o2 > 0.f ? o2 : (__expf(o2) - 1.f);
  o3 = o3 > 0.f ? o3 : (__expf(o3) - 1.f);
  ushort4 ov;
  ov.x = f2bf(o0); ov.y = f2bf(o1); ov.z = f2bf(o2); ov.w = f2bf(o3);
  *reinterpret_cast<ushort4*>(&h1b[(size_t)n * F1 + fbase]) = ov;
}

// ---- GEMM2 (+scores2), register-tiled -----------------------------------
__global__ __launch_bounds__(256) void k_gemm2(const unsigned short* __restrict__ h1b,
                                               const float* __restrict__ W2,
                                               const float* __restrict__ w2sv,
                                               const float* __restrict__ w2dv,
                                               unsigned short* __restrict__ hp2b,
                                               float* __restrict__ s2s,
                                               float* __restrict__ s2d) {
  __shared__ float h1T[64][128];   // 32 KB
  __shared__ float w2s[64][64];    // 16 KB
  __shared__ float sred_s[128], sred_d[128];  // 1 KB
  int t = threadIdx.x;
  int n0 = blockIdx.x * 128;
  int nCnt = min(128, N_NODESC - n0);
  int tn8 = (t & 15) * 8;
  int tc4 = (t >> 4) * 4;
  int sn = t & 127;          // staging node
  int kh = (t >> 7) * 32;    // staging k-half
  float acc[8][4] = {};
  float ssp = 0.f, ddp = 0.f;
  for (int cc = 0; cc < 512; cc += 64) {
    __syncthreads();
    for (int i = t; i < 1024; i += 256)
      reinterpret_cast<float4*>(&w2s[0][0])[i] =
          reinterpret_cast<const float4*>(W2 + (size_t)cc * 64)[i];
    if (sn < nCnt) {
      const size_t base = (size_t)(n0 + sn) * F1 + cc + kh;
#pragma unroll
      for (int i = 0; i < 4; ++i) {
        uint4 u = *reinterpret_cast<const uint4*>(&h1b[base + i * 8]);
        int k0 = kh + i * 8;
        float f0 = bf2f((unsigned short)(u.x & 0xffff));
        float f1 = bf2f((unsigned short)(u.x >> 16));
        float f2 = bf2f((unsigned short)(u.y & 0xffff));
        float f3 = bf2f((unsigned short)(u.y >> 16));
        float f4 = bf2f((unsigned short)(u.z & 0xffff));
        float f5 = bf2f((unsigned short)(u.z >> 16));
        float f6 = bf2f((unsigned short)(u.w & 0xffff));
        float f7 = bf2f((unsigned short)(u.w >> 16));
        h1T[k0 + 0][sn] = f0; h1T[k0 + 1][sn] = f1;
        h1T[k0 + 2][sn] = f2; h1T[k0 + 3][sn] = f3;
        h1T[k0 + 4][sn] = f4; h1T[k0 + 5][sn] = f5;
        h1T[k0 + 6][sn] = f6; h1T[k0 + 7][sn] = f7;
        int kg = cc + k0;
        ssp += f0 * w2sv[kg + 0] + f1 * w2sv[kg + 1] + f2 * w2sv[kg + 2] + f3 * w2sv[kg + 3]
             + f4 * w2sv[kg + 4] + f5 * w2sv[kg + 5] + f6 * w2sv[kg + 6] + f7 * w2sv[kg + 7];
        ddp += f0 * w2dv[kg + 0] + f1 * w2dv[kg + 1] + f2 * w2dv[kg + 2] + f3 * w2dv[kg + 3]
             + f4 * w2dv[kg + 4] + f5 * w2dv[kg + 5] + f6 * w2dv[kg + 6] + f7 * w2dv[kg + 7];
      }
    }
    __syncthreads();
#pragma unroll 8
    for (int k = 0; k < 64; ++k) {
      float4 a0 = *reinterpret_cast<const float4*>(&h1T[k][tn8]);
      float4 a1 = *reinterpret_cast<const float4*>(&h1T[k][tn8 + 4]);
      float4 bv = *reinterpret_cast<const float4*>(&w2s[k][tc4]);
      float av[8] = {a0.x, a0.y, a0.z, a0.w, a1.x, a1.y, a1.z, a1.w};
      float bvv[4] = {bv.x, bv.y, bv.z, bv.w};
#pragma unroll
      for (int i = 0; i < 8; ++i)
#pragma unroll
        for (int jj = 0; jj < 4; ++jj) acc[i][jj] += av[i] * bvv[jj];
    }
  }
  if (t >= 128) { sred_s[sn] = ssp; sred_d[sn] = ddp; }
  __syncthreads();
  if (t < 128 && sn < nCnt) {
    s2s[n0 + sn] = ssp + sred_s[sn];
    s2d[n0 + sn] = ddp + sred_d[sn];
  }
#pragma unroll
  for (int i = 0; i < 8; ++i) {
    int node = tn8 + i;
    if (node < nCnt) {
      ushort4 ov;
      ov.x = f2bf(acc[i][0]); ov.y = f2bf(acc[i][1]);
      ov.z = f2bf(acc[i][2]); ov.w = f2bf(acc[i][3]);
      *reinterpret_cast<ushort4*>(&hp2b[(size_t)(n0 + node) * HID + tc4]) = ov;
    }
  }
}

// ---- layer-2 aggregate: SINGLE PASS + bias + pooled atomicAdd -----------
// Block: 256 thr = 4 nodes x 1 wave.
__global__ __launch_bounds__(256) void k_agg2(const int* __restrict__ rowstart,
                                              const int* __restrict__ esrc,
                                              const unsigned short* __restrict__ hp2b,
                                              const float* __restrict__ s2s,
                                              const float* __restrict__ s2d,
                                              const float* __restrict__ b2,
                                              const int* __restrict__ batch,
                                              float* __restrict__ pooled) {
  int n = blockIdx.x * 4 + (threadIdx.x >> 6);
  int lane = threadIdx.x & 63;
  int half = lane >> 5;
  int fl = lane & 31;
  int r0 = rowstart[n], dg = rowstart[n + 1] - r0;
  float sdst = s2d[n];
  float ax = 0.f, ay = 0.f, dsum = 0.f;
  for (int base = 0; base < dg; base += 32) {
    int i = base + fl;  // both halves compute same 32 weights
    float p = 0.f;
    int s = 0;
    if (i < dg) {
      s = esrc[r0 + i];
      p = __expf(lrelu(s2s[s] + sdst));
    }
    dsum += p;
    int cnt = min(32, dg - base);
    for (int j = 0; j < cnt; j += 2) {
      int jj = j + half;  // lo half: even edges, hi half: odd (p=0 past cnt)
      float pj = __shfl(p, jj, 32);
      int sj = __shfl(s, jj, 32);
      ushort2 hv = *reinterpret_cast<const ushort2*>(&hp2b[(size_t)sj * 64 + fl * 2]);
      ax += pj * bf2f(hv.x);
      ay += pj * bf2f(hv.y);
    }
  }
  // dsum: each half independently holds the full edge sum across its 32 lanes
#pragma unroll
  for (int o = 1; o < 32; o <<= 1) dsum += __shfl_xor(dsum, o);
  float inv = 1.f / (dsum + 1e-16f);
  ax += __shfl_xor(ax, 32);
  ay += __shfl_xor(ay, 32);
  int f = 2 * fl + half;
  float o = (half ? ay : ax) * inv + b2[f];
  atomicAdd(&pooled[batch[n] * 64 + f], o);
}

// ---- final: out[512,40000] = pooled[512,64] @ Wp[64,40000] + bp ---------
__global__ __launch_bounds__(256) void k_final(const float* __restrict__ pooled,
                                               const float* __restrict__ Wp,
                                               const float* __restrict__ bp,
                                               float* __restrict__ out) {
  int v = blockIdx.x * 256 + threadIdx.x;
  bool valid = v < VOCAB_C;
  float w[64];
  float bpv = 0.f;
  if (valid) {
#pragma unroll
    for (int c = 0; c < 64; ++c) w[c] = Wp[(size_t)c * VOCAB_C + v];
    bpv = bp[v];
  }
  __shared__ float ps[64 * 64];  // 16 KB
  int g0 = blockIdx.y * 64;
  const float4* psrc = reinterpret_cast<const float4*>(pooled + (size_t)g0 * 64);
  for (int idx = threadIdx.x; idx < 1024; idx += 256)
    reinterpret_cast<float4*>(ps)[idx] = psrc[idx];
  __syncthreads();
  for (int gl = 0; gl < 64; ++gl) {
    const float4* pr4 = reinterpret_cast<const float4*>(&ps[gl * 64]);
    float acc = bpv;
#pragma unroll
    for (int c4 = 0; c4 < 16; ++c4) {
      float4 pv = pr4[c4];
      acc += pv.x * w[c4 * 4 + 0] + pv.y * w[c4 * 4 + 1] + pv.z * w[c4 * 4 + 2] + pv.w * w[c4 * 4 + 3];
    }
    if (valid) out[(size_t)(g0 + gl) * VOCAB_C + v] = acc;
  }
}

extern "C" void kernel_launch(void* const* d_in, const int* in_sizes, int n_in,
                              void* d_out, int out_size, void* d_ws, size_t ws_size,
                              hipStream_t stream) {
  const int*   x     = (const int*)d_in[0];
  const int*   ei    = (const int*)d_in[1];
  const int*   batch = (const int*)d_in[2];
  const float* emb   = (const float*)d_in[3];
  const float* W1    = (const float*)d_in[4];
  const float* as1   = (const float*)d_in[5];
  const float* ad1   = (const float*)d_in[6];
  const float* b1    = (const float*)d_in[7];
  const float* W2    = (const float*)d_in[8];
  const float* as2   = (const float*)d_in[9];
  const float* ad2   = (const float*)d_in[10];
  const float* b2    = (const float*)d_in[11];
  const float* Wp    = (const float*)d_in[12];
  const float* bp    = (const float*)d_in[13];
  float* out = (float*)d_out;

  char* ws = (char*)d_ws;
  size_t off = 0;
#define WS_ALLOC(T, name, bytes) T name = (T)(ws + off); off += (((size_t)(bytes)) + 255) & ~(size_t)255;
  WS_ALLOC(unsigned short*, hp1b, (size_t)N_NODESC * F1 * 2)
  WS_ALLOC(unsigned short*, h1b,  (size_t)N_NODESC * F1 * 2)
  WS_ALLOC(unsigned short*, hp2b, (size_t)N_NODESC * HID * 2)
  WS_ALLOC(float*, s1s,  (size_t)N_NODESC * HEADS_C * 4)
  WS_ALLOC(float*, s1d,  (size_t)N_NODESC * HEADS_C * 4)
  WS_ALLOC(float*, s2s,  (size_t)N_NODESC * 4)
  WS_ALLOC(float*, s2d,  (size_t)N_NODESC * 4)
  WS_ALLOC(float*, pooled, (size_t)N_GR * HID * 4)
  WS_ALLOC(float*, wa1s, 8 * 64 * 4)
  WS_ALLOC(float*, wa1d, 8 * 64 * 4)
  WS_ALLOC(float*, w2sv, 512 * 4)
  WS_ALLOC(float*, w2dv, 512 * 4)
  WS_ALLOC(int*,   deg,      (size_t)N_NODESC * 4)
  WS_ALLOC(int*,   rowstart, (size_t)(N_NODESC + 1) * 4)
  WS_ALLOC(int*,   cursor,   (size_t)N_NODESC * 4)
  WS_ALLOC(int*,   esrc,     (size_t)E_TOT * 4)
#undef WS_ALLOC
  (void)ws_size; (void)in_sizes; (void)n_in; (void)out_size;

  hipMemsetAsync(deg, 0, (size_t)N_NODESC * 4, stream);
  hipMemsetAsync(cursor, 0, (size_t)N_NODESC * 4, stream);
  hipMemsetAsync(pooled, 0, (size_t)N_GR * HID * 4, stream);

  int ethreads = 256, eblocks = (E_TOT + 255) / 256;
  k_deg<<<eblocks, ethreads, 0, stream>>>(ei, deg);
  k_scan<<<1, 1024, 0, stream>>>(deg, rowstart);
  k_scatter<<<eblocks, ethreads, 0, stream>>>(ei, rowstart, cursor, esrc);
  k_prep<<<1, 512, 0, stream>>>(W1, as1, ad1, W2, as2, ad2, wa1s, wa1d, w2sv, w2dv);

  k_gemm1<<<(N_NODESC + 63) / 64, 256, 0, stream>>>(x, emb, W1, wa1s, wa1d, hp1b, s1s, s1d);
  k_agg1<<<N_NODESC / 2, 256, 0, stream>>>(rowstart, esrc, hp1b, s1s, s1d, b1, h1b);

  k_gemm2<<<(N_NODESC + 127) / 128, 256, 0, stream>>>(h1b, W2, w2sv, w2dv, hp2b, s2s, s2d);
  k_agg2<<<N_NODESC / 4, 256, 0, stream>>>(rowstart, esrc, hp2b, s2s, s2d, b2, batch, pooled);

  k_final<<<dim3((VOCAB_C + 255) / 256, 8), 256, 0, stream>>>(pooled, Wp, bp, out);
}

// Round 7
// 471.209 us; speedup vs baseline: 2.3606x; 1.0174x over previous
//
#include <hip/hip_runtime.h>
#include <hip/hip_bf16.h>

#define N_NODESC 50000
#define N_EDGESC 500000
#define E_TOT    (N_EDGESC + N_NODESC)   // 550000, with self loops
#define HID      64
#define HEADS_C  8
#define F1       (HEADS_C * HID)         // 512
#define VOCAB_C  40000
#define N_GR     512

__device__ __forceinline__ float wred_sum(float v) {
#pragma unroll
  for (int o = 32; o; o >>= 1) v += __shfl_xor(v, o);
  return v;
}
__device__ __forceinline__ float lrelu(float x) { return x > 0.f ? x : 0.2f * x; }
__device__ __forceinline__ float bf2f(unsigned short u) {
  return __uint_as_float(((unsigned int)u) << 16);
}
__device__ __forceinline__ unsigned short f2bf(float f) {
  unsigned int u = __float_as_uint(f);
  unsigned int r = (u + 0x7fffu + ((u >> 16) & 1u)) >> 16;
  return (unsigned short)r;
}

// ---- CSR build ----------------------------------------------------------
__global__ void k_deg(const int* __restrict__ ei, int* __restrict__ deg) {
  int e = blockIdx.x * blockDim.x + threadIdx.x;
  if (e >= E_TOT) return;
  int dst = (e < N_EDGESC) ? ei[N_EDGESC + e] : (e - N_EDGESC);
  atomicAdd(&deg[dst], 1);
}

__global__ void k_scan(const int* __restrict__ deg, int* __restrict__ rowstart) {
  __shared__ int part[1024];
  const int ITEMS = 49;  // 1024*49 = 50176 >= 50000
  int t = threadIdx.x;
  int lo = t * ITEMS, hi = min(lo + ITEMS, N_NODESC);
  int s = 0;
  for (int i = lo; i < hi; ++i) s += deg[i];
  part[t] = s;
  __syncthreads();
  for (int o = 1; o < 1024; o <<= 1) {
    int v = (t >= o) ? part[t - o] : 0;
    __syncthreads();
    part[t] += v;
    __syncthreads();
  }
  int off = part[t] - s;  // exclusive
  for (int i = lo; i < hi; ++i) { rowstart[i] = off; off += deg[i]; }
  if (t == 1023) rowstart[N_NODESC] = part[1023];
}

__global__ void k_scatter(const int* __restrict__ ei, const int* __restrict__ rowstart,
                          int* __restrict__ cursor, int* __restrict__ esrc) {
  int e = blockIdx.x * blockDim.x + threadIdx.x;
  if (e >= E_TOT) return;
  int src, dst;
  if (e < N_EDGESC) { src = ei[e]; dst = ei[N_EDGESC + e]; }
  else { src = dst = e - N_EDGESC; }
  int slot = rowstart[dst] + atomicAdd(&cursor[dst], 1);
  esrc[slot] = src;
}

// ---- prep: fold attention vectors through the weight matrices -----------
__global__ __launch_bounds__(512) void k_prep(const float* __restrict__ W1,
                                              const float* __restrict__ as1,
                                              const float* __restrict__ ad1,
                                              const float* __restrict__ W2,
                                              const float* __restrict__ as2,
                                              const float* __restrict__ ad2,
                                              float* __restrict__ wa1s, float* __restrict__ wa1d,
                                              float* __restrict__ w2sv, float* __restrict__ w2dv) {
  int t = threadIdx.x;  // 512
  int k = t >> 3, h = t & 7;
  float ss = 0.f, dd = 0.f;
  for (int c = 0; c < 64; ++c) {
    float w = W1[k * F1 + h * 64 + c];
    ss += w * as1[h * 64 + c];
    dd += w * ad1[h * 64 + c];
  }
  wa1s[h * 64 + k] = ss;
  wa1d[h * 64 + k] = dd;
  float s2 = 0.f, d2 = 0.f;
  for (int c = 0; c < 64; ++c) {
    float w = W2[t * 64 + c];
    s2 += w * as2[c];
    d2 += w * ad2[c];
  }
  w2sv[t] = s2;
  w2dv[t] = d2;
}

// ---- GEMM1 (+embed gather +scores1), register-tiled ---------------------
__global__ __launch_bounds__(256) void k_gemm1(const int* __restrict__ x,
                                               const float* __restrict__ emb,
                                               const float* __restrict__ W1,
                                               const float* __restrict__ wa1s,
                                               const float* __restrict__ wa1d,
                                               unsigned short* __restrict__ hp1b,
                                               float* __restrict__ s1s,
                                               float* __restrict__ s1d) {
  __shared__ float hT[64][64];     // 16 KB, [k][node]
  __shared__ float w1s[64][128];   // 32 KB
  __shared__ float was[512], wad[512];  // 4 KB
  int t = threadIdx.x;
  int n0 = blockIdx.x * 64;
  int nCnt = min(64, N_NODESC - n0);
  was[t] = wa1s[t]; was[t + 256] = wa1s[t + 256];
  wad[t] = wa1d[t]; wad[t + 256] = wa1d[t + 256];
  int sn = t & 63, kq = (t >> 6) * 16;
  if (sn < nCnt) {
    int row = x[n0 + sn];
    const float4* er = reinterpret_cast<const float4*>(emb + (size_t)row * 64 + kq);
#pragma unroll
    for (int i = 0; i < 4; ++i) {
      float4 v = er[i];
      hT[kq + i * 4 + 0][sn] = v.x;
      hT[kq + i * 4 + 1][sn] = v.y;
      hT[kq + i * 4 + 2][sn] = v.z;
      hT[kq + i * 4 + 3][sn] = v.w;
    }
  } else {
#pragma unroll
    for (int i = 0; i < 16; ++i) hT[kq + i][sn] = 0.f;
  }
  __syncthreads();
  {
    int node = t & 63;
    int part = t >> 6;
    const float* wa = (part & 2) ? wad : was;
    int h0 = (part & 1) * 4;
    float a0 = 0.f, a1 = 0.f, a2 = 0.f, a3 = 0.f;
#pragma unroll 8
    for (int k = 0; k < 64; ++k) {
      float hv = hT[k][node];
      a0 += hv * wa[(h0 + 0) * 64 + k];
      a1 += hv * wa[(h0 + 1) * 64 + k];
      a2 += hv * wa[(h0 + 2) * 64 + k];
      a3 += hv * wa[(h0 + 3) * 64 + k];
    }
    if (node < nCnt) {
      float4 st = {a0, a1, a2, a3};
      float* dstp = (part & 2) ? s1d : s1s;
      reinterpret_cast<float4*>(dstp)[(size_t)(n0 + node) * 2 + (part & 1)] = st;
    }
  }
  int cg = t & 31;   // col group: 4 cols
  int ng = t >> 5;   // node group: 8 nodes
  for (int cc = 0; cc < 512; cc += 128) {
    __syncthreads();
    for (int idx = t; idx < 64 * 32; idx += 256) {
      int k = idx >> 5, c4 = idx & 31;
      reinterpret_cast<float4*>(&w1s[k][0])[c4] =
          *reinterpret_cast<const float4*>(&W1[(size_t)k * F1 + cc + c4 * 4]);
    }
    __syncthreads();
    float acc[8][4] = {};
#pragma unroll 4
    for (int k = 0; k < 64; ++k) {
      float4 b = *reinterpret_cast<const float4*>(&w1s[k][cg * 4]);
      float4 a0 = *reinterpret_cast<const float4*>(&hT[k][ng * 8]);
      float4 a1 = *reinterpret_cast<const float4*>(&hT[k][ng * 8 + 4]);
      float av[8] = {a0.x, a0.y, a0.z, a0.w, a1.x, a1.y, a1.z, a1.w};
#pragma unroll
      for (int i = 0; i < 8; ++i) {
        acc[i][0] += av[i] * b.x;
        acc[i][1] += av[i] * b.y;
        acc[i][2] += av[i] * b.z;
        acc[i][3] += av[i] * b.w;
      }
    }
#pragma unroll
    for (int i = 0; i < 8; ++i) {
      int node = ng * 8 + i;
      if (node < nCnt) {
        ushort4 ov;
        ov.x = f2bf(acc[i][0]); ov.y = f2bf(acc[i][1]);
        ov.z = f2bf(acc[i][2]); ov.w = f2bf(acc[i][3]);
        *reinterpret_cast<ushort4*>(&hp1b[(size_t)(n0 + node) * F1 + cc + cg * 4]) = ov;
      }
    }
  }
}

// ---- layer-1 aggregate: single pass, ONE WAVE per node ------------------
// Lane L covers features [8L, 8L+8) (one dwordx4 = full 1KB row per wave).
// p-phase: lane (e,h) = (L>>3, L&7) computes exp weight for edge-slot e, head h.
__global__ __launch_bounds__(256) void k_agg1(const int* __restrict__ rowstart,
                                              const int* __restrict__ esrc,
                                              const unsigned short* __restrict__ hp1b,
                                              const float* __restrict__ s1s,
                                              const float* __restrict__ s1d,
                                              const float* __restrict__ b1,
                                              unsigned short* __restrict__ h1b) {
  int n = blockIdx.x * 4 + (threadIdx.x >> 6);
  int L = threadIdx.x & 63;
  int eh = L >> 3;  // edge slot (p-phase)
  int hh = L & 7;   // head (p-phase)
  int r0 = rowstart[n], dg = rowstart[n + 1] - r0;
  float sdst = s1d[n * 8 + hh];
  float acc[8] = {};
  float dsum = 0.f;
  int myh = L >> 3;  // head of this lane's feature slice
  for (int base = 0; base < dg; base += 8) {
    int i = base + eh;
    float p = 0.f;
    int s = 0;
    if (i < dg) {
      s = esrc[r0 + i];
      p = __expf(lrelu(s1s[s * 8 + hh] + sdst));
    }
    dsum += p;
    int cnt = min(8, dg - base);
    for (int j = 0; j < cnt; ++j) {
      float pj = __shfl(p, (j << 3) | myh);
      int sj = __shfl(s, j << 3);
      uint4 u = *reinterpret_cast<const uint4*>(&hp1b[(size_t)sj * F1 + L * 8]);
      acc[0] += pj * bf2f((unsigned short)(u.x & 0xffff));
      acc[1] += pj * bf2f((unsigned short)(u.x >> 16));
      acc[2] += pj * bf2f((unsigned short)(u.y & 0xffff));
      acc[3] += pj * bf2f((unsigned short)(u.y >> 16));
      acc[4] += pj * bf2f((unsigned short)(u.z & 0xffff));
      acc[5] += pj * bf2f((unsigned short)(u.z >> 16));
      acc[6] += pj * bf2f((unsigned short)(u.w & 0xffff));
      acc[7] += pj * bf2f((unsigned short)(u.w >> 16));
    }
  }
  // reduce dsum across edge slots (lanes with equal L&7), then fetch my head's
  dsum += __shfl_xor(dsum, 8);
  dsum += __shfl_xor(dsum, 16);
  dsum += __shfl_xor(dsum, 32);
  float inv = 1.f / (__shfl(dsum, myh) + 1e-16f);
  int f0 = L * 8;
  float o[8];
#pragma unroll
  for (int k = 0; k < 8; ++k) {
    float v = acc[k] * inv + b1[f0 + k];
    o[k] = v > 0.f ? v : (__expf(v) - 1.f);
  }
  uint4 ov;
  ov.x = (unsigned int)f2bf(o[0]) | ((unsigned int)f2bf(o[1]) << 16);
  ov.y = (unsigned int)f2bf(o[2]) | ((unsigned int)f2bf(o[3]) << 16);
  ov.z = (unsigned int)f2bf(o[4]) | ((unsigned int)f2bf(o[5]) << 16);
  ov.w = (unsigned int)f2bf(o[6]) | ((unsigned int)f2bf(o[7]) << 16);
  *reinterpret_cast<uint4*>(&h1b[(size_t)n * F1 + f0]) = ov;
}

// ---- GEMM2 (+scores2), register-tiled -----------------------------------
__global__ __launch_bounds__(256) void k_gemm2(const unsigned short* __restrict__ h1b,
                                               const float* __restrict__ W2,
                                               const float* __restrict__ w2sv,
                                               const float* __restrict__ w2dv,
                                               unsigned short* __restrict__ hp2b,
                                               float* __restrict__ s2s,
                                               float* __restrict__ s2d) {
  __shared__ float h1T[64][128];   // 32 KB
  __shared__ float w2s[64][64];    // 16 KB
  __shared__ float sred_s[128], sred_d[128];  // 1 KB
  int t = threadIdx.x;
  int n0 = blockIdx.x * 128;
  int nCnt = min(128, N_NODESC - n0);
  int tn8 = (t & 15) * 8;
  int tc4 = (t >> 4) * 4;
  int sn = t & 127;          // staging node
  int kh = (t >> 7) * 32;    // staging k-half
  float acc[8][4] = {};
  float ssp = 0.f, ddp = 0.f;
  for (int cc = 0; cc < 512; cc += 64) {
    __syncthreads();
    for (int i = t; i < 1024; i += 256)
      reinterpret_cast<float4*>(&w2s[0][0])[i] =
          reinterpret_cast<const float4*>(W2 + (size_t)cc * 64)[i];
    if (sn < nCnt) {
      const size_t base = (size_t)(n0 + sn) * F1 + cc + kh;
#pragma unroll
      for (int i = 0; i < 4; ++i) {
        uint4 u = *reinterpret_cast<const uint4*>(&h1b[base + i * 8]);
        int k0 = kh + i * 8;
        float f0 = bf2f((unsigned short)(u.x & 0xffff));
        float f1 = bf2f((unsigned short)(u.x >> 16));
        float f2 = bf2f((unsigned short)(u.y & 0xffff));
        float f3 = bf2f((unsigned short)(u.y >> 16));
        float f4 = bf2f((unsigned short)(u.z & 0xffff));
        float f5 = bf2f((unsigned short)(u.z >> 16));
        float f6 = bf2f((unsigned short)(u.w & 0xffff));
        float f7 = bf2f((unsigned short)(u.w >> 16));
        h1T[k0 + 0][sn] = f0; h1T[k0 + 1][sn] = f1;
        h1T[k0 + 2][sn] = f2; h1T[k0 + 3][sn] = f3;
        h1T[k0 + 4][sn] = f4; h1T[k0 + 5][sn] = f5;
        h1T[k0 + 6][sn] = f6; h1T[k0 + 7][sn] = f7;
        int kg = cc + k0;
        ssp += f0 * w2sv[kg + 0] + f1 * w2sv[kg + 1] + f2 * w2sv[kg + 2] + f3 * w2sv[kg + 3]
             + f4 * w2sv[kg + 4] + f5 * w2sv[kg + 5] + f6 * w2sv[kg + 6] + f7 * w2sv[kg + 7];
        ddp += f0 * w2dv[kg + 0] + f1 * w2dv[kg + 1] + f2 * w2dv[kg + 2] + f3 * w2dv[kg + 3]
             + f4 * w2dv[kg + 4] + f5 * w2dv[kg + 5] + f6 * w2dv[kg + 6] + f7 * w2dv[kg + 7];
      }
    }
    __syncthreads();
#pragma unroll 8
    for (int k = 0; k < 64; ++k) {
      float4 a0 = *reinterpret_cast<const float4*>(&h1T[k][tn8]);
      float4 a1 = *reinterpret_cast<const float4*>(&h1T[k][tn8 + 4]);
      float4 bv = *reinterpret_cast<const float4*>(&w2s[k][tc4]);
      float av[8] = {a0.x, a0.y, a0.z, a0.w, a1.x, a1.y, a1.z, a1.w};
      float bvv[4] = {bv.x, bv.y, bv.z, bv.w};
#pragma unroll
      for (int i = 0; i < 8; ++i)
#pragma unroll
        for (int jj = 0; jj < 4; ++jj) acc[i][jj] += av[i] * bvv[jj];
    }
  }
  if (t >= 128) { sred_s[sn] = ssp; sred_d[sn] = ddp; }
  __syncthreads();
  if (t < 128 && sn < nCnt) {
    s2s[n0 + sn] = ssp + sred_s[sn];
    s2d[n0 + sn] = ddp + sred_d[sn];
  }
#pragma unroll
  for (int i = 0; i < 8; ++i) {
    int node = tn8 + i;
    if (node < nCnt) {
      ushort4 ov;
      ov.x = f2bf(acc[i][0]); ov.y = f2bf(acc[i][1]);
      ov.z = f2bf(acc[i][2]); ov.w = f2bf(acc[i][3]);
      *reinterpret_cast<ushort4*>(&hp2b[(size_t)(n0 + node) * HID + tc4]) = ov;
    }
  }
}

// ---- layer-2 aggregate: SINGLE PASS + bias + pooled atomicAdd -----------
__global__ __launch_bounds__(256) void k_agg2(const int* __restrict__ rowstart,
                                              const int* __restrict__ esrc,
                                              const unsigned short* __restrict__ hp2b,
                                              const float* __restrict__ s2s,
                                              const float* __restrict__ s2d,
                                              const float* __restrict__ b2,
                                              const int* __restrict__ batch,
                                              float* __restrict__ pooled) {
  int n = blockIdx.x * 4 + (threadIdx.x >> 6);
  int lane = threadIdx.x & 63;
  int half = lane >> 5;
  int fl = lane & 31;
  int r0 = rowstart[n], dg = rowstart[n + 1] - r0;
  float sdst = s2d[n];
  float ax = 0.f, ay = 0.f, dsum = 0.f;
  for (int base = 0; base < dg; base += 32) {
    int i = base + fl;  // both halves compute same 32 weights
    float p = 0.f;
    int s = 0;
    if (i < dg) {
      s = esrc[r0 + i];
      p = __expf(lrelu(s2s[s] + sdst));
    }
    dsum += p;
    int cnt = min(32, dg - base);
    for (int j = 0; j < cnt; j += 2) {
      int jj = j + half;  // lo half: even edges, hi half: odd (p=0 past cnt)
      float pj = __shfl(p, jj, 32);
      int sj = __shfl(s, jj, 32);
      ushort2 hv = *reinterpret_cast<const ushort2*>(&hp2b[(size_t)sj * 64 + fl * 2]);
      ax += pj * bf2f(hv.x);
      ay += pj * bf2f(hv.y);
    }
  }
#pragma unroll
  for (int o = 1; o < 32; o <<= 1) dsum += __shfl_xor(dsum, o);
  float inv = 1.f / (dsum + 1e-16f);
  ax += __shfl_xor(ax, 32);
  ay += __shfl_xor(ay, 32);
  int f = 2 * fl + half;
  float o = (half ? ay : ax) * inv + b2[f];
  atomicAdd(&pooled[batch[n] * 64 + f], o);
}

// ---- final: out[512,40000] = pooled[512,64] @ Wp[64,40000] + bp ---------
__global__ __launch_bounds__(256) void k_final(const float* __restrict__ pooled,
                                               const float* __restrict__ Wp,
                                               const float* __restrict__ bp,
                                               float* __restrict__ out) {
  int v = blockIdx.x * 256 + threadIdx.x;
  bool valid = v < VOCAB_C;
  float w[64];
  float bpv = 0.f;
  if (valid) {
#pragma unroll
    for (int c = 0; c < 64; ++c) w[c] = Wp[(size_t)c * VOCAB_C + v];
    bpv = bp[v];
  }
  __shared__ float ps[64 * 64];  // 16 KB
  int g0 = blockIdx.y * 64;
  const float4* psrc = reinterpret_cast<const float4*>(pooled + (size_t)g0 * 64);
  for (int idx = threadIdx.x; idx < 1024; idx += 256)
    reinterpret_cast<float4*>(ps)[idx] = psrc[idx];
  __syncthreads();
  for (int gl = 0; gl < 64; ++gl) {
    const float4* pr4 = reinterpret_cast<const float4*>(&ps[gl * 64]);
    float acc = bpv;
#pragma unroll
    for (int c4 = 0; c4 < 16; ++c4) {
      float4 pv = pr4[c4];
      acc += pv.x * w[c4 * 4 + 0] + pv.y * w[c4 * 4 + 1] + pv.z * w[c4 * 4 + 2] + pv.w * w[c4 * 4 + 3];
    }
    if (valid) out[(size_t)(g0 + gl) * VOCAB_C + v] = acc;
  }
}

extern "C" void kernel_launch(void* const* d_in, const int* in_sizes, int n_in,
                              void* d_out, int out_size, void* d_ws, size_t ws_size,
                              hipStream_t stream) {
  const int*   x     = (const int*)d_in[0];
  const int*   ei    = (const int*)d_in[1];
  const int*   batch = (const int*)d_in[2];
  const float* emb   = (const float*)d_in[3];
  const float* W1    = (const float*)d_in[4];
  const float* as1   = (const float*)d_in[5];
  const float* ad1   = (const float*)d_in[6];
  const float* b1    = (const float*)d_in[7];
  const float* W2    = (const float*)d_in[8];
  const float* as2   = (const float*)d_in[9];
  const float* ad2   = (const float*)d_in[10];
  const float* b2    = (const float*)d_in[11];
  const float* Wp    = (const float*)d_in[12];
  const float* bp    = (const float*)d_in[13];
  float* out = (float*)d_out;

  char* ws = (char*)d_ws;
  size_t off = 0;
#define WS_ALLOC(T, name, bytes) T name = (T)(ws + off); off += (((size_t)(bytes)) + 255) & ~(size_t)255;
  WS_ALLOC(unsigned short*, hp1b, (size_t)N_NODESC * F1 * 2)
  WS_ALLOC(unsigned short*, h1b,  (size_t)N_NODESC * F1 * 2)
  WS_ALLOC(unsigned short*, hp2b, (size_t)N_NODESC * HID * 2)
  WS_ALLOC(float*, s1s,  (size_t)N_NODESC * HEADS_C * 4)
  WS_ALLOC(float*, s1d,  (size_t)N_NODESC * HEADS_C * 4)
  WS_ALLOC(float*, s2s,  (size_t)N_NODESC * 4)
  WS_ALLOC(float*, s2d,  (size_t)N_NODESC * 4)
  WS_ALLOC(float*, pooled, (size_t)N_GR * HID * 4)
  WS_ALLOC(float*, wa1s, 8 * 64 * 4)
  WS_ALLOC(float*, wa1d, 8 * 64 * 4)
  WS_ALLOC(float*, w2sv, 512 * 4)
  WS_ALLOC(float*, w2dv, 512 * 4)
  WS_ALLOC(int*,   deg,      (size_t)N_NODESC * 4)
  WS_ALLOC(int*,   rowstart, (size_t)(N_NODESC + 1) * 4)
  WS_ALLOC(int*,   cursor,   (size_t)N_NODESC * 4)
  WS_ALLOC(int*,   esrc,     (size_t)E_TOT * 4)
#undef WS_ALLOC
  (void)ws_size; (void)in_sizes; (void)n_in; (void)out_size;

  hipMemsetAsync(deg, 0, (size_t)N_NODESC * 4, stream);
  hipMemsetAsync(cursor, 0, (size_t)N_NODESC * 4, stream);
  hipMemsetAsync(pooled, 0, (size_t)N_GR * HID * 4, stream);

  int ethreads = 256, eblocks = (E_TOT + 255) / 256;
  k_deg<<<eblocks, ethreads, 0, stream>>>(ei, deg);
  k_scan<<<1, 1024, 0, stream>>>(deg, rowstart);
  k_scatter<<<eblocks, ethreads, 0, stream>>>(ei, rowstart, cursor, esrc);
  k_prep<<<1, 512, 0, stream>>>(W1, as1, ad1, W2, as2, ad2, wa1s, wa1d, w2sv, w2dv);

  k_gemm1<<<(N_NODESC + 63) / 64, 256, 0, stream>>>(x, emb, W1, wa1s, wa1d, hp1b, s1s, s1d);
  k_agg1<<<N_NODESC / 4, 256, 0, stream>>>(rowstart, esrc, hp1b, s1s, s1d, b1, h1b);

  k_gemm2<<<(N_NODESC + 127) / 128, 256, 0, stream>>>(h1b, W2, w2sv, w2dv, hp2b, s2s, s2d);
  k_agg2<<<N_NODESC / 4, 256, 0, stream>>>(rowstart, esrc, hp2b, s2s, s2d, b2, batch, pooled);

  k_final<<<dim3((VOCAB_C + 255) / 256, 8), 256, 0, stream>>>(pooled, Wp, bp, out);
}

// Round 8
// 467.821 us; speedup vs baseline: 2.3777x; 1.0072x over previous
//
#include <hip/hip_runtime.h>
#include <hip/hip_bf16.h>

#define N_NODESC 50000
#define N_EDGESC 500000
#define E_TOT    (N_EDGESC + N_NODESC)   // 550000, with self loops
#define HID      64
#define HEADS_C  8
#define F1       (HEADS_C * HID)         // 512
#define VOCAB_C  40000
#define N_GR     512

typedef __attribute__((ext_vector_type(8))) short bf16x8;
typedef __attribute__((ext_vector_type(4))) float f32x4;

__device__ __forceinline__ float lrelu(float x) { return x > 0.f ? x : 0.2f * x; }
__device__ __forceinline__ float bf2f(unsigned short u) {
  return __uint_as_float(((unsigned int)u) << 16);
}
__device__ __forceinline__ unsigned short f2bf(float f) {
  unsigned int u = __float_as_uint(f);
  unsigned int r = (u + 0x7fffu + ((u >> 16) & 1u)) >> 16;
  return (unsigned short)r;
}

// ---- CSR build ----------------------------------------------------------
__global__ void k_deg(const int* __restrict__ ei, int* __restrict__ deg) {
  int e = blockIdx.x * blockDim.x + threadIdx.x;
  if (e >= E_TOT) return;
  int dst = (e < N_EDGESC) ? ei[N_EDGESC + e] : (e - N_EDGESC);
  atomicAdd(&deg[dst], 1);
}

__global__ void k_scan(const int* __restrict__ deg, int* __restrict__ rowstart) {
  __shared__ int part[1024];
  const int ITEMS = 49;  // 1024*49 = 50176 >= 50000
  int t = threadIdx.x;
  int lo = t * ITEMS, hi = min(lo + ITEMS, N_NODESC);
  int s = 0;
  for (int i = lo; i < hi; ++i) s += deg[i];
  part[t] = s;
  __syncthreads();
  for (int o = 1; o < 1024; o <<= 1) {
    int v = (t >= o) ? part[t - o] : 0;
    __syncthreads();
    part[t] += v;
    __syncthreads();
  }
  int off = part[t] - s;  // exclusive
  for (int i = lo; i < hi; ++i) { rowstart[i] = off; off += deg[i]; }
  if (t == 1023) rowstart[N_NODESC] = part[1023];
}

__global__ void k_scatter(const int* __restrict__ ei, const int* __restrict__ rowstart,
                          int* __restrict__ cursor, int* __restrict__ esrc) {
  int e = blockIdx.x * blockDim.x + threadIdx.x;
  if (e >= E_TOT) return;
  int src, dst;
  if (e < N_EDGESC) { src = ei[e]; dst = ei[N_EDGESC + e]; }
  else { src = dst = e - N_EDGESC; }
  int slot = rowstart[dst] + atomicAdd(&cursor[dst], 1);
  esrc[slot] = src;
}

// ---- prep: fold attention vectors through the weight matrices -----------
__global__ __launch_bounds__(512) void k_prep(const float* __restrict__ W1,
                                              const float* __restrict__ as1,
                                              const float* __restrict__ ad1,
                                              const float* __restrict__ W2,
                                              const float* __restrict__ as2,
                                              const float* __restrict__ ad2,
                                              float* __restrict__ wa1s, float* __restrict__ wa1d,
                                              float* __restrict__ w2sv, float* __restrict__ w2dv) {
  int t = threadIdx.x;  // 512
  int k = t >> 3, h = t & 7;
  float ss = 0.f, dd = 0.f;
  for (int c = 0; c < 64; ++c) {
    float w = W1[k * F1 + h * 64 + c];
    ss += w * as1[h * 64 + c];
    dd += w * ad1[h * 64 + c];
  }
  wa1s[h * 64 + k] = ss;
  wa1d[h * 64 + k] = dd;
  float s2 = 0.f, d2 = 0.f;
  for (int c = 0; c < 64; ++c) {
    float w = W2[t * 64 + c];
    s2 += w * as2[c];
    d2 += w * ad2[c];
  }
  w2sv[t] = s2;
  w2dv[t] = d2;
}

// ---- weight convert/transpose to bf16 for MFMA B-operands ---------------
// w1bT[c][k] = bf16(W1[k][c]) (512x64); w2bT[c][k] = bf16(W2[k][c]) (64x512)
__global__ __launch_bounds__(256) void k_wconv(const float* __restrict__ W1,
                                               const float* __restrict__ W2,
                                               unsigned short* __restrict__ w1bT,
                                               unsigned short* __restrict__ w2bT) {
  int g = blockIdx.x * 256 + threadIdx.x;
  if (g < 32768) {
    int c = g >> 6, k = g & 63;
    w1bT[g] = f2bf(W1[(size_t)k * F1 + c]);
  } else {
    int idx = g - 32768;
    int c = idx >> 9, k = idx & 511;
    w2bT[idx] = f2bf(W2[(size_t)k * HID + c]);
  }
}

// ---- embed gather -> bf16 rows, + scores1 from f32 ----------------------
__global__ __launch_bounds__(256) void k_embed(const int* __restrict__ x,
                                               const float* __restrict__ emb,
                                               const float* __restrict__ wa1s,
                                               const float* __restrict__ wa1d,
                                               unsigned short* __restrict__ hbf,
                                               float* __restrict__ s1s,
                                               float* __restrict__ s1d) {
  int n = blockIdx.x * 4 + (threadIdx.x >> 6);
  int lane = threadIdx.x & 63;
  float h = emb[(size_t)x[n] * 64 + lane];
  hbf[(size_t)n * 64 + lane] = f2bf(h);
  float ps[8], pd[8];
#pragma unroll
  for (int j = 0; j < 8; ++j) {
    ps[j] = h * wa1s[j * 64 + lane];
    pd[j] = h * wa1d[j * 64 + lane];
  }
#pragma unroll
  for (int off = 1; off < 64; off <<= 1) {
#pragma unroll
    for (int j = 0; j < 8; ++j) {
      ps[j] += __shfl_xor(ps[j], off);
      pd[j] += __shfl_xor(pd[j], off);
    }
  }
  if (lane == 0) {
#pragma unroll
    for (int j = 0; j < 8; ++j) {
      s1s[n * 8 + j] = ps[j];
      s1d[n * 8 + j] = pd[j];
    }
  }
}

// ---- GEMM1 via MFMA: hp1b[N,512] = hbf[N,64] @ w1bT^T -------------------
// Block 256 thr = 4 waves; wave w: 16 nodes x cols [128w,128w+128), K=64.
__global__ __launch_bounds__(256) void k_gemm1(const unsigned short* __restrict__ hbf,
                                               const unsigned short* __restrict__ w1bT,
                                               unsigned short* __restrict__ hp1b) {
  int w = threadIdx.x >> 6, lane = threadIdx.x & 63;
  int lrow = lane & 15, lq = lane >> 4;
  int n0 = blockIdx.x * 16;       // 3125 blocks exact
  int c0 = w * 128;
  const bf16x8* arow = reinterpret_cast<const bf16x8*>(hbf + (size_t)(n0 + lrow) * 64 + lq * 8);
  bf16x8 a0 = arow[0];  // k = lq*8..+8
  bf16x8 a1 = arow[4];  // k = 32+lq*8..+8
  f32x4 acc[8] = {};
#pragma unroll
  for (int ct = 0; ct < 8; ++ct) {
    int col = c0 + ct * 16 + lrow;
    const bf16x8* brow = reinterpret_cast<const bf16x8*>(w1bT + (size_t)col * 64 + lq * 8);
    acc[ct] = __builtin_amdgcn_mfma_f32_16x16x32_bf16(a0, brow[0], acc[ct], 0, 0, 0);
    acc[ct] = __builtin_amdgcn_mfma_f32_16x16x32_bf16(a1, brow[4], acc[ct], 0, 0, 0);
  }
#pragma unroll
  for (int ct = 0; ct < 8; ++ct) {
    int col = c0 + ct * 16 + lrow;
#pragma unroll
    for (int r = 0; r < 4; ++r)
      hp1b[(size_t)(n0 + lq * 4 + r) * F1 + col] = f2bf(acc[ct][r]);
  }
}

// ---- layer-1 aggregate: single pass, ONE WAVE per node ------------------
__global__ __launch_bounds__(256) void k_agg1(const int* __restrict__ rowstart,
                                              const int* __restrict__ esrc,
                                              const unsigned short* __restrict__ hp1b,
                                              const float* __restrict__ s1s,
                                              const float* __restrict__ s1d,
                                              const float* __restrict__ b1,
                                              unsigned short* __restrict__ h1b) {
  int n = blockIdx.x * 4 + (threadIdx.x >> 6);
  int L = threadIdx.x & 63;
  int eh = L >> 3;  // edge slot (p-phase)
  int hh = L & 7;   // head (p-phase)
  int r0 = rowstart[n], dg = rowstart[n + 1] - r0;
  float sdst = s1d[n * 8 + hh];
  float acc[8] = {};
  float dsum = 0.f;
  int myh = L >> 3;  // head of this lane's feature slice
  for (int base = 0; base < dg; base += 8) {
    int i = base + eh;
    float p = 0.f;
    int s = 0;
    if (i < dg) {
      s = esrc[r0 + i];
      p = __expf(lrelu(s1s[s * 8 + hh] + sdst));
    }
    dsum += p;
    int cnt = min(8, dg - base);
    for (int j = 0; j < cnt; ++j) {
      float pj = __shfl(p, (j << 3) | myh);
      int sj = __shfl(s, j << 3);
      uint4 u = *reinterpret_cast<const uint4*>(&hp1b[(size_t)sj * F1 + L * 8]);
      acc[0] += pj * bf2f((unsigned short)(u.x & 0xffff));
      acc[1] += pj * bf2f((unsigned short)(u.x >> 16));
      acc[2] += pj * bf2f((unsigned short)(u.y & 0xffff));
      acc[3] += pj * bf2f((unsigned short)(u.y >> 16));
      acc[4] += pj * bf2f((unsigned short)(u.z & 0xffff));
      acc[5] += pj * bf2f((unsigned short)(u.z >> 16));
      acc[6] += pj * bf2f((unsigned short)(u.w & 0xffff));
      acc[7] += pj * bf2f((unsigned short)(u.w >> 16));
    }
  }
  dsum += __shfl_xor(dsum, 8);
  dsum += __shfl_xor(dsum, 16);
  dsum += __shfl_xor(dsum, 32);
  float inv = 1.f / (__shfl(dsum, myh) + 1e-16f);
  int f0 = L * 8;
  float o[8];
#pragma unroll
  for (int k = 0; k < 8; ++k) {
    float v = acc[k] * inv + b1[f0 + k];
    o[k] = v > 0.f ? v : (__expf(v) - 1.f);
  }
  uint4 ov;
  ov.x = (unsigned int)f2bf(o[0]) | ((unsigned int)f2bf(o[1]) << 16);
  ov.y = (unsigned int)f2bf(o[2]) | ((unsigned int)f2bf(o[3]) << 16);
  ov.z = (unsigned int)f2bf(o[4]) | ((unsigned int)f2bf(o[5]) << 16);
  ov.w = (unsigned int)f2bf(o[6]) | ((unsigned int)f2bf(o[7]) << 16);
  *reinterpret_cast<uint4*>(&h1b[(size_t)n * F1 + f0]) = ov;
}

// ---- GEMM2 via MFMA (+scores2): hp2b[N,64] = h1b[N,512] @ w2bT^T --------
// Block 256 thr = 4 waves; wave: 16 nodes x 64 cols, K=512.
__global__ __launch_bounds__(256) void k_gemm2(const unsigned short* __restrict__ h1b,
                                               const unsigned short* __restrict__ w2bT,
                                               const float* __restrict__ w2sv,
                                               const float* __restrict__ w2dv,
                                               unsigned short* __restrict__ hp2b,
                                               float* __restrict__ s2s,
                                               float* __restrict__ s2d) {
  __shared__ float wsv[512], wdv[512];
  int t = threadIdx.x;
  for (int i = t; i < 512; i += 256) { wsv[i] = w2sv[i]; wdv[i] = w2dv[i]; }
  __syncthreads();
  int w = t >> 6, lane = t & 63;
  int lrow = lane & 15, lq = lane >> 4;
  int nb = blockIdx.x * 64 + w * 16;
  if (nb >= N_NODESC) return;
  f32x4 acc[4] = {};
  float ssp = 0.f, ddp = 0.f;
  const unsigned short* arowp = h1b + (size_t)(nb + lrow) * F1;
#pragma unroll 4
  for (int kq = 0; kq < 16; ++kq) {
    int kbase = kq * 32 + lq * 8;
    bf16x8 a = *reinterpret_cast<const bf16x8*>(arowp + kbase);
#pragma unroll
    for (int i = 0; i < 8; ++i) {
      float f = bf2f((unsigned short)a[i]);
      ssp += f * wsv[kbase + i];
      ddp += f * wdv[kbase + i];
    }
#pragma unroll
    for (int ct = 0; ct < 4; ++ct) {
      bf16x8 b = *reinterpret_cast<const bf16x8*>(w2bT + (size_t)(ct * 16 + lrow) * F1 + kbase);
      acc[ct] = __builtin_amdgcn_mfma_f32_16x16x32_bf16(a, b, acc[ct], 0, 0, 0);
    }
  }
  ssp += __shfl_xor(ssp, 16); ssp += __shfl_xor(ssp, 32);
  ddp += __shfl_xor(ddp, 16); ddp += __shfl_xor(ddp, 32);
  if (lane < 16) { s2s[nb + lane] = ssp; s2d[nb + lane] = ddp; }
#pragma unroll
  for (int ct = 0; ct < 4; ++ct) {
    int col = ct * 16 + lrow;
#pragma unroll
    for (int r = 0; r < 4; ++r)
      hp2b[(size_t)(nb + lq * 4 + r) * HID + col] = f2bf(acc[ct][r]);
  }
}

// ---- layer-2 aggregate: SINGLE PASS + bias + pooled atomicAdd -----------
__global__ __launch_bounds__(256) void k_agg2(const int* __restrict__ rowstart,
                                              const int* __restrict__ esrc,
                                              const unsigned short* __restrict__ hp2b,
                                              const float* __restrict__ s2s,
                                              const float* __restrict__ s2d,
                                              const float* __restrict__ b2,
                                              const int* __restrict__ batch,
                                              float* __restrict__ pooled) {
  int n = blockIdx.x * 4 + (threadIdx.x >> 6);
  int lane = threadIdx.x & 63;
  int half = lane >> 5;
  int fl = lane & 31;
  int r0 = rowstart[n], dg = rowstart[n + 1] - r0;
  float sdst = s2d[n];
  float ax = 0.f, ay = 0.f, dsum = 0.f;
  for (int base = 0; base < dg; base += 32) {
    int i = base + fl;
    float p = 0.f;
    int s = 0;
    if (i < dg) {
      s = esrc[r0 + i];
      p = __expf(lrelu(s2s[s] + sdst));
    }
    dsum += p;
    int cnt = min(32, dg - base);
    for (int j = 0; j < cnt; j += 2) {
      int jj = j + half;
      float pj = __shfl(p, jj, 32);
      int sj = __shfl(s, jj, 32);
      ushort2 hv = *reinterpret_cast<const ushort2*>(&hp2b[(size_t)sj * 64 + fl * 2]);
      ax += pj * bf2f(hv.x);
      ay += pj * bf2f(hv.y);
    }
  }
#pragma unroll
  for (int o = 1; o < 32; o <<= 1) dsum += __shfl_xor(dsum, o);
  float inv = 1.f / (dsum + 1e-16f);
  ax += __shfl_xor(ax, 32);
  ay += __shfl_xor(ay, 32);
  int f = 2 * fl + half;
  float o = (half ? ay : ax) * inv + b2[f];
  atomicAdd(&pooled[batch[n] * 64 + f], o);
}

// ---- final: out[512,40000] = pooled[512,64] @ Wp[64,40000] + bp ---------
__global__ __launch_bounds__(256) void k_final(const float* __restrict__ pooled,
                                               const float* __restrict__ Wp,
                                               const float* __restrict__ bp,
                                               float* __restrict__ out) {
  int v = blockIdx.x * 256 + threadIdx.x;
  bool valid = v < VOCAB_C;
  float w[64];
  float bpv = 0.f;
  if (valid) {
#pragma unroll
    for (int c = 0; c < 64; ++c) w[c] = Wp[(size_t)c * VOCAB_C + v];
    bpv = bp[v];
  }
  __shared__ float ps[64 * 64];  // 16 KB
  int g0 = blockIdx.y * 64;
  const float4* psrc = reinterpret_cast<const float4*>(pooled + (size_t)g0 * 64);
  for (int idx = threadIdx.x; idx < 1024; idx += 256)
    reinterpret_cast<float4*>(ps)[idx] = psrc[idx];
  __syncthreads();
  for (int gl = 0; gl < 64; ++gl) {
    const float4* pr4 = reinterpret_cast<const float4*>(&ps[gl * 64]);
    float acc = bpv;
#pragma unroll
    for (int c4 = 0; c4 < 16; ++c4) {
      float4 pv = pr4[c4];
      acc += pv.x * w[c4 * 4 + 0] + pv.y * w[c4 * 4 + 1] + pv.z * w[c4 * 4 + 2] + pv.w * w[c4 * 4 + 3];
    }
    if (valid) out[(size_t)(g0 + gl) * VOCAB_C + v] = acc;
  }
}

extern "C" void kernel_launch(void* const* d_in, const int* in_sizes, int n_in,
                              void* d_out, int out_size, void* d_ws, size_t ws_size,
                              hipStream_t stream) {
  const int*   x     = (const int*)d_in[0];
  const int*   ei    = (const int*)d_in[1];
  const int*   batch = (const int*)d_in[2];
  const float* emb   = (const float*)d_in[3];
  const float* W1    = (const float*)d_in[4];
  const float* as1   = (const float*)d_in[5];
  const float* ad1   = (const float*)d_in[6];
  const float* b1    = (const float*)d_in[7];
  const float* W2    = (const float*)d_in[8];
  const float* as2   = (const float*)d_in[9];
  const float* ad2   = (const float*)d_in[10];
  const float* b2    = (const float*)d_in[11];
  const float* Wp    = (const float*)d_in[12];
  const float* bp    = (const float*)d_in[13];
  float* out = (float*)d_out;

  char* ws = (char*)d_ws;
  size_t off = 0;
#define WS_ALLOC(T, name, bytes) T name = (T)(ws + off); off += (((size_t)(bytes)) + 255) & ~(size_t)255;
  WS_ALLOC(unsigned short*, hbf,  (size_t)N_NODESC * HID * 2)
  WS_ALLOC(unsigned short*, hp1b, (size_t)N_NODESC * F1 * 2)
  WS_ALLOC(unsigned short*, h1b,  (size_t)N_NODESC * F1 * 2)
  WS_ALLOC(unsigned short*, hp2b, (size_t)N_NODESC * HID * 2)
  WS_ALLOC(unsigned short*, w1bT, 512 * 64 * 2)
  WS_ALLOC(unsigned short*, w2bT, 64 * 512 * 2)
  WS_ALLOC(float*, s1s,  (size_t)N_NODESC * HEADS_C * 4)
  WS_ALLOC(float*, s1d,  (size_t)N_NODESC * HEADS_C * 4)
  WS_ALLOC(float*, s2s,  (size_t)N_NODESC * 4)
  WS_ALLOC(float*, s2d,  (size_t)N_NODESC * 4)
  WS_ALLOC(float*, pooled, (size_t)N_GR * HID * 4)
  WS_ALLOC(float*, wa1s, 8 * 64 * 4)
  WS_ALLOC(float*, wa1d, 8 * 64 * 4)
  WS_ALLOC(float*, w2sv, 512 * 4)
  WS_ALLOC(float*, w2dv, 512 * 4)
  WS_ALLOC(int*,   deg,      (size_t)N_NODESC * 4)
  WS_ALLOC(int*,   rowstart, (size_t)(N_NODESC + 1) * 4)
  WS_ALLOC(int*,   cursor,   (size_t)N_NODESC * 4)
  WS_ALLOC(int*,   esrc,     (size_t)E_TOT * 4)
#undef WS_ALLOC
  (void)ws_size; (void)in_sizes; (void)n_in; (void)out_size;

  hipMemsetAsync(deg, 0, (size_t)N_NODESC * 4, stream);
  hipMemsetAsync(cursor, 0, (size_t)N_NODESC * 4, stream);
  hipMemsetAsync(pooled, 0, (size_t)N_GR * HID * 4, stream);

  int ethreads = 256, eblocks = (E_TOT + 255) / 256;
  k_deg<<<eblocks, ethreads, 0, stream>>>(ei, deg);
  k_scan<<<1, 1024, 0, stream>>>(deg, rowstart);
  k_scatter<<<eblocks, ethreads, 0, stream>>>(ei, rowstart, cursor, esrc);
  k_prep<<<1, 512, 0, stream>>>(W1, as1, ad1, W2, as2, ad2, wa1s, wa1d, w2sv, w2dv);
  k_wconv<<<256, 256, 0, stream>>>(W1, W2, w1bT, w2bT);

  k_embed<<<N_NODESC / 4, 256, 0, stream>>>(x, emb, wa1s, wa1d, hbf, s1s, s1d);
  k_gemm1<<<N_NODESC / 16, 256, 0, stream>>>(hbf, w1bT, hp1b);
  k_agg1<<<N_NODESC / 4, 256, 0, stream>>>(rowstart, esrc, hp1b, s1s, s1d, b1, h1b);

  k_gemm2<<<(N_NODESC + 63) / 64, 256, 0, stream>>>(h1b, w2bT, w2sv, w2dv, hp2b, s2s, s2d);
  k_agg2<<<N_NODESC / 4, 256, 0, stream>>>(rowstart, esrc, hp2b, s2s, s2d, b2, batch, pooled);

  k_final<<<dim3((VOCAB_C + 255) / 256, 8), 256, 0, stream>>>(pooled, Wp, bp, out);
}

// Round 9
// 405.878 us; speedup vs baseline: 2.7406x; 1.1526x over previous
//
#include <hip/hip_runtime.h>
#include <hip/hip_bf16.h>

#define N_NODESC 50000
#define N_EDGESC 500000
#define E_TOT    (N_EDGESC + N_NODESC)   // 550000, with self loops
#define HID      64
#define HEADS_C  8
#define F1       (HEADS_C * HID)         // 512
#define VOCAB_C  40000
#define N_GR     512

typedef __attribute__((ext_vector_type(8))) short bf16x8;
typedef __attribute__((ext_vector_type(4))) float f32x4;

__device__ __forceinline__ float lrelu(float x) { return x > 0.f ? x : 0.2f * x; }
__device__ __forceinline__ float bf2f(unsigned short u) {
  return __uint_as_float(((unsigned int)u) << 16);
}
__device__ __forceinline__ unsigned short f2bf(float f) {
  unsigned int u = __float_as_uint(f);
  unsigned int r = (u + 0x7fffu + ((u >> 16) & 1u)) >> 16;
  return (unsigned short)r;
}

// ---- zero scratch (replaces 3 memsets) ----------------------------------
__global__ void k_zero(int* __restrict__ deg, int* __restrict__ cursor,
                       float* __restrict__ pooled) {
  int i = blockIdx.x * 256 + threadIdx.x;
  if (i < N_NODESC) { deg[i] = 0; cursor[i] = 0; }
  if (i < N_GR * HID) pooled[i] = 0.f;
}

// ---- CSR build ----------------------------------------------------------
__global__ void k_deg(const int* __restrict__ ei, int* __restrict__ deg) {
  int e = blockIdx.x * blockDim.x + threadIdx.x;
  if (e >= E_TOT) return;
  int dst = (e < N_EDGESC) ? ei[N_EDGESC + e] : (e - N_EDGESC);
  atomicAdd(&deg[dst], 1);
}

__global__ void k_scan(const int* __restrict__ deg, int* __restrict__ rowstart) {
  __shared__ int part[1024];
  const int ITEMS = 49;  // 1024*49 = 50176 >= 50000
  int t = threadIdx.x;
  int lo = t * ITEMS, hi = min(lo + ITEMS, N_NODESC);
  int s = 0;
  for (int i = lo; i < hi; ++i) s += deg[i];
  part[t] = s;
  __syncthreads();
  for (int o = 1; o < 1024; o <<= 1) {
    int v = (t >= o) ? part[t - o] : 0;
    __syncthreads();
    part[t] += v;
    __syncthreads();
  }
  int off = part[t] - s;  // exclusive
  for (int i = lo; i < hi; ++i) { rowstart[i] = off; off += deg[i]; }
  if (t == 1023) rowstart[N_NODESC] = part[1023];
}

__global__ void k_scatter(const int* __restrict__ ei, const int* __restrict__ rowstart,
                          int* __restrict__ cursor, int* __restrict__ esrc) {
  int e = blockIdx.x * blockDim.x + threadIdx.x;
  if (e >= E_TOT) return;
  int src, dst;
  if (e < N_EDGESC) { src = ei[e]; dst = ei[N_EDGESC + e]; }
  else { src = dst = e - N_EDGESC; }
  int slot = rowstart[dst] + atomicAdd(&cursor[dst], 1);
  esrc[slot] = src;
}

// ---- prep (attn-vector folds) + weight convert/transpose, one kernel ----
// blocks 0..63: w1bT; 64..127: w2bT; 128: prep folds.
__global__ __launch_bounds__(512) void k_prepwconv(const float* __restrict__ W1,
                                                   const float* __restrict__ as1,
                                                   const float* __restrict__ ad1,
                                                   const float* __restrict__ W2,
                                                   const float* __restrict__ as2,
                                                   const float* __restrict__ ad2,
                                                   float* __restrict__ wa1s,
                                                   float* __restrict__ wa1d,
                                                   float* __restrict__ w2sv,
                                                   float* __restrict__ w2dv,
                                                   unsigned short* __restrict__ w1bT,
                                                   unsigned short* __restrict__ w2bT) {
  int b = blockIdx.x, t = threadIdx.x;
  if (b < 64) {
    int g = b * 512 + t;           // 0..32767
    int c = g >> 6, k = g & 63;
    w1bT[g] = f2bf(W1[(size_t)k * F1 + c]);
  } else if (b < 128) {
    int idx = (b - 64) * 512 + t;  // 0..32767
    int c = idx >> 9, k = idx & 511;
    w2bT[idx] = f2bf(W2[(size_t)k * HID + c]);
  } else {
    int k = t >> 3, h = t & 7;
    float ss = 0.f, dd = 0.f;
    for (int c = 0; c < 64; ++c) {
      float w = W1[k * F1 + h * 64 + c];
      ss += w * as1[h * 64 + c];
      dd += w * ad1[h * 64 + c];
    }
    wa1s[h * 64 + k] = ss;
    wa1d[h * 64 + k] = dd;
    float s2 = 0.f, d2 = 0.f;
    for (int c = 0; c < 64; ++c) {
      float w = W2[t * 64 + c];
      s2 += w * as2[c];
      d2 += w * ad2[c];
    }
    w2sv[t] = s2;
    w2dv[t] = d2;
  }
}

// ---- GEMM1 fused (embed gather + scores1 + MFMA + coalesced store) ------
// Block 256 thr = 4 waves; 16 nodes/block; wave w covers cols [128w,128w+128).
__global__ __launch_bounds__(256) void k_gemm1(const int* __restrict__ x,
                                               const float* __restrict__ emb,
                                               const unsigned short* __restrict__ w1bT,
                                               const float* __restrict__ wa1s,
                                               const float* __restrict__ wa1d,
                                               unsigned short* __restrict__ hp1b,
                                               float* __restrict__ s1s,
                                               float* __restrict__ s1d) {
  __shared__ unsigned short As[16][72];    // A tile, padded: b128 reads <=2-way
  __shared__ unsigned short Ts[16][520];   // store staging, rows 16B-aligned
  __shared__ float was[512], wad[512];
  int t = threadIdx.x;
  int n0 = blockIdx.x * 16;  // 3125 blocks exact
  was[t] = wa1s[t]; was[t + 256] = wa1s[t + 256];
  wad[t] = wa1d[t]; wad[t + 256] = wa1d[t + 256];
  {  // stage A: thread (row=t>>4, q=t&15) loads float4 of emb row
    int row = t >> 4, q = t & 15;
    int xr = x[n0 + row];
    float4 hv = reinterpret_cast<const float4*>(emb)[(size_t)xr * 16 + q];
    ushort4 u;
    u.x = f2bf(hv.x); u.y = f2bf(hv.y); u.z = f2bf(hv.z); u.w = f2bf(hv.w);
    *reinterpret_cast<ushort4*>(&As[row][q * 4]) = u;
  }
  __syncthreads();
  {  // scores1: thread = (node=t&15, head=(t>>4)&7, sel=t>>7)
    int node = t & 15, head = (t >> 4) & 7, sel = t >> 7;
    const float* wa = sel ? wad : was;
    float a = 0.f;
#pragma unroll 8
    for (int k = 0; k < 64; ++k) a += bf2f(As[node][k]) * wa[head * 64 + k];
    (sel ? s1d : s1s)[(size_t)(n0 + node) * 8 + head] = a;
  }
  int w = t >> 6, lane = t & 63;
  int lrow = lane & 15, lq = lane >> 4;
  bf16x8 a0 = *reinterpret_cast<const bf16x8*>(&As[lrow][lq * 8]);
  bf16x8 a1 = *reinterpret_cast<const bf16x8*>(&As[lrow][32 + lq * 8]);
  int c0 = w * 128;
  f32x4 acc[8] = {};
#pragma unroll
  for (int ct = 0; ct < 8; ++ct) {
    int col = c0 + ct * 16 + lrow;
    const bf16x8* brow = reinterpret_cast<const bf16x8*>(w1bT + (size_t)col * 64 + lq * 8);
    acc[ct] = __builtin_amdgcn_mfma_f32_16x16x32_bf16(a0, brow[0], acc[ct], 0, 0, 0);
    acc[ct] = __builtin_amdgcn_mfma_f32_16x16x32_bf16(a1, brow[4], acc[ct], 0, 0, 0);
  }
#pragma unroll
  for (int ct = 0; ct < 8; ++ct) {
    int col = c0 + ct * 16 + lrow;
#pragma unroll
    for (int r = 0; r < 4; ++r)
      Ts[lq * 4 + r][col] = f2bf(acc[ct][r]);
  }
  __syncthreads();
  for (int i = t; i < 1024; i += 256) {  // 16 rows x 512 cols bf16, 16B/thr
    int r = i >> 6, c16 = i & 63;
    reinterpret_cast<uint4*>(&hp1b[(size_t)(n0 + r) * F1])[c16] =
        *reinterpret_cast<const uint4*>(&Ts[r][c16 * 8]);
  }
}

// ---- layer-1 aggregate: single pass, ONE WAVE per node ------------------
__global__ __launch_bounds__(256) void k_agg1(const int* __restrict__ rowstart,
                                              const int* __restrict__ esrc,
                                              const unsigned short* __restrict__ hp1b,
                                              const float* __restrict__ s1s,
                                              const float* __restrict__ s1d,
                                              const float* __restrict__ b1,
                                              unsigned short* __restrict__ h1b) {
  int n = blockIdx.x * 4 + (threadIdx.x >> 6);
  int L = threadIdx.x & 63;
  int eh = L >> 3;  // edge slot (p-phase)
  int hh = L & 7;   // head (p-phase)
  int r0 = rowstart[n], dg = rowstart[n + 1] - r0;
  float sdst = s1d[n * 8 + hh];
  float acc[8] = {};
  float dsum = 0.f;
  int myh = L >> 3;  // head of this lane's feature slice
  for (int base = 0; base < dg; base += 8) {
    int i = base + eh;
    float p = 0.f;
    int s = 0;
    if (i < dg) {
      s = esrc[r0 + i];
      p = __expf(lrelu(s1s[s * 8 + hh] + sdst));
    }
    dsum += p;
    int cnt = min(8, dg - base);
    for (int j = 0; j < cnt; ++j) {
      float pj = __shfl(p, (j << 3) | myh);
      int sj = __shfl(s, j << 3);
      uint4 u = *reinterpret_cast<const uint4*>(&hp1b[(size_t)sj * F1 + L * 8]);
      acc[0] += pj * bf2f((unsigned short)(u.x & 0xffff));
      acc[1] += pj * bf2f((unsigned short)(u.x >> 16));
      acc[2] += pj * bf2f((unsigned short)(u.y & 0xffff));
      acc[3] += pj * bf2f((unsigned short)(u.y >> 16));
      acc[4] += pj * bf2f((unsigned short)(u.z & 0xffff));
      acc[5] += pj * bf2f((unsigned short)(u.z >> 16));
      acc[6] += pj * bf2f((unsigned short)(u.w & 0xffff));
      acc[7] += pj * bf2f((unsigned short)(u.w >> 16));
    }
  }
  dsum += __shfl_xor(dsum, 8);
  dsum += __shfl_xor(dsum, 16);
  dsum += __shfl_xor(dsum, 32);
  float inv = 1.f / (__shfl(dsum, myh) + 1e-16f);
  int f0 = L * 8;
  float o[8];
#pragma unroll
  for (int k = 0; k < 8; ++k) {
    float v = acc[k] * inv + b1[f0 + k];
    o[k] = v > 0.f ? v : (__expf(v) - 1.f);
  }
  uint4 ov;
  ov.x = (unsigned int)f2bf(o[0]) | ((unsigned int)f2bf(o[1]) << 16);
  ov.y = (unsigned int)f2bf(o[2]) | ((unsigned int)f2bf(o[3]) << 16);
  ov.z = (unsigned int)f2bf(o[4]) | ((unsigned int)f2bf(o[5]) << 16);
  ov.w = (unsigned int)f2bf(o[6]) | ((unsigned int)f2bf(o[7]) << 16);
  *reinterpret_cast<uint4*>(&h1b[(size_t)n * F1 + f0]) = ov;
}

// ---- GEMM2 via MFMA (+scores2): hp2b[N,64] = h1b[N,512] @ w2bT^T --------
__global__ __launch_bounds__(256) void k_gemm2(const unsigned short* __restrict__ h1b,
                                               const unsigned short* __restrict__ w2bT,
                                               const float* __restrict__ w2sv,
                                               const float* __restrict__ w2dv,
                                               unsigned short* __restrict__ hp2b,
                                               float* __restrict__ s2s,
                                               float* __restrict__ s2d) {
  __shared__ float wsv[512], wdv[512];
  int t = threadIdx.x;
  for (int i = t; i < 512; i += 256) { wsv[i] = w2sv[i]; wdv[i] = w2dv[i]; }
  __syncthreads();
  int w = t >> 6, lane = t & 63;
  int lrow = lane & 15, lq = lane >> 4;
  int nb = blockIdx.x * 64 + w * 16;
  if (nb >= N_NODESC) return;
  f32x4 acc[4] = {};
  float ssp = 0.f, ddp = 0.f;
  const unsigned short* arowp = h1b + (size_t)(nb + lrow) * F1;
#pragma unroll 4
  for (int kq = 0; kq < 16; ++kq) {
    int kbase = kq * 32 + lq * 8;
    bf16x8 a = *reinterpret_cast<const bf16x8*>(arowp + kbase);
#pragma unroll
    for (int i = 0; i < 8; ++i) {
      float f = bf2f((unsigned short)a[i]);
      ssp += f * wsv[kbase + i];
      ddp += f * wdv[kbase + i];
    }
#pragma unroll
    for (int ct = 0; ct < 4; ++ct) {
      bf16x8 b = *reinterpret_cast<const bf16x8*>(w2bT + (size_t)(ct * 16 + lrow) * F1 + kbase);
      acc[ct] = __builtin_amdgcn_mfma_f32_16x16x32_bf16(a, b, acc[ct], 0, 0, 0);
    }
  }
  ssp += __shfl_xor(ssp, 16); ssp += __shfl_xor(ssp, 32);
  ddp += __shfl_xor(ddp, 16); ddp += __shfl_xor(ddp, 32);
  if (lane < 16) { s2s[nb + lane] = ssp; s2d[nb + lane] = ddp; }
#pragma unroll
  for (int ct = 0; ct < 4; ++ct) {
    int col = ct * 16 + lrow;
#pragma unroll
    for (int r = 0; r < 4; ++r)
      hp2b[(size_t)(nb + lq * 4 + r) * HID + col] = f2bf(acc[ct][r]);
  }
}

// ---- layer-2 aggregate: SINGLE PASS + bias + pooled atomicAdd -----------
__global__ __launch_bounds__(256) void k_agg2(const int* __restrict__ rowstart,
                                              const int* __restrict__ esrc,
                                              const unsigned short* __restrict__ hp2b,
                                              const float* __restrict__ s2s,
                                              const float* __restrict__ s2d,
                                              const float* __restrict__ b2,
                                              const int* __restrict__ batch,
                                              float* __restrict__ pooled) {
  int n = blockIdx.x * 4 + (threadIdx.x >> 6);
  int lane = threadIdx.x & 63;
  int half = lane >> 5;
  int fl = lane & 31;
  int r0 = rowstart[n], dg = rowstart[n + 1] - r0;
  float sdst = s2d[n];
  float ax = 0.f, ay = 0.f, dsum = 0.f;
  for (int base = 0; base < dg; base += 32) {
    int i = base + fl;
    float p = 0.f;
    int s = 0;
    if (i < dg) {
      s = esrc[r0 + i];
      p = __expf(lrelu(s2s[s] + sdst));
    }
    dsum += p;
    int cnt = min(32, dg - base);
    for (int j = 0; j < cnt; j += 2) {
      int jj = j + half;
      float pj = __shfl(p, jj, 32);
      int sj = __shfl(s, jj, 32);
      ushort2 hv = *reinterpret_cast<const ushort2*>(&hp2b[(size_t)sj * 64 + fl * 2]);
      ax += pj * bf2f(hv.x);
      ay += pj * bf2f(hv.y);
    }
  }
#pragma unroll
  for (int o = 1; o < 32; o <<= 1) dsum += __shfl_xor(dsum, o);
  float inv = 1.f / (dsum + 1e-16f);
  ax += __shfl_xor(ax, 32);
  ay += __shfl_xor(ay, 32);
  int f = 2 * fl + half;
  float o = (half ? ay : ax) * inv + b2[f];
  atomicAdd(&pooled[batch[n] * 64 + f], o);
}

// ---- final: out[512,40000] = pooled[512,64] @ Wp[64,40000] + bp ---------
__global__ __launch_bounds__(256) void k_final(const float* __restrict__ pooled,
                                               const float* __restrict__ Wp,
                                               const float* __restrict__ bp,
                                               float* __restrict__ out) {
  int v = blockIdx.x * 256 + threadIdx.x;
  bool valid = v < VOCAB_C;
  float w[64];
  float bpv = 0.f;
  if (valid) {
#pragma unroll
    for (int c = 0; c < 64; ++c) w[c] = Wp[(size_t)c * VOCAB_C + v];
    bpv = bp[v];
  }
  __shared__ float ps[64 * 64];  // 16 KB
  int g0 = blockIdx.y * 64;
  const float4* psrc = reinterpret_cast<const float4*>(pooled + (size_t)g0 * 64);
  for (int idx = threadIdx.x; idx < 1024; idx += 256)
    reinterpret_cast<float4*>(ps)[idx] = psrc[idx];
  __syncthreads();
  for (int gl = 0; gl < 64; ++gl) {
    const float4* pr4 = reinterpret_cast<const float4*>(&ps[gl * 64]);
    float acc = bpv;
#pragma unroll
    for (int c4 = 0; c4 < 16; ++c4) {
      float4 pv = pr4[c4];
      acc += pv.x * w[c4 * 4 + 0] + pv.y * w[c4 * 4 + 1] + pv.z * w[c4 * 4 + 2] + pv.w * w[c4 * 4 + 3];
    }
    if (valid) out[(size_t)(g0 + gl) * VOCAB_C + v] = acc;
  }
}

extern "C" void kernel_launch(void* const* d_in, const int* in_sizes, int n_in,
                              void* d_out, int out_size, void* d_ws, size_t ws_size,
                              hipStream_t stream) {
  const int*   x     = (const int*)d_in[0];
  const int*   ei    = (const int*)d_in[1];
  const int*   batch = (const int*)d_in[2];
  const float* emb   = (const float*)d_in[3];
  const float* W1    = (const float*)d_in[4];
  const float* as1   = (const float*)d_in[5];
  const float* ad1   = (const float*)d_in[6];
  const float* b1    = (const float*)d_in[7];
  const float* W2    = (const float*)d_in[8];
  const float* as2   = (const float*)d_in[9];
  const float* ad2   = (const float*)d_in[10];
  const float* b2    = (const float*)d_in[11];
  const float* Wp    = (const float*)d_in[12];
  const float* bp    = (const float*)d_in[13];
  float* out = (float*)d_out;

  char* ws = (char*)d_ws;
  size_t off = 0;
#define WS_ALLOC(T, name, bytes) T name = (T)(ws + off); off += (((size_t)(bytes)) + 255) & ~(size_t)255;
  WS_ALLOC(unsigned short*, hp1b, (size_t)N_NODESC * F1 * 2)
  WS_ALLOC(unsigned short*, h1b,  (size_t)N_NODESC * F1 * 2)
  WS_ALLOC(unsigned short*, hp2b, (size_t)N_NODESC * HID * 2)
  WS_ALLOC(unsigned short*, w1bT, 512 * 64 * 2)
  WS_ALLOC(unsigned short*, w2bT, 64 * 512 * 2)
  WS_ALLOC(float*, s1s,  (size_t)N_NODESC * HEADS_C * 4)
  WS_ALLOC(float*, s1d,  (size_t)N_NODESC * HEADS_C * 4)
  WS_ALLOC(float*, s2s,  (size_t)N_NODESC * 4)
  WS_ALLOC(float*, s2d,  (size_t)N_NODESC * 4)
  WS_ALLOC(float*, pooled, (size_t)N_GR * HID * 4)
  WS_ALLOC(float*, wa1s, 8 * 64 * 4)
  WS_ALLOC(float*, wa1d, 8 * 64 * 4)
  WS_ALLOC(float*, w2sv, 512 * 4)
  WS_ALLOC(float*, w2dv, 512 * 4)
  WS_ALLOC(int*,   deg,      (size_t)N_NODESC * 4)
  WS_ALLOC(int*,   rowstart, (size_t)(N_NODESC + 1) * 4)
  WS_ALLOC(int*,   cursor,   (size_t)N_NODESC * 4)
  WS_ALLOC(int*,   esrc,     (size_t)E_TOT * 4)
#undef WS_ALLOC
  (void)ws_size; (void)in_sizes; (void)n_in; (void)out_size;

  int ethreads = 256, eblocks = (E_TOT + 255) / 256;
  k_zero<<<(N_NODESC + 255) / 256, 256, 0, stream>>>(deg, cursor, pooled);
  k_deg<<<eblocks, ethreads, 0, stream>>>(ei, deg);
  k_scan<<<1, 1024, 0, stream>>>(deg, rowstart);
  k_scatter<<<eblocks, ethreads, 0, stream>>>(ei, rowstart, cursor, esrc);
  k_prepwconv<<<129, 512, 0, stream>>>(W1, as1, ad1, W2, as2, ad2,
                                       wa1s, wa1d, w2sv, w2dv, w1bT, w2bT);

  k_gemm1<<<N_NODESC / 16, 256, 0, stream>>>(x, emb, w1bT, wa1s, wa1d, hp1b, s1s, s1d);
  k_agg1<<<N_NODESC / 4, 256, 0, stream>>>(rowstart, esrc, hp1b, s1s, s1d, b1, h1b);

  k_gemm2<<<(N_NODESC + 63) / 64, 256, 0, stream>>>(h1b, w2bT, w2sv, w2dv, hp2b, s2s, s2d);
  k_agg2<<<N_NODESC / 4, 256, 0, stream>>>(rowstart, esrc, hp2b, s2s, s2d, b2, batch, pooled);

  k_final<<<dim3((VOCAB_C + 255) / 256, 8), 256, 0, stream>>>(pooled, Wp, bp, out);
}

// Round 10
// 317.000 us; speedup vs baseline: 3.5090x; 1.2804x over previous
//
#include <hip/hip_runtime.h>
#include <hip/hip_bf16.h>

#define N_NODESC 50000
#define N_EDGESC 500000
#define E_TOT    (N_EDGESC + N_NODESC)   // 550000, with self loops
#define HID      64
#define HEADS_C  8
#define F1       (HEADS_C * HID)         // 512
#define VOCAB_C  40000
#define N_GR     512
#define SCAN_B   196                     // ceil(50000/256)

typedef __attribute__((ext_vector_type(8))) short bf16x8;
typedef __attribute__((ext_vector_type(4))) float f32x4;

__device__ __forceinline__ float lrelu(float x) { return x > 0.f ? x : 0.2f * x; }
__device__ __forceinline__ float bf2f(unsigned short u) {
  return __uint_as_float(((unsigned int)u) << 16);
}
__device__ __forceinline__ unsigned short f2bf(float f) {
  unsigned int u = __float_as_uint(f);
  unsigned int r = (u + 0x7fffu + ((u >> 16) & 1u)) >> 16;
  return (unsigned short)r;
}

// ---- zero scratch -------------------------------------------------------
__global__ void k_zero(int* __restrict__ deg, int* __restrict__ cursor,
                       float* __restrict__ pooled) {
  int i = blockIdx.x * 256 + threadIdx.x;
  if (i < N_NODESC) { deg[i] = 0; cursor[i] = 0; }
  if (i < N_GR * HID) pooled[i] = 0.f;
}

// ---- CSR build ----------------------------------------------------------
__global__ void k_deg(const int* __restrict__ ei, int* __restrict__ deg) {
  int e = blockIdx.x * blockDim.x + threadIdx.x;
  if (e >= E_TOT) return;
  int dst = (e < N_EDGESC) ? ei[N_EDGESC + e] : (e - N_EDGESC);
  atomicAdd(&deg[dst], 1);
}

// multi-block scan: scan1 (per-block inclusive) -> scan2 (partials) -> scan3
__global__ __launch_bounds__(256) void k_scan1(const int* __restrict__ deg,
                                               int* __restrict__ rowtmp,
                                               int* __restrict__ partials) {
  __shared__ int sh[256];
  int b = blockIdx.x, t = threadIdx.x, i = b * 256 + t;
  int d = (i < N_NODESC) ? deg[i] : 0;
  sh[t] = d;
  __syncthreads();
  for (int o = 1; o < 256; o <<= 1) {
    int v = (t >= o) ? sh[t - o] : 0;
    __syncthreads();
    sh[t] += v;
    __syncthreads();
  }
  if (i < N_NODESC) rowtmp[i] = sh[t];  // inclusive within block
  if (t == 255) partials[b] = sh[255];
}

__global__ __launch_bounds__(256) void k_scan2(int* __restrict__ partials,
                                               int* __restrict__ rowN) {
  __shared__ int sh[256];
  int t = threadIdx.x;
  sh[t] = (t < SCAN_B) ? partials[t] : 0;
  __syncthreads();
  for (int o = 1; o < 256; o <<= 1) {
    int v = (t >= o) ? sh[t - o] : 0;
    __syncthreads();
    sh[t] += v;
    __syncthreads();
  }
  if (t < SCAN_B) partials[t] = sh[t];  // inclusive
  if (t == SCAN_B - 1) rowN[0] = sh[t]; // total -> rowstart[N]
}

__global__ __launch_bounds__(256) void k_scan3(const int* __restrict__ deg,
                                               const int* __restrict__ rowtmp,
                                               const int* __restrict__ partials,
                                               int* __restrict__ rowstart) {
  int b = blockIdx.x;
  int i = b * 256 + threadIdx.x;
  if (i >= N_NODESC) return;
  int base = b ? partials[b - 1] : 0;
  rowstart[i] = base + rowtmp[i] - deg[i];  // exclusive
}

__global__ void k_scatter(const int* __restrict__ ei, const int* __restrict__ rowstart,
                          int* __restrict__ cursor, int* __restrict__ esrc) {
  int e = blockIdx.x * blockDim.x + threadIdx.x;
  if (e >= E_TOT) return;
  int src, dst;
  if (e < N_EDGESC) { src = ei[e]; dst = ei[N_EDGESC + e]; }
  else { src = dst = e - N_EDGESC; }
  int slot = rowstart[dst] + atomicAdd(&cursor[dst], 1);
  esrc[slot] = src;
}

// ---- prep (attn-vector folds) + weight convert/transpose ----------------
__global__ __launch_bounds__(512) void k_prepwconv(const float* __restrict__ W1,
                                                   const float* __restrict__ as1,
                                                   const float* __restrict__ ad1,
                                                   const float* __restrict__ W2,
                                                   const float* __restrict__ as2,
                                                   const float* __restrict__ ad2,
                                                   float* __restrict__ wa1s,
                                                   float* __restrict__ wa1d,
                                                   float* __restrict__ w2sv,
                                                   float* __restrict__ w2dv,
                                                   unsigned short* __restrict__ w1bT,
                                                   unsigned short* __restrict__ w2bT) {
  int b = blockIdx.x, t = threadIdx.x;
  if (b < 64) {
    int g = b * 512 + t;
    int c = g >> 6, k = g & 63;
    w1bT[g] = f2bf(W1[(size_t)k * F1 + c]);
  } else if (b < 128) {
    int idx = (b - 64) * 512 + t;
    int c = idx >> 9, k = idx & 511;
    w2bT[idx] = f2bf(W2[(size_t)k * HID + c]);
  } else {
    int k = t >> 3, h = t & 7;
    float ss = 0.f, dd = 0.f;
    for (int c = 0; c < 64; ++c) {
      float w = W1[k * F1 + h * 64 + c];
      ss += w * as1[h * 64 + c];
      dd += w * ad1[h * 64 + c];
    }
    wa1s[h * 64 + k] = ss;
    wa1d[h * 64 + k] = dd;
    float s2 = 0.f, d2 = 0.f;
    for (int c = 0; c < 64; ++c) {
      float w = W2[t * 64 + c];
      s2 += w * as2[c];
      d2 += w * ad2[c];
    }
    w2sv[t] = s2;
    w2dv[t] = d2;
  }
}

// ---- Wp tile-transpose to bf16: wpT[v][k] -------------------------------
__global__ __launch_bounds__(256) void k_wpt(const float* __restrict__ Wp,
                                             unsigned short* __restrict__ wpT) {
  __shared__ float ws[64][65];
  int v0 = blockIdx.x * 64;
  int t = threadIdx.x;
#pragma unroll
  for (int rep = 0; rep < 16; ++rep) {
    int idx = rep * 256 + t;
    int k = idx >> 6, v = idx & 63;
    ws[k][v] = Wp[(size_t)k * VOCAB_C + v0 + v];
  }
  __syncthreads();
#pragma unroll
  for (int rep = 0; rep < 16; ++rep) {
    int idx = rep * 256 + t;
    int v = idx >> 6, k = idx & 63;
    wpT[(size_t)(v0 + v) * 64 + k] = f2bf(ws[k][v]);
  }
}

// ---- GEMM1 fused (embed gather + scores1 + MFMA + coalesced store) ------
__global__ __launch_bounds__(256) void k_gemm1(const int* __restrict__ x,
                                               const float* __restrict__ emb,
                                               const unsigned short* __restrict__ w1bT,
                                               const float* __restrict__ wa1s,
                                               const float* __restrict__ wa1d,
                                               unsigned short* __restrict__ hp1b,
                                               float* __restrict__ s1s,
                                               float* __restrict__ s1d) {
  __shared__ unsigned short As[16][72];
  __shared__ unsigned short Ts[16][520];
  __shared__ float was[512], wad[512];
  int t = threadIdx.x;
  int n0 = blockIdx.x * 16;
  was[t] = wa1s[t]; was[t + 256] = wa1s[t + 256];
  wad[t] = wa1d[t]; wad[t + 256] = wa1d[t + 256];
  {
    int row = t >> 4, q = t & 15;
    int xr = x[n0 + row];
    float4 hv = reinterpret_cast<const float4*>(emb)[(size_t)xr * 16 + q];
    ushort4 u;
    u.x = f2bf(hv.x); u.y = f2bf(hv.y); u.z = f2bf(hv.z); u.w = f2bf(hv.w);
    *reinterpret_cast<ushort4*>(&As[row][q * 4]) = u;
  }
  __syncthreads();
  {
    int node = t & 15, head = (t >> 4) & 7, sel = t >> 7;
    const float* wa = sel ? wad : was;
    float a = 0.f;
#pragma unroll 8
    for (int k = 0; k < 64; ++k) a += bf2f(As[node][k]) * wa[head * 64 + k];
    (sel ? s1d : s1s)[(size_t)(n0 + node) * 8 + head] = a;
  }
  int w = t >> 6, lane = t & 63;
  int lrow = lane & 15, lq = lane >> 4;
  bf16x8 a0 = *reinterpret_cast<const bf16x8*>(&As[lrow][lq * 8]);
  bf16x8 a1 = *reinterpret_cast<const bf16x8*>(&As[lrow][32 + lq * 8]);
  int c0 = w * 128;
  f32x4 acc[8] = {};
#pragma unroll
  for (int ct = 0; ct < 8; ++ct) {
    int col = c0 + ct * 16 + lrow;
    const bf16x8* brow = reinterpret_cast<const bf16x8*>(w1bT + (size_t)col * 64 + lq * 8);
    acc[ct] = __builtin_amdgcn_mfma_f32_16x16x32_bf16(a0, brow[0], acc[ct], 0, 0, 0);
    acc[ct] = __builtin_amdgcn_mfma_f32_16x16x32_bf16(a1, brow[4], acc[ct], 0, 0, 0);
  }
#pragma unroll
  for (int ct = 0; ct < 8; ++ct) {
    int col = c0 + ct * 16 + lrow;
#pragma unroll
    for (int r = 0; r < 4; ++r)
      Ts[lq * 4 + r][col] = f2bf(acc[ct][r]);
  }
  __syncthreads();
  for (int i = t; i < 1024; i += 256) {
    int r = i >> 6, c16 = i & 63;
    reinterpret_cast<uint4*>(&hp1b[(size_t)(n0 + r) * F1])[c16] =
        *reinterpret_cast<const uint4*>(&Ts[r][c16 * 8]);
  }
}

// ---- layer-1 aggregate: single pass, one wave/node, prefetch pipeline ---
#define AGG1_BODY(J) {                                                        \
    float pj = __shfl(pc, ((J) << 3) | myh);                                  \
    int sj = __shfl(sc, (J) << 3);                                            \
    uint4 u = *reinterpret_cast<const uint4*>(&hp1b[(size_t)sj * F1 + L * 8]);\
    acc[0] += pj * bf2f((unsigned short)(u.x & 0xffff));                      \
    acc[1] += pj * bf2f((unsigned short)(u.x >> 16));                         \
    acc[2] += pj * bf2f((unsigned short)(u.y & 0xffff));                      \
    acc[3] += pj * bf2f((unsigned short)(u.y >> 16));                         \
    acc[4] += pj * bf2f((unsigned short)(u.z & 0xffff));                      \
    acc[5] += pj * bf2f((unsigned short)(u.z >> 16));                         \
    acc[6] += pj * bf2f((unsigned short)(u.w & 0xffff));                      \
    acc[7] += pj * bf2f((unsigned short)(u.w >> 16));                         \
  }
__global__ __launch_bounds__(256) void k_agg1(const int* __restrict__ rowstart,
                                              const int* __restrict__ esrc,
                                              const unsigned short* __restrict__ hp1b,
                                              const float* __restrict__ s1s,
                                              const float* __restrict__ s1d,
                                              const float* __restrict__ b1,
                                              unsigned short* __restrict__ h1b) {
  int n = blockIdx.x * 4 + (threadIdx.x >> 6);
  int L = threadIdx.x & 63;
  int eh = L >> 3;   // edge slot (p-phase)
  int hh = L & 7;    // head (p-phase)
  int myh = L >> 3;  // head of this lane's feature slice
  int r0 = rowstart[n], dg = rowstart[n + 1] - r0;
  float sdst = s1d[n * 8 + hh];
  float acc[8] = {};
  float dsum = 0.f;
  int s = 0; float p = 0.f;
  if (eh < dg) { s = esrc[r0 + eh]; p = __expf(lrelu(s1s[s * 8 + hh] + sdst)); }
  for (int base = 0; base < dg; base += 8) {
    dsum += p;
    float pc = p; int sc = s;
    // prefetch next chunk's weight (overlaps with row loads below)
    int inext = base + 8 + eh;
    s = 0; p = 0.f;
    if (inext < dg) { s = esrc[r0 + inext]; p = __expf(lrelu(s1s[s * 8 + hh] + sdst)); }
    int cnt = min(8, dg - base);
    if (cnt == 8) {
#pragma unroll
      for (int j = 0; j < 8; ++j) AGG1_BODY(j)
    } else {
      for (int j = 0; j < cnt; ++j) AGG1_BODY(j)
    }
  }
  dsum += __shfl_xor(dsum, 8);
  dsum += __shfl_xor(dsum, 16);
  dsum += __shfl_xor(dsum, 32);
  float inv = 1.f / (__shfl(dsum, myh) + 1e-16f);
  int f0 = L * 8;
  float o[8];
#pragma unroll
  for (int k = 0; k < 8; ++k) {
    float v = acc[k] * inv + b1[f0 + k];
    o[k] = v > 0.f ? v : (__expf(v) - 1.f);
  }
  uint4 ov;
  ov.x = (unsigned int)f2bf(o[0]) | ((unsigned int)f2bf(o[1]) << 16);
  ov.y = (unsigned int)f2bf(o[2]) | ((unsigned int)f2bf(o[3]) << 16);
  ov.z = (unsigned int)f2bf(o[4]) | ((unsigned int)f2bf(o[5]) << 16);
  ov.w = (unsigned int)f2bf(o[6]) | ((unsigned int)f2bf(o[7]) << 16);
  *reinterpret_cast<uint4*>(&h1b[(size_t)n * F1 + f0]) = ov;
}

// ---- GEMM2 via MFMA (+scores2) ------------------------------------------
__global__ __launch_bounds__(256) void k_gemm2(const unsigned short* __restrict__ h1b,
                                               const unsigned short* __restrict__ w2bT,
                                               const float* __restrict__ w2sv,
                                               const float* __restrict__ w2dv,
                                               unsigned short* __restrict__ hp2b,
                                               float* __restrict__ s2s,
                                               float* __restrict__ s2d) {
  __shared__ float wsv[512], wdv[512];
  int t = threadIdx.x;
  for (int i = t; i < 512; i += 256) { wsv[i] = w2sv[i]; wdv[i] = w2dv[i]; }
  __syncthreads();
  int w = t >> 6, lane = t & 63;
  int lrow = lane & 15, lq = lane >> 4;
  int nb = blockIdx.x * 64 + w * 16;
  if (nb >= N_NODESC) return;
  f32x4 acc[4] = {};
  float ssp = 0.f, ddp = 0.f;
  const unsigned short* arowp = h1b + (size_t)(nb + lrow) * F1;
#pragma unroll 4
  for (int kq = 0; kq < 16; ++kq) {
    int kbase = kq * 32 + lq * 8;
    bf16x8 a = *reinterpret_cast<const bf16x8*>(arowp + kbase);
#pragma unroll
    for (int i = 0; i < 8; ++i) {
      float f = bf2f((unsigned short)a[i]);
      ssp += f * wsv[kbase + i];
      ddp += f * wdv[kbase + i];
    }
#pragma unroll
    for (int ct = 0; ct < 4; ++ct) {
      bf16x8 b = *reinterpret_cast<const bf16x8*>(w2bT + (size_t)(ct * 16 + lrow) * F1 + kbase);
      acc[ct] = __builtin_amdgcn_mfma_f32_16x16x32_bf16(a, b, acc[ct], 0, 0, 0);
    }
  }
  ssp += __shfl_xor(ssp, 16); ssp += __shfl_xor(ssp, 32);
  ddp += __shfl_xor(ddp, 16); ddp += __shfl_xor(ddp, 32);
  if (lane < 16) { s2s[nb + lane] = ssp; s2d[nb + lane] = ddp; }
#pragma unroll
  for (int ct = 0; ct < 4; ++ct) {
    int col = ct * 16 + lrow;
#pragma unroll
    for (int r = 0; r < 4; ++r)
      hp2b[(size_t)(nb + lq * 4 + r) * HID + col] = f2bf(acc[ct][r]);
  }
}

// ---- layer-2 aggregate: SINGLE PASS + bias + pooled atomicAdd -----------
__global__ __launch_bounds__(256) void k_agg2(const int* __restrict__ rowstart,
                                              const int* __restrict__ esrc,
                                              const unsigned short* __restrict__ hp2b,
                                              const float* __restrict__ s2s,
                                              const float* __restrict__ s2d,
                                              const float* __restrict__ b2,
                                              const int* __restrict__ batch,
                                              float* __restrict__ pooled) {
  int n = blockIdx.x * 4 + (threadIdx.x >> 6);
  int lane = threadIdx.x & 63;
  int half = lane >> 5;
  int fl = lane & 31;
  int r0 = rowstart[n], dg = rowstart[n + 1] - r0;
  float sdst = s2d[n];
  float ax = 0.f, ay = 0.f, dsum = 0.f;
  for (int base = 0; base < dg; base += 32) {
    int i = base + fl;
    float p = 0.f;
    int s = 0;
    if (i < dg) {
      s = esrc[r0 + i];
      p = __expf(lrelu(s2s[s] + sdst));
    }
    dsum += p;
    int cnt = min(32, dg - base);
    for (int j = 0; j < cnt; j += 2) {
      int jj = j + half;
      float pj = __shfl(p, jj, 32);
      int sj = __shfl(s, jj, 32);
      ushort2 hv = *reinterpret_cast<const ushort2*>(&hp2b[(size_t)sj * 64 + fl * 2]);
      ax += pj * bf2f(hv.x);
      ay += pj * bf2f(hv.y);
    }
  }
#pragma unroll
  for (int o = 1; o < 32; o <<= 1) dsum += __shfl_xor(dsum, o);
  float inv = 1.f / (dsum + 1e-16f);
  ax += __shfl_xor(ax, 32);
  ay += __shfl_xor(ay, 32);
  int f = 2 * fl + half;
  float o = (half ? ay : ax) * inv + b2[f];
  atomicAdd(&pooled[batch[n] * 64 + f], o);
}

// ---- final via MFMA: out[512,40000] = pooled @ Wp + bp ------------------
// Grid (625, 32): block = 64 vocab x 16 graphs, 4 waves, 2 MFMA each.
__global__ __launch_bounds__(256) void k_final(const float* __restrict__ pooled,
                                               const unsigned short* __restrict__ wpT,
                                               const float* __restrict__ bp,
                                               float* __restrict__ out) {
  __shared__ unsigned short As[16][72];
  __shared__ float Cs[16][68];
  int t = threadIdx.x;
  int g0 = blockIdx.y * 16;
  int vb = blockIdx.x * 64;
  {
    int g = t >> 4, k4 = (t & 15) * 4;
    float4 pv = *reinterpret_cast<const float4*>(&pooled[(size_t)(g0 + g) * 64 + k4]);
    ushort4 u;
    u.x = f2bf(pv.x); u.y = f2bf(pv.y); u.z = f2bf(pv.z); u.w = f2bf(pv.w);
    *reinterpret_cast<ushort4*>(&As[g][k4]) = u;
  }
  __syncthreads();
  int w = t >> 6, lane = t & 63;
  int lrow = lane & 15, lq = lane >> 4;
  bf16x8 a0 = *reinterpret_cast<const bf16x8*>(&As[lrow][lq * 8]);
  bf16x8 a1 = *reinterpret_cast<const bf16x8*>(&As[lrow][32 + lq * 8]);
  int v = vb + w * 16 + lrow;
  const bf16x8* brow = reinterpret_cast<const bf16x8*>(wpT + (size_t)v * 64 + lq * 8);
  f32x4 acc = {};
  acc = __builtin_amdgcn_mfma_f32_16x16x32_bf16(a0, brow[0], acc, 0, 0, 0);
  acc = __builtin_amdgcn_mfma_f32_16x16x32_bf16(a1, brow[4], acc, 0, 0, 0);
#pragma unroll
  for (int r = 0; r < 4; ++r) Cs[lq * 4 + r][w * 16 + lrow] = acc[r];
  __syncthreads();
  {
    int row = t >> 4, c4 = t & 15;
    float4 c = *reinterpret_cast<const float4*>(&Cs[row][c4 * 4]);
    float4 b = *reinterpret_cast<const float4*>(&bp[vb + c4 * 4]);
    c.x += b.x; c.y += b.y; c.z += b.z; c.w += b.w;
    *reinterpret_cast<float4*>(&out[(size_t)(g0 + row) * VOCAB_C + vb + c4 * 4]) = c;
  }
}

extern "C" void kernel_launch(void* const* d_in, const int* in_sizes, int n_in,
                              void* d_out, int out_size, void* d_ws, size_t ws_size,
                              hipStream_t stream) {
  const int*   x     = (const int*)d_in[0];
  const int*   ei    = (const int*)d_in[1];
  const int*   batch = (const int*)d_in[2];
  const float* emb   = (const float*)d_in[3];
  const float* W1    = (const float*)d_in[4];
  const float* as1   = (const float*)d_in[5];
  const float* ad1   = (const float*)d_in[6];
  const float* b1    = (const float*)d_in[7];
  const float* W2    = (const float*)d_in[8];
  const float* as2   = (const float*)d_in[9];
  const float* ad2   = (const float*)d_in[10];
  const float* b2    = (const float*)d_in[11];
  const float* Wp    = (const float*)d_in[12];
  const float* bp    = (const float*)d_in[13];
  float* out = (float*)d_out;

  char* ws = (char*)d_ws;
  size_t off = 0;
#define WS_ALLOC(T, name, bytes) T name = (T)(ws + off); off += (((size_t)(bytes)) + 255) & ~(size_t)255;
  WS_ALLOC(unsigned short*, hp1b, (size_t)N_NODESC * F1 * 2)
  WS_ALLOC(unsigned short*, h1b,  (size_t)N_NODESC * F1 * 2)
  WS_ALLOC(unsigned short*, hp2b, (size_t)N_NODESC * HID * 2)
  WS_ALLOC(unsigned short*, w1bT, 512 * 64 * 2)
  WS_ALLOC(unsigned short*, w2bT, 64 * 512 * 2)
  WS_ALLOC(unsigned short*, wpT,  (size_t)VOCAB_C * HID * 2)
  WS_ALLOC(float*, s1s,  (size_t)N_NODESC * HEADS_C * 4)
  WS_ALLOC(float*, s1d,  (size_t)N_NODESC * HEADS_C * 4)
  WS_ALLOC(float*, s2s,  (size_t)N_NODESC * 4)
  WS_ALLOC(float*, s2d,  (size_t)N_NODESC * 4)
  WS_ALLOC(float*, pooled, (size_t)N_GR * HID * 4)
  WS_ALLOC(float*, wa1s, 8 * 64 * 4)
  WS_ALLOC(float*, wa1d, 8 * 64 * 4)
  WS_ALLOC(float*, w2sv, 512 * 4)
  WS_ALLOC(float*, w2dv, 512 * 4)
  WS_ALLOC(int*,   deg,      (size_t)N_NODESC * 4)
  WS_ALLOC(int*,   rowstart, (size_t)(N_NODESC + 1) * 4)
  WS_ALLOC(int*,   rowtmp,   (size_t)N_NODESC * 4)
  WS_ALLOC(int*,   partials, 256 * 4)
  WS_ALLOC(int*,   cursor,   (size_t)N_NODESC * 4)
  WS_ALLOC(int*,   esrc,     (size_t)E_TOT * 4)
#undef WS_ALLOC
  (void)ws_size; (void)in_sizes; (void)n_in; (void)out_size;

  int ethreads = 256, eblocks = (E_TOT + 255) / 256;
  k_zero<<<(N_NODESC + 255) / 256, 256, 0, stream>>>(deg, cursor, pooled);
  k_deg<<<eblocks, ethreads, 0, stream>>>(ei, deg);
  k_scan1<<<SCAN_B, 256, 0, stream>>>(deg, rowtmp, partials);
  k_scan2<<<1, 256, 0, stream>>>(partials, rowstart + N_NODESC);
  k_scan3<<<SCAN_B, 256, 0, stream>>>(deg, rowtmp, partials, rowstart);
  k_scatter<<<eblocks, ethreads, 0, stream>>>(ei, rowstart, cursor, esrc);
  k_prepwconv<<<129, 512, 0, stream>>>(W1, as1, ad1, W2, as2, ad2,
                                       wa1s, wa1d, w2sv, w2dv, w1bT, w2bT);
  k_wpt<<<VOCAB_C / 64, 256, 0, stream>>>(Wp, wpT);

  k_gemm1<<<N_NODESC / 16, 256, 0, stream>>>(x, emb, w1bT, wa1s, wa1d, hp1b, s1s, s1d);
  k_agg1<<<N_NODESC / 4, 256, 0, stream>>>(rowstart, esrc, hp1b, s1s, s1d, b1, h1b);

  k_gemm2<<<(N_NODESC + 63) / 64, 256, 0, stream>>>(h1b, w2bT, w2sv, w2dv, hp2b, s2s, s2d);
  k_agg2<<<N_NODESC / 4, 256, 0, stream>>>(rowstart, esrc, hp2b, s2s, s2d, b2, batch, pooled);

  k_final<<<dim3(VOCAB_C / 64, N_GR / 16), 256, 0, stream>>>(pooled, wpT, bp, out);
}

// Round 11
// 294.472 us; speedup vs baseline: 3.7774x; 1.0765x over previous
//
#include <hip/hip_runtime.h>
#include <hip/hip_bf16.h>

#define N_NODESC 50000
#define N_EDGESC 500000
#define E_TOT    (N_EDGESC + N_NODESC)   // 550000, with self loops
#define HID      64
#define HEADS_C  8
#define F1       (HEADS_C * HID)         // 512
#define VOCAB_C  40000
#define N_GR     512
#define SCAN_B   196                     // ceil(50000/256)

typedef __attribute__((ext_vector_type(8))) short bf16x8;
typedef __attribute__((ext_vector_type(4))) float f32x4;

__device__ __forceinline__ float lrelu(float x) { return x > 0.f ? x : 0.2f * x; }
__device__ __forceinline__ float bf2f(unsigned short u) {
  return __uint_as_float(((unsigned int)u) << 16);
}
__device__ __forceinline__ unsigned short f2bf(float f) {
  unsigned int u = __float_as_uint(f);
  unsigned int r = (u + 0x7fffu + ((u >> 16) & 1u)) >> 16;
  return (unsigned short)r;
}

// ---- zero scratch -------------------------------------------------------
__global__ void k_zero(int* __restrict__ deg, float* __restrict__ pooled) {
  int i = blockIdx.x * 256 + threadIdx.x;
  if (i < N_NODESC) deg[i] = 0;
  if (i < N_GR * HID) pooled[i] = 0.f;
}

// ---- CSR build: deg + per-edge slot in one pass -------------------------
__global__ void k_deg(const int* __restrict__ ei, int* __restrict__ deg,
                      int* __restrict__ eslot) {
  int e = blockIdx.x * blockDim.x + threadIdx.x;
  if (e >= E_TOT) return;
  int dst = (e < N_EDGESC) ? ei[N_EDGESC + e] : (e - N_EDGESC);
  eslot[e] = atomicAdd(&deg[dst], 1);
}

__global__ __launch_bounds__(256) void k_scan1(const int* __restrict__ deg,
                                               int* __restrict__ rowtmp,
                                               int* __restrict__ partials) {
  __shared__ int sh[256];
  int b = blockIdx.x, t = threadIdx.x, i = b * 256 + t;
  int d = (i < N_NODESC) ? deg[i] : 0;
  sh[t] = d;
  __syncthreads();
  for (int o = 1; o < 256; o <<= 1) {
    int v = (t >= o) ? sh[t - o] : 0;
    __syncthreads();
    sh[t] += v;
    __syncthreads();
  }
  if (i < N_NODESC) rowtmp[i] = sh[t];  // inclusive within block
  if (t == 255) partials[b] = sh[255];  // raw block total
}

// scan3: each block reduces partials[0..b-1] itself (no scan2 kernel)
__global__ __launch_bounds__(256) void k_scan3(const int* __restrict__ deg,
                                               const int* __restrict__ rowtmp,
                                               const int* __restrict__ partials,
                                               int* __restrict__ rowstart) {
  __shared__ int wsum[4];
  int b = blockIdx.x, t = threadIdx.x;
  int acc = 0;
  for (int i = t; i < b; i += 256) acc += partials[i];
#pragma unroll
  for (int o = 32; o; o >>= 1) acc += __shfl_xor(acc, o);
  if ((t & 63) == 0) wsum[t >> 6] = acc;
  __syncthreads();
  int base = wsum[0] + wsum[1] + wsum[2] + wsum[3];
  int i = b * 256 + t;
  if (i < N_NODESC) rowstart[i] = base + rowtmp[i] - deg[i];  // exclusive
  if (i == N_NODESC - 1) rowstart[N_NODESC] = base + rowtmp[i];
}

__global__ void k_scatter(const int* __restrict__ ei, const int* __restrict__ rowstart,
                          const int* __restrict__ eslot, int* __restrict__ esrc) {
  int e = blockIdx.x * blockDim.x + threadIdx.x;
  if (e >= E_TOT) return;
  int src, dst;
  if (e < N_EDGESC) { src = ei[e]; dst = ei[N_EDGESC + e]; }
  else { src = dst = e - N_EDGESC; }
  esrc[rowstart[dst] + eslot[e]] = src;
}

// ---- prep folds + weight converts + Wp transpose, one kernel ------------
// blocks 0..63: w1bT; 64..127: w2bT; 128: folds; 129..753: wpT tiles.
__global__ __launch_bounds__(512) void k_prepwconv(const float* __restrict__ W1,
                                                   const float* __restrict__ as1,
                                                   const float* __restrict__ ad1,
                                                   const float* __restrict__ W2,
                                                   const float* __restrict__ as2,
                                                   const float* __restrict__ ad2,
                                                   const float* __restrict__ Wp,
                                                   float* __restrict__ wa1s,
                                                   float* __restrict__ wa1d,
                                                   float* __restrict__ w2sv,
                                                   float* __restrict__ w2dv,
                                                   unsigned short* __restrict__ w1bT,
                                                   unsigned short* __restrict__ w2bT,
                                                   unsigned short* __restrict__ wpT) {
  __shared__ float ws[64][65];
  int b = blockIdx.x, t = threadIdx.x;
  if (b < 64) {
    int g = b * 512 + t;
    int c = g >> 6, k = g & 63;
    w1bT[g] = f2bf(W1[(size_t)k * F1 + c]);
  } else if (b < 128) {
    int idx = (b - 64) * 512 + t;
    int c = idx >> 9, k = idx & 511;
    w2bT[idx] = f2bf(W2[(size_t)k * HID + c]);
  } else if (b == 128) {
    int k = t >> 3, h = t & 7;
    float ss = 0.f, dd = 0.f;
    for (int c = 0; c < 64; ++c) {
      float w = W1[k * F1 + h * 64 + c];
      ss += w * as1[h * 64 + c];
      dd += w * ad1[h * 64 + c];
    }
    wa1s[h * 64 + k] = ss;
    wa1d[h * 64 + k] = dd;
    float s2 = 0.f, d2 = 0.f;
    for (int c = 0; c < 64; ++c) {
      float w = W2[t * 64 + c];
      s2 += w * as2[c];
      d2 += w * ad2[c];
    }
    w2sv[t] = s2;
    w2dv[t] = d2;
  } else {
    int v0 = (b - 129) * 64;
#pragma unroll
    for (int rep = 0; rep < 8; ++rep) {
      int idx = rep * 512 + t;
      int k = idx >> 6, v = idx & 63;
      ws[k][v] = Wp[(size_t)k * VOCAB_C + v0 + v];
    }
    __syncthreads();
#pragma unroll
    for (int rep = 0; rep < 8; ++rep) {
      int idx = rep * 512 + t;
      int v = idx >> 6, k = idx & 63;
      wpT[(size_t)(v0 + v) * 64 + k] = f2bf(ws[k][v]);
    }
  }
}

// ---- GEMM1 fused (embed gather + scores1 + MFMA + coalesced store) ------
__global__ __launch_bounds__(256) void k_gemm1(const int* __restrict__ x,
                                               const float* __restrict__ emb,
                                               const unsigned short* __restrict__ w1bT,
                                               const float* __restrict__ wa1s,
                                               const float* __restrict__ wa1d,
                                               unsigned short* __restrict__ hp1b,
                                               float* __restrict__ s1s,
                                               float* __restrict__ s1d) {
  __shared__ unsigned short As[16][72];
  __shared__ unsigned short Ts[16][520];
  __shared__ float was[512], wad[512];
  int t = threadIdx.x;
  int n0 = blockIdx.x * 16;
  was[t] = wa1s[t]; was[t + 256] = wa1s[t + 256];
  wad[t] = wa1d[t]; wad[t + 256] = wa1d[t + 256];
  {
    int row = t >> 4, q = t & 15;
    int xr = x[n0 + row];
    float4 hv = reinterpret_cast<const float4*>(emb)[(size_t)xr * 16 + q];
    ushort4 u;
    u.x = f2bf(hv.x); u.y = f2bf(hv.y); u.z = f2bf(hv.z); u.w = f2bf(hv.w);
    *reinterpret_cast<ushort4*>(&As[row][q * 4]) = u;
  }
  __syncthreads();
  {
    int node = t & 15, head = (t >> 4) & 7, sel = t >> 7;
    const float* wa = sel ? wad : was;
    float a = 0.f;
#pragma unroll 8
    for (int k = 0; k < 64; ++k) a += bf2f(As[node][k]) * wa[head * 64 + k];
    (sel ? s1d : s1s)[(size_t)(n0 + node) * 8 + head] = a;
  }
  int w = t >> 6, lane = t & 63;
  int lrow = lane & 15, lq = lane >> 4;
  bf16x8 a0 = *reinterpret_cast<const bf16x8*>(&As[lrow][lq * 8]);
  bf16x8 a1 = *reinterpret_cast<const bf16x8*>(&As[lrow][32 + lq * 8]);
  int c0 = w * 128;
  f32x4 acc[8] = {};
#pragma unroll
  for (int ct = 0; ct < 8; ++ct) {
    int col = c0 + ct * 16 + lrow;
    const bf16x8* brow = reinterpret_cast<const bf16x8*>(w1bT + (size_t)col * 64 + lq * 8);
    acc[ct] = __builtin_amdgcn_mfma_f32_16x16x32_bf16(a0, brow[0], acc[ct], 0, 0, 0);
    acc[ct] = __builtin_amdgcn_mfma_f32_16x16x32_bf16(a1, brow[4], acc[ct], 0, 0, 0);
  }
#pragma unroll
  for (int ct = 0; ct < 8; ++ct) {
    int col = c0 + ct * 16 + lrow;
#pragma unroll
    for (int r = 0; r < 4; ++r)
      Ts[lq * 4 + r][col] = f2bf(acc[ct][r]);
  }
  __syncthreads();
  for (int i = t; i < 1024; i += 256) {
    int r = i >> 6, c16 = i & 63;
    reinterpret_cast<uint4*>(&hp1b[(size_t)(n0 + r) * F1])[c16] =
        *reinterpret_cast<const uint4*>(&Ts[r][c16 * 8]);
  }
}

// ---- layer-1 aggregate: single pass, ONE WAVE per node ------------------
__global__ __launch_bounds__(256) void k_agg1(const int* __restrict__ rowstart,
                                              const int* __restrict__ esrc,
                                              const unsigned short* __restrict__ hp1b,
                                              const float* __restrict__ s1s,
                                              const float* __restrict__ s1d,
                                              const float* __restrict__ b1,
                                              unsigned short* __restrict__ h1b) {
  int n = blockIdx.x * 4 + (threadIdx.x >> 6);
  int L = threadIdx.x & 63;
  int eh = L >> 3;  // edge slot (p-phase)
  int hh = L & 7;   // head (p-phase)
  int r0 = rowstart[n], dg = rowstart[n + 1] - r0;
  float sdst = s1d[n * 8 + hh];
  float acc[8] = {};
  float dsum = 0.f;
  int myh = L >> 3;  // head of this lane's feature slice
  for (int base = 0; base < dg; base += 8) {
    int i = base + eh;
    float p = 0.f;
    int s = 0;
    if (i < dg) {
      s = esrc[r0 + i];
      p = __expf(lrelu(s1s[s * 8 + hh] + sdst));
    }
    dsum += p;
    int cnt = min(8, dg - base);
    for (int j = 0; j < cnt; ++j) {
      float pj = __shfl(p, (j << 3) | myh);
      int sj = __shfl(s, j << 3);
      uint4 u = *reinterpret_cast<const uint4*>(&hp1b[(size_t)sj * F1 + L * 8]);
      acc[0] += pj * bf2f((unsigned short)(u.x & 0xffff));
      acc[1] += pj * bf2f((unsigned short)(u.x >> 16));
      acc[2] += pj * bf2f((unsigned short)(u.y & 0xffff));
      acc[3] += pj * bf2f((unsigned short)(u.y >> 16));
      acc[4] += pj * bf2f((unsigned short)(u.z & 0xffff));
      acc[5] += pj * bf2f((unsigned short)(u.z >> 16));
      acc[6] += pj * bf2f((unsigned short)(u.w & 0xffff));
      acc[7] += pj * bf2f((unsigned short)(u.w >> 16));
    }
  }
  dsum += __shfl_xor(dsum, 8);
  dsum += __shfl_xor(dsum, 16);
  dsum += __shfl_xor(dsum, 32);
  float inv = 1.f / (__shfl(dsum, myh) + 1e-16f);
  int f0 = L * 8;
  float o[8];
#pragma unroll
  for (int k = 0; k < 8; ++k) {
    float v = acc[k] * inv + b1[f0 + k];
    o[k] = v > 0.f ? v : (__expf(v) - 1.f);
  }
  uint4 ov;
  ov.x = (unsigned int)f2bf(o[0]) | ((unsigned int)f2bf(o[1]) << 16);
  ov.y = (unsigned int)f2bf(o[2]) | ((unsigned int)f2bf(o[3]) << 16);
  ov.z = (unsigned int)f2bf(o[4]) | ((unsigned int)f2bf(o[5]) << 16);
  ov.w = (unsigned int)f2bf(o[6]) | ((unsigned int)f2bf(o[7]) << 16);
  *reinterpret_cast<uint4*>(&h1b[(size_t)n * F1 + f0]) = ov;
}

// ---- GEMM2 via MFMA (+scores2) ------------------------------------------
__global__ __launch_bounds__(256) void k_gemm2(const unsigned short* __restrict__ h1b,
                                               const unsigned short* __restrict__ w2bT,
                                               const float* __restrict__ w2sv,
                                               const float* __restrict__ w2dv,
                                               unsigned short* __restrict__ hp2b,
                                               float* __restrict__ s2s,
                                               float* __restrict__ s2d) {
  __shared__ float wsv[512], wdv[512];
  int t = threadIdx.x;
  for (int i = t; i < 512; i += 256) { wsv[i] = w2sv[i]; wdv[i] = w2dv[i]; }
  __syncthreads();
  int w = t >> 6, lane = t & 63;
  int lrow = lane & 15, lq = lane >> 4;
  int nb = blockIdx.x * 64 + w * 16;
  if (nb >= N_NODESC) return;
  f32x4 acc[4] = {};
  float ssp = 0.f, ddp = 0.f;
  const unsigned short* arowp = h1b + (size_t)(nb + lrow) * F1;
#pragma unroll 4
  for (int kq = 0; kq < 16; ++kq) {
    int kbase = kq * 32 + lq * 8;
    bf16x8 a = *reinterpret_cast<const bf16x8*>(arowp + kbase);
#pragma unroll
    for (int i = 0; i < 8; ++i) {
      float f = bf2f((unsigned short)a[i]);
      ssp += f * wsv[kbase + i];
      ddp += f * wdv[kbase + i];
    }
#pragma unroll
    for (int ct = 0; ct < 4; ++ct) {
      bf16x8 b = *reinterpret_cast<const bf16x8*>(w2bT + (size_t)(ct * 16 + lrow) * F1 + kbase);
      acc[ct] = __builtin_amdgcn_mfma_f32_16x16x32_bf16(a, b, acc[ct], 0, 0, 0);
    }
  }
  ssp += __shfl_xor(ssp, 16); ssp += __shfl_xor(ssp, 32);
  ddp += __shfl_xor(ddp, 16); ddp += __shfl_xor(ddp, 32);
  if (lane < 16) { s2s[nb + lane] = ssp; s2d[nb + lane] = ddp; }
#pragma unroll
  for (int ct = 0; ct < 4; ++ct) {
    int col = ct * 16 + lrow;
#pragma unroll
    for (int r = 0; r < 4; ++r)
      hp2b[(size_t)(nb + lq * 4 + r) * HID + col] = f2bf(acc[ct][r]);
  }
}

// ---- layer-2 aggregate: SINGLE PASS + bias + pooled atomicAdd -----------
__global__ __launch_bounds__(256) void k_agg2(const int* __restrict__ rowstart,
                                              const int* __restrict__ esrc,
                                              const unsigned short* __restrict__ hp2b,
                                              const float* __restrict__ s2s,
                                              const float* __restrict__ s2d,
                                              const float* __restrict__ b2,
                                              const int* __restrict__ batch,
                                              float* __restrict__ pooled) {
  int n = blockIdx.x * 4 + (threadIdx.x >> 6);
  int lane = threadIdx.x & 63;
  int half = lane >> 5;
  int fl = lane & 31;
  int r0 = rowstart[n], dg = rowstart[n + 1] - r0;
  float sdst = s2d[n];
  float ax = 0.f, ay = 0.f, dsum = 0.f;
  for (int base = 0; base < dg; base += 32) {
    int i = base + fl;
    float p = 0.f;
    int s = 0;
    if (i < dg) {
      s = esrc[r0 + i];
      p = __expf(lrelu(s2s[s] + sdst));
    }
    dsum += p;
    int cnt = min(32, dg - base);
    for (int j = 0; j < cnt; j += 2) {
      int jj = j + half;
      float pj = __shfl(p, jj, 32);
      int sj = __shfl(s, jj, 32);
      ushort2 hv = *reinterpret_cast<const ushort2*>(&hp2b[(size_t)sj * 64 + fl * 2]);
      ax += pj * bf2f(hv.x);
      ay += pj * bf2f(hv.y);
    }
  }
#pragma unroll
  for (int o = 1; o < 32; o <<= 1) dsum += __shfl_xor(dsum, o);
  float inv = 1.f / (dsum + 1e-16f);
  ax += __shfl_xor(ax, 32);
  ay += __shfl_xor(ay, 32);
  int f = 2 * fl + half;
  float o = (half ? ay : ax) * inv + b2[f];
  atomicAdd(&pooled[batch[n] * 64 + f], o);
}

// ---- final via MFMA: out[512,40000] = pooled @ Wp + bp ------------------
// Grid (125, 32): block = 320 vocab x 16 graphs; wave handles 5 col-tiles.
__global__ __launch_bounds__(256) void k_final(const float* __restrict__ pooled,
                                               const unsigned short* __restrict__ wpT,
                                               const float* __restrict__ bp,
                                               float* __restrict__ out) {
  __shared__ unsigned short As[16][72];
  __shared__ float Cs[16][324];
  int t = threadIdx.x;
  int g0 = blockIdx.y * 16;
  int vb = blockIdx.x * 320;
  {
    int g = t >> 4, k4 = (t & 15) * 4;
    float4 pv = *reinterpret_cast<const float4*>(&pooled[(size_t)(g0 + g) * 64 + k4]);
    ushort4 u;
    u.x = f2bf(pv.x); u.y = f2bf(pv.y); u.z = f2bf(pv.z); u.w = f2bf(pv.w);
    *reinterpret_cast<ushort4*>(&As[g][k4]) = u;
  }
  __syncthreads();
  int w = t >> 6, lane = t & 63;
  int lrow = lane & 15, lq = lane >> 4;
  bf16x8 a0 = *reinterpret_cast<const bf16x8*>(&As[lrow][lq * 8]);
  bf16x8 a1 = *reinterpret_cast<const bf16x8*>(&As[lrow][32 + lq * 8]);
#pragma unroll
  for (int ct = 0; ct < 5; ++ct) {
    int cloc = (w * 5 + ct) * 16 + lrow;
    const bf16x8* brow = reinterpret_cast<const bf16x8*>(wpT + (size_t)(vb + cloc) * 64 + lq * 8);
    f32x4 acc = {};
    acc = __builtin_amdgcn_mfma_f32_16x16x32_bf16(a0, brow[0], acc, 0, 0, 0);
    acc = __builtin_amdgcn_mfma_f32_16x16x32_bf16(a1, brow[4], acc, 0, 0, 0);
#pragma unroll
    for (int r = 0; r < 4; ++r) Cs[lq * 4 + r][cloc] = acc[r];
  }
  __syncthreads();
  for (int i = t; i < 1280; i += 256) {
    int r = i / 80, c = i % 80;
    float4 cv = *reinterpret_cast<const float4*>(&Cs[r][c * 4]);
    float4 bv = *reinterpret_cast<const float4*>(&bp[vb + c * 4]);
    cv.x += bv.x; cv.y += bv.y; cv.z += bv.z; cv.w += bv.w;
    *reinterpret_cast<float4*>(&out[(size_t)(g0 + r) * VOCAB_C + vb + c * 4]) = cv;
  }
}

extern "C" void kernel_launch(void* const* d_in, const int* in_sizes, int n_in,
                              void* d_out, int out_size, void* d_ws, size_t ws_size,
                              hipStream_t stream) {
  const int*   x     = (const int*)d_in[0];
  const int*   ei    = (const int*)d_in[1];
  const int*   batch = (const int*)d_in[2];
  const float* emb   = (const float*)d_in[3];
  const float* W1    = (const float*)d_in[4];
  const float* as1   = (const float*)d_in[5];
  const float* ad1   = (const float*)d_in[6];
  const float* b1    = (const float*)d_in[7];
  const float* W2    = (const float*)d_in[8];
  const float* as2   = (const float*)d_in[9];
  const float* ad2   = (const float*)d_in[10];
  const float* b2    = (const float*)d_in[11];
  const float* Wp    = (const float*)d_in[12];
  const float* bp    = (const float*)d_in[13];
  float* out = (float*)d_out;

  char* ws = (char*)d_ws;
  size_t off = 0;
#define WS_ALLOC(T, name, bytes) T name = (T)(ws + off); off += (((size_t)(bytes)) + 255) & ~(size_t)255;
  WS_ALLOC(unsigned short*, hp1b, (size_t)N_NODESC * F1 * 2)
  WS_ALLOC(unsigned short*, h1b,  (size_t)N_NODESC * F1 * 2)
  WS_ALLOC(unsigned short*, hp2b, (size_t)N_NODESC * HID * 2)
  WS_ALLOC(unsigned short*, w1bT, 512 * 64 * 2)
  WS_ALLOC(unsigned short*, w2bT, 64 * 512 * 2)
  WS_ALLOC(unsigned short*, wpT,  (size_t)VOCAB_C * HID * 2)
  WS_ALLOC(float*, s1s,  (size_t)N_NODESC * HEADS_C * 4)
  WS_ALLOC(float*, s1d,  (size_t)N_NODESC * HEADS_C * 4)
  WS_ALLOC(float*, s2s,  (size_t)N_NODESC * 4)
  WS_ALLOC(float*, s2d,  (size_t)N_NODESC * 4)
  WS_ALLOC(float*, pooled, (size_t)N_GR * HID * 4)
  WS_ALLOC(float*, wa1s, 8 * 64 * 4)
  WS_ALLOC(float*, wa1d, 8 * 64 * 4)
  WS_ALLOC(float*, w2sv, 512 * 4)
  WS_ALLOC(float*, w2dv, 512 * 4)
  WS_ALLOC(int*,   deg,      (size_t)N_NODESC * 4)
  WS_ALLOC(int*,   rowstart, (size_t)(N_NODESC + 1) * 4)
  WS_ALLOC(int*,   rowtmp,   (size_t)N_NODESC * 4)
  WS_ALLOC(int*,   partials, 256 * 4)
  WS_ALLOC(int*,   eslot,    (size_t)E_TOT * 4)
  WS_ALLOC(int*,   esrc,     (size_t)E_TOT * 4)
#undef WS_ALLOC
  (void)ws_size; (void)in_sizes; (void)n_in; (void)out_size;

  int ethreads = 256, eblocks = (E_TOT + 255) / 256;
  k_zero<<<SCAN_B, 256, 0, stream>>>(deg, pooled);
  k_deg<<<eblocks, ethreads, 0, stream>>>(ei, deg, eslot);
  k_scan1<<<SCAN_B, 256, 0, stream>>>(deg, rowtmp, partials);
  k_scan3<<<SCAN_B, 256, 0, stream>>>(deg, rowtmp, partials, rowstart);
  k_scatter<<<eblocks, ethreads, 0, stream>>>(ei, rowstart, eslot, esrc);
  k_prepwconv<<<129 + VOCAB_C / 64, 512, 0, stream>>>(
      W1, as1, ad1, W2, as2, ad2, Wp,
      wa1s, wa1d, w2sv, w2dv, w1bT, w2bT, wpT);

  k_gemm1<<<N_NODESC / 16, 256, 0, stream>>>(x, emb, w1bT, wa1s, wa1d, hp1b, s1s, s1d);
  k_agg1<<<N_NODESC / 4, 256, 0, stream>>>(rowstart, esrc, hp1b, s1s, s1d, b1, h1b);

  k_gemm2<<<(N_NODESC + 63) / 64, 256, 0, stream>>>(h1b, w2bT, w2sv, w2dv, hp2b, s2s, s2d);
  k_agg2<<<N_NODESC / 4, 256, 0, stream>>>(rowstart, esrc, hp2b, s2s, s2d, b2, batch, pooled);

  k_final<<<dim3(VOCAB_C / 320, N_GR / 16), 256, 0, stream>>>(pooled, wpT, bp, out);
}